// Round 1
// baseline (2572.887 us; speedup 1.0000x reference)
//
#include <hip/hip_runtime.h>
#include <hip/hip_bf16.h>
#include <math.h>

#define D_   1024
#define H_   16
#define DH_  64
#define FFN_ 4096
#define B_   4
#define T_   1024
#define M_   128
#define N_   64
#define PREF 192
#define L_   1216
#define BL_  (B_*L_)   // 4864
#define BT_  (B_*T_)   // 4096

// ---------------- block reduce helper ----------------
__device__ __forceinline__ float block_reduce_sum256(float v, float* sbuf) {
#pragma unroll
    for (int o = 32; o > 0; o >>= 1) v += __shfl_xor(v, o, 64);
    int w = threadIdx.x >> 6;
    if ((threadIdx.x & 63) == 0) sbuf[w] = v;
    __syncthreads();
    float r = sbuf[0] + sbuf[1] + sbuf[2] + sbuf[3];
    __syncthreads();
    return r;
}

// ---------------- concat + LayerNorm1 ----------------
// one block per row of x_full (BL rows); 256 threads * 4 floats = 1024
__global__ __launch_bounds__(256) void ln1_concat_kernel(
    const float* __restrict__ x, const float* __restrict__ mem,
    const float* __restrict__ nmr, const float* __restrict__ g,
    const float* __restrict__ be, float* __restrict__ x_full,
    float* __restrict__ xa)
{
    __shared__ float sbuf[4];
    int row = blockIdx.x;
    int b = row / L_, pos = row % L_;
    const float* src;
    if (pos < M_)          src = mem + ((size_t)b*M_ + pos)      * D_;
    else if (pos < M_+N_)  src = nmr + ((size_t)b*N_ + (pos-M_)) * D_;
    else                   src = x   + ((size_t)b*T_ + (pos-PREF))*D_;

    int c = threadIdx.x << 2;
    float4 v = *(const float4*)(src + c);
    float s = v.x + v.y + v.z + v.w;
    s = block_reduce_sum256(s, sbuf);
    float mu = s * (1.0f / D_);
    float dx = v.x - mu, dy = v.y - mu, dz = v.z - mu, dw = v.w - mu;
    float q = dx*dx + dy*dy + dz*dz + dw*dw;
    q = block_reduce_sum256(q, sbuf);
    float inv = rsqrtf(q * (1.0f / D_) + 1e-5f);
    float4 gv = *(const float4*)(g + c);
    float4 bv = *(const float4*)(be + c);
    float4 o;
    o.x = dx*inv*gv.x + bv.x;
    o.y = dy*inv*gv.y + bv.y;
    o.z = dz*inv*gv.z + bv.z;
    o.w = dw*inv*gv.w + bv.w;
    *(float4*)(x_full + (size_t)row*D_ + c) = v;
    *(float4*)(xa     + (size_t)row*D_ + c) = o;
}

// ---------------- LayerNorm2 (plain) ----------------
__global__ __launch_bounds__(256) void ln2_kernel(
    const float* __restrict__ src, const float* __restrict__ g,
    const float* __restrict__ be, float* __restrict__ dst)
{
    __shared__ float sbuf[4];
    int row = blockIdx.x;
    int c = threadIdx.x << 2;
    float4 v = *(const float4*)(src + (size_t)row*D_ + c);
    float s = v.x + v.y + v.z + v.w;
    s = block_reduce_sum256(s, sbuf);
    float mu = s * (1.0f / D_);
    float dx = v.x - mu, dy = v.y - mu, dz = v.z - mu, dw = v.w - mu;
    float q = dx*dx + dy*dy + dz*dz + dw*dw;
    q = block_reduce_sum256(q, sbuf);
    float inv = rsqrtf(q * (1.0f / D_) + 1e-5f);
    float4 gv = *(const float4*)(g + c);
    float4 bv = *(const float4*)(be + c);
    float4 o;
    o.x = dx*inv*gv.x + bv.x;
    o.y = dy*inv*gv.y + bv.y;
    o.z = dz*inv*gv.z + bv.z;
    o.w = dw*inv*gv.w + bv.w;
    *(float4*)(dst + (size_t)row*D_ + c) = o;
}

// ---------------- tiled fp32 GEMM, 64x64 tile, BK=16 ----------------
// C[Mr x Nc] = A[Mr x K] @ W[K x Nc] + bias, with epilogue modes:
//   mode 0: +bias            mode 1: +bias +res           mode 2: relu(+bias)^2
// stridedRes: res row index maps compact row r -> batch-strided x_full row.
__global__ __launch_bounds__(256) void gemm_f32_kernel(
    const float* __restrict__ A, const float* __restrict__ Wt,
    const float* __restrict__ bias, const float* __restrict__ res,
    float* __restrict__ C, int K, int Nc, int mode, int stridedRes)
{
    __shared__ float As[16][68];   // transposed A tile, padded for b128 alignment
    __shared__ float Bs[16][64];
    int tid = threadIdx.x;
    int tx = tid & 15, ty = tid >> 4;
    int row0 = blockIdx.y << 6, col0 = blockIdx.x << 6;
    float acc[4][4] = {};

    int ar = tid >> 2, ac4 = (tid & 3) << 2;
    int br = tid >> 4, bc4 = (tid & 15) << 2;
    const float* Aptr = A  + (size_t)(row0 + ar) * K + ac4;
    const float* Bptr = Wt + (size_t)br * Nc + col0 + bc4;

    for (int k0 = 0; k0 < K; k0 += 16) {
        float4 av = *(const float4*)Aptr;  Aptr += 16;
        float4 bv = *(const float4*)Bptr;  Bptr += (size_t)16 * Nc;
        As[ac4+0][ar] = av.x; As[ac4+1][ar] = av.y;
        As[ac4+2][ar] = av.z; As[ac4+3][ar] = av.w;
        *(float4*)(&Bs[br][bc4]) = bv;
        __syncthreads();
#pragma unroll
        for (int kk = 0; kk < 16; ++kk) {
            float4 a = *(const float4*)(&As[kk][ty << 2]);
            float4 b = *(const float4*)(&Bs[kk][tx << 2]);
            acc[0][0] = fmaf(a.x, b.x, acc[0][0]);
            acc[0][1] = fmaf(a.x, b.y, acc[0][1]);
            acc[0][2] = fmaf(a.x, b.z, acc[0][2]);
            acc[0][3] = fmaf(a.x, b.w, acc[0][3]);
            acc[1][0] = fmaf(a.y, b.x, acc[1][0]);
            acc[1][1] = fmaf(a.y, b.y, acc[1][1]);
            acc[1][2] = fmaf(a.y, b.z, acc[1][2]);
            acc[1][3] = fmaf(a.y, b.w, acc[1][3]);
            acc[2][0] = fmaf(a.z, b.x, acc[2][0]);
            acc[2][1] = fmaf(a.z, b.y, acc[2][1]);
            acc[2][2] = fmaf(a.z, b.z, acc[2][2]);
            acc[2][3] = fmaf(a.z, b.w, acc[2][3]);
            acc[3][0] = fmaf(a.w, b.x, acc[3][0]);
            acc[3][1] = fmaf(a.w, b.y, acc[3][1]);
            acc[3][2] = fmaf(a.w, b.z, acc[3][2]);
            acc[3][3] = fmaf(a.w, b.w, acc[3][3]);
        }
        __syncthreads();
    }

    int ccol = col0 + (tx << 2);
    float4 biasv = *(const float4*)(bias + ccol);
#pragma unroll
    for (int i = 0; i < 4; ++i) {
        int r = row0 + (ty << 2) + i;
        float4 o;
        o.x = acc[i][0] + biasv.x;
        o.y = acc[i][1] + biasv.y;
        o.z = acc[i][2] + biasv.z;
        o.w = acc[i][3] + biasv.w;
        if (mode == 2) {
            o.x = fmaxf(o.x, 0.f); o.x *= o.x;
            o.y = fmaxf(o.y, 0.f); o.y *= o.y;
            o.z = fmaxf(o.z, 0.f); o.z *= o.z;
            o.w = fmaxf(o.w, 0.f); o.w *= o.w;
        } else if (mode == 1) {
            size_t roff;
            if (stridedRes) roff = ((size_t)(r >> 10) * L_ + PREF + (r & (T_-1))) * D_ + ccol;
            else            roff = (size_t)r * Nc + ccol;
            float4 rv = *(const float4*)(res + roff);
            o.x += rv.x; o.y += rv.y; o.z += rv.z; o.w += rv.w;
        }
        *(float4*)(C + (size_t)r * Nc + ccol) = o;
    }
}

// ---------------- RoPE (in place on q_lin and k_lin) ----------------
// one block per row; thread t: head = t>>4, freq index d = t&15 (ROT/2 = 16)
__global__ __launch_bounds__(256) void rope_kernel(
    float* __restrict__ q_lin, float* __restrict__ k_lin)
{
    int row = blockIdx.x;
    int pos = row % L_;
    int h = threadIdx.x >> 4, d = threadIdx.x & 15;
    float invf = powf(10000.0f, -(float)d * (1.0f / 16.0f));
    float th = (float)pos * invf;
    float sn, cs;
    sincosf(th, &sn, &cs);
    size_t base = (size_t)row * D_ + h * DH_;
    float a0 = q_lin[base + d], a1 = q_lin[base + d + 16];
    q_lin[base + d]      = a0 * cs - a1 * sn;
    q_lin[base + d + 16] = a1 * cs + a0 * sn;
    float b0 = k_lin[base + d], b1 = k_lin[base + d + 16];
    k_lin[base + d]      = b0 * cs - b1 * sn;
    k_lin[base + d + 16] = b1 * cs + b0 * sn;
}

// ---------------- causal attention (flash-style, fp32) ----------------
// grid: B*H*(T/16) blocks; block = 256 = 4 waves; each wave owns 4 query rows.
// q/k/v layout: [b, pos, h*64+d] (row-major BL x D)
__global__ __launch_bounds__(256) void attn_kernel(
    const float* __restrict__ q_lin, const float* __restrict__ k_lin,
    const float* __restrict__ v_lin, float* __restrict__ attn_c)
{
    __shared__ float Ks[64][65];
    __shared__ float Vs[64][64];
    __shared__ float qs[16][64];

    int bid = blockIdx.x;
    int qg = bid & 63;
    int h  = (bid >> 6) & (H_ - 1);
    int b  = bid >> 10;
    int tid = threadIdx.x, lane = tid & 63, w = tid >> 6;
    int i0_blk = PREF + (qg << 4);

    {   // stage the 16 query rows (each row = 64 floats of this head)
        int r = tid >> 4, c4 = (tid & 15) << 2;
        float4 qv = *(const float4*)(q_lin + ((size_t)b*L_ + i0_blk + r)*D_ + h*DH_ + c4);
        *(float4*)(&qs[r][c4]) = qv;
    }

    int i_base = i0_blk + (w << 2);
    const int qb = w << 2;
    float acc0=0.f, acc1=0.f, acc2=0.f, acc3=0.f;
    float m0=-INFINITY, m1=-INFINITY, m2=-INFINITY, m3=-INFINITY;
    float l0=0.f, l1=0.f, l2=0.f, l3=0.f;

    int nkb = ((i0_blk + 15) >> 6) + 1;
    for (int jb = 0; jb < nkb; ++jb) {
        int j0 = jb << 6;
        __syncthreads();
#pragma unroll
        for (int s = 0; s < 4; ++s) {   // stage K,V 64x64 tiles
            int idx = (s << 8) + tid;
            int r = idx >> 4, c4 = (idx & 15) << 2;
            size_t goff = ((size_t)b*L_ + j0 + r)*D_ + h*DH_ + c4;
            float4 kv = *(const float4*)(k_lin + goff);
            Ks[r][c4+0] = kv.x; Ks[r][c4+1] = kv.y;
            Ks[r][c4+2] = kv.z; Ks[r][c4+3] = kv.w;
            float4 vv = *(const float4*)(v_lin + goff);
            *(float4*)(&Vs[r][c4]) = vv;
        }
        __syncthreads();

        float s0=0.f, s1=0.f, s2=0.f, s3=0.f;
#pragma unroll 16
        for (int d = 0; d < 64; ++d) {
            float kd = Ks[lane][d];
            s0 = fmaf(qs[qb+0][d], kd, s0);
            s1 = fmaf(qs[qb+1][d], kd, s1);
            s2 = fmaf(qs[qb+2][d], kd, s2);
            s3 = fmaf(qs[qb+3][d], kd, s3);
        }
        int j = j0 + lane;
        s0 = (j <= i_base+0) ? s0 * 0.125f : -INFINITY;
        s1 = (j <= i_base+1) ? s1 * 0.125f : -INFINITY;
        s2 = (j <= i_base+2) ? s2 * 0.125f : -INFINITY;
        s3 = (j <= i_base+3) ? s3 * 0.125f : -INFINITY;

        float bm0=s0, bm1=s1, bm2=s2, bm3=s3;
#pragma unroll
        for (int o = 32; o > 0; o >>= 1) {
            bm0 = fmaxf(bm0, __shfl_xor(bm0, o, 64));
            bm1 = fmaxf(bm1, __shfl_xor(bm1, o, 64));
            bm2 = fmaxf(bm2, __shfl_xor(bm2, o, 64));
            bm3 = fmaxf(bm3, __shfl_xor(bm3, o, 64));
        }
        float nm0 = fmaxf(m0, bm0), nm1 = fmaxf(m1, bm1);
        float nm2 = fmaxf(m2, bm2), nm3 = fmaxf(m3, bm3);
        float c0 = expf(m0 - nm0), c1 = expf(m1 - nm1);
        float c2 = expf(m2 - nm2), c3 = expf(m3 - nm3);
        float p0 = expf(s0 - nm0), p1 = expf(s1 - nm1);
        float p2 = expf(s2 - nm2), p3 = expf(s3 - nm3);
        float ps0=p0, ps1=p1, ps2=p2, ps3=p3;
#pragma unroll
        for (int o = 32; o > 0; o >>= 1) {
            ps0 += __shfl_xor(ps0, o, 64);
            ps1 += __shfl_xor(ps1, o, 64);
            ps2 += __shfl_xor(ps2, o, 64);
            ps3 += __shfl_xor(ps3, o, 64);
        }
        l0 = l0*c0 + ps0; l1 = l1*c1 + ps1;
        l2 = l2*c2 + ps2; l3 = l3*c3 + ps3;
        acc0 *= c0; acc1 *= c1; acc2 *= c2; acc3 *= c3;
#pragma unroll 8
        for (int t = 0; t < 64; ++t) {
            float vv = Vs[t][lane];
            acc0 = fmaf(__shfl(p0, t, 64), vv, acc0);
            acc1 = fmaf(__shfl(p1, t, 64), vv, acc1);
            acc2 = fmaf(__shfl(p2, t, 64), vv, acc2);
            acc3 = fmaf(__shfl(p3, t, 64), vv, acc3);
        }
        m0 = nm0; m1 = nm1; m2 = nm2; m3 = nm3;
    }

    size_t obase = ((size_t)b*T_ + (i_base - PREF)) * D_ + h*DH_ + lane;
    attn_c[obase]        = acc0 / l0;
    attn_c[obase + D_]   = acc1 / l1;
    attn_c[obase + 2*D_] = acc2 / l2;
    attn_c[obase + 3*D_] = acc3 / l3;
}

// ---------------- launch ----------------
extern "C" void kernel_launch(void* const* d_in, const int* in_sizes, int n_in,
                              void* d_out, int out_size, void* d_ws, size_t ws_size,
                              hipStream_t stream) {
    const float* x   = (const float*)d_in[0];
    const float* mem = (const float*)d_in[1];
    const float* nmr = (const float*)d_in[2];
    const float* Wq  = (const float*)d_in[3];
    const float* bq  = (const float*)d_in[4];
    const float* Wk  = (const float*)d_in[5];
    const float* bk  = (const float*)d_in[6];
    const float* Wv  = (const float*)d_in[7];
    const float* bv  = (const float*)d_in[8];
    const float* Wo  = (const float*)d_in[9];
    const float* bo  = (const float*)d_in[10];
    const float* W1  = (const float*)d_in[11];
    const float* b1  = (const float*)d_in[12];
    const float* W2  = (const float*)d_in[13];
    const float* b2  = (const float*)d_in[14];
    const float* g1  = (const float*)d_in[15];
    const float* be1 = (const float*)d_in[16];
    const float* g2  = (const float*)d_in[17];
    const float* be2 = (const float*)d_in[18];
    float* out = (float*)d_out;

    float* f = (float*)d_ws;
    const size_t BLD = (size_t)BL_ * D_;
    float* x_full = f;
    float* xa     = f + BLD;
    float* q_lin  = f + 2*BLD;
    float* k_lin  = f + 3*BLD;
    float* v_lin  = f + 4*BLD;
    float* h1     = f + 5*BLD;       // BT_ * FFN_ floats
    float* attn_c = xa;              // xa dead after QKV gemms
    float* x2     = q_lin;           // q dead after attention
    float* xf_in  = k_lin;           // k dead after attention

    ln1_concat_kernel<<<BL_, 256, 0, stream>>>(x, mem, nmr, g1, be1, x_full, xa);

    gemm_f32_kernel<<<dim3(D_/64, BL_/64), 256, 0, stream>>>(xa, Wq, bq, nullptr, q_lin, D_, D_, 0, 0);
    gemm_f32_kernel<<<dim3(D_/64, BL_/64), 256, 0, stream>>>(xa, Wk, bk, nullptr, k_lin, D_, D_, 0, 0);
    gemm_f32_kernel<<<dim3(D_/64, BL_/64), 256, 0, stream>>>(xa, Wv, bv, nullptr, v_lin, D_, D_, 0, 0);

    rope_kernel<<<BL_, 256, 0, stream>>>(q_lin, k_lin);

    attn_kernel<<<B_*H_*(T_/16), 256, 0, stream>>>(q_lin, k_lin, v_lin, attn_c);

    // x2 = attn @ Wo + bo + x_full[rows >= pref]  (strided residual)
    gemm_f32_kernel<<<dim3(D_/64, BT_/64), 256, 0, stream>>>(attn_c, Wo, bo, x_full, x2, D_, D_, 1, 1);

    ln2_kernel<<<BT_, 256, 0, stream>>>(x2, g2, be2, xf_in);

    // h1 = relu(xf @ W1 + b1)^2
    gemm_f32_kernel<<<dim3(FFN_/64, BT_/64), 256, 0, stream>>>(xf_in, W1, b1, nullptr, h1, D_, FFN_, 2, 0);

    // out = h1 @ W2 + b2 + x2
    gemm_f32_kernel<<<dim3(D_/64, BT_/64), 256, 0, stream>>>(h1, W2, b2, x2, out, FFN_, D_, 1, 0);
}

// Round 2
// 1424.649 us; speedup vs baseline: 1.8060x; 1.8060x over previous
//
#include <hip/hip_runtime.h>
#include <hip/hip_bf16.h>
#include <math.h>

#define D_   1024
#define H_   16
#define DH_  64
#define FFN_ 4096
#define B_   4
#define T_   1024
#define M_   128
#define N_   64
#define PREF 192
#define L_   1216
#define BL_  (B_*L_)   // 4864
#define BT_  (B_*T_)   // 4096

typedef __attribute__((ext_vector_type(4))) float f32x4;
typedef __attribute__((ext_vector_type(8))) short bf16x8;
typedef const __attribute__((address_space(1))) void gvoid_t;
typedef __attribute__((address_space(3))) void lvoid_t;

__device__ __forceinline__ void gl_lds16(const void* g, void* l) {
    __builtin_amdgcn_global_load_lds((gvoid_t*)g, (lvoid_t*)l, 16, 0, 0);
}

__device__ __forceinline__ ushort f2bf(float x) {
    union { __hip_bfloat16 h; ushort u; } cv;
    cv.h = __float2bfloat16(x);
    return cv.u;
}

// ---------------- block reduce helper ----------------
__device__ __forceinline__ float block_reduce_sum256(float v, float* sbuf) {
#pragma unroll
    for (int o = 32; o > 0; o >>= 1) v += __shfl_xor(v, o, 64);
    int w = threadIdx.x >> 6;
    if ((threadIdx.x & 63) == 0) sbuf[w] = v;
    __syncthreads();
    float r = sbuf[0] + sbuf[1] + sbuf[2] + sbuf[3];
    __syncthreads();
    return r;
}

// ---------------- weight fp32 [K][Nc] -> bf16 W^T [Nc][K] ----------------
__global__ __launch_bounds__(256) void wtr_kernel(
    const float* __restrict__ W, ushort* __restrict__ Wt, int K, int Nc)
{
    __shared__ float tl[64][65];
    int c0 = blockIdx.x << 6, k0 = blockIdx.y << 6;
    int tid = threadIdx.x;
    int rr = tid >> 4, c4 = (tid & 15) << 2;
#pragma unroll
    for (int p = 0; p < 4; ++p) {
        int r = (p << 4) + rr;
        float4 v = *(const float4*)(W + (size_t)(k0 + r) * Nc + c0 + c4);
        tl[r][c4+0] = v.x; tl[r][c4+1] = v.y; tl[r][c4+2] = v.z; tl[r][c4+3] = v.w;
    }
    __syncthreads();
#pragma unroll
    for (int p = 0; p < 4; ++p) {
        int rT = (p << 4) + rr;          // row of Wt within tile (= col of W)
        ushort4 uv;
        uv.x = f2bf(tl[c4+0][rT]);
        uv.y = f2bf(tl[c4+1][rT]);
        uv.z = f2bf(tl[c4+2][rT]);
        uv.w = f2bf(tl[c4+3][rT]);
        *(ushort4*)(Wt + (size_t)(c0 + rT) * K + k0 + c4) = uv;
    }
}

// ---------------- concat + LayerNorm1: x_full f32, xa bf16 ----------------
__global__ __launch_bounds__(256) void ln1_concat_kernel(
    const float* __restrict__ x, const float* __restrict__ mem,
    const float* __restrict__ nmr, const float* __restrict__ g,
    const float* __restrict__ be, float* __restrict__ x_full,
    ushort* __restrict__ xa_bf)
{
    __shared__ float sbuf[4];
    int row = blockIdx.x;
    int b = row / L_, pos = row % L_;
    const float* src;
    if (pos < M_)          src = mem + ((size_t)b*M_ + pos)      * D_;
    else if (pos < M_+N_)  src = nmr + ((size_t)b*N_ + (pos-M_)) * D_;
    else                   src = x   + ((size_t)b*T_ + (pos-PREF))*D_;

    int c = threadIdx.x << 2;
    float4 v = *(const float4*)(src + c);
    float s = v.x + v.y + v.z + v.w;
    s = block_reduce_sum256(s, sbuf);
    float mu = s * (1.0f / D_);
    float dx = v.x - mu, dy = v.y - mu, dz = v.z - mu, dw = v.w - mu;
    float q = dx*dx + dy*dy + dz*dz + dw*dw;
    q = block_reduce_sum256(q, sbuf);
    float inv = rsqrtf(q * (1.0f / D_) + 1e-5f);
    float4 gv = *(const float4*)(g + c);
    float4 bv = *(const float4*)(be + c);
    ushort4 o;
    o.x = f2bf(dx*inv*gv.x + bv.x);
    o.y = f2bf(dy*inv*gv.y + bv.y);
    o.z = f2bf(dz*inv*gv.z + bv.z);
    o.w = f2bf(dw*inv*gv.w + bv.w);
    *(float4*)(x_full + (size_t)row*D_ + c) = v;
    *(ushort4*)(xa_bf + (size_t)row*D_ + c) = o;
}

// ---------------- LayerNorm2: f32 in, bf16 out ----------------
__global__ __launch_bounds__(256) void ln2_kernel(
    const float* __restrict__ src, const float* __restrict__ g,
    const float* __restrict__ be, ushort* __restrict__ dst)
{
    __shared__ float sbuf[4];
    int row = blockIdx.x;
    int c = threadIdx.x << 2;
    float4 v = *(const float4*)(src + (size_t)row*D_ + c);
    float s = v.x + v.y + v.z + v.w;
    s = block_reduce_sum256(s, sbuf);
    float mu = s * (1.0f / D_);
    float dx = v.x - mu, dy = v.y - mu, dz = v.z - mu, dw = v.w - mu;
    float q = dx*dx + dy*dy + dz*dz + dw*dw;
    q = block_reduce_sum256(q, sbuf);
    float inv = rsqrtf(q * (1.0f / D_) + 1e-5f);
    float4 gv = *(const float4*)(g + c);
    float4 bv = *(const float4*)(be + c);
    ushort4 o;
    o.x = f2bf(dx*inv*gv.x + bv.x);
    o.y = f2bf(dy*inv*gv.y + bv.y);
    o.z = f2bf(dz*inv*gv.z + bv.z);
    o.w = f2bf(dw*inv*gv.w + bv.w);
    *(ushort4*)(dst + (size_t)row*D_ + c) = o;
}

// ---------------- bf16 MFMA GEMM: C = A @ Bt^T (+bias, epilogue) ----------
// A: bf16 [Mr][K] row-major. Bt: bf16 [Nc][K] row-major (= W^T).
// mode 0: f32 out, +bias
// mode 1: f32 out, +bias +res (row-major [Mr][Nc])
// mode 2: f32 out, +bias +res strided (x_full row map, Nc==D_)
// mode 3: bf16 out, relu(+bias)^2
// LDS k-chunk swizzle: logical chunk c of row r stored at slot c ^ ((r>>1)&3).
__global__ __launch_bounds__(256) void gemm_bf16_kernel(
    const ushort* __restrict__ A, const ushort* __restrict__ Bt,
    const float* __restrict__ bias, const float* __restrict__ res,
    void* __restrict__ Cout, int Mr, int Nc, int K, int mode)
{
    __shared__ ushort As[128*32];
    __shared__ ushort Bs[128*32];
    int tid = threadIdx.x;
    int lane = tid & 63, w = tid >> 6;
    int wm = w >> 1, wn = w & 1;
    int row0 = blockIdx.y << 7, col0 = blockIdx.x << 7;
    int l15 = lane & 15, l4 = lane >> 4;

    f32x4 acc[4][4] = {};

    int r_a = tid >> 2;          // staging row (call adds 64)
    int sc  = tid & 3;           // stored slot

    for (int k0 = 0; k0 < K; k0 += 32) {
#pragma unroll
        for (int c = 0; c < 2; ++c) {
            int r = (c << 6) + r_a;
            int lc = sc ^ ((r >> 1) & 3);            // logical chunk to fetch
            gl_lds16(A  + (size_t)(row0 + r)*K + k0 + (lc << 3),
                     (char*)As + (((c << 8) + tid) << 4));
            gl_lds16(Bt + (size_t)(col0 + r)*K + k0 + (lc << 3),
                     (char*)Bs + (((c << 8) + tid) << 4));
        }
        __syncthreads();
        bf16x8 af[4], bfr[4];
#pragma unroll
        for (int i = 0; i < 4; ++i) {
            int ra = (wm << 6) + (i << 4) + l15;
            af[i]  = *(const bf16x8*)(As + ra*32 + ((l4 ^ ((ra >> 1) & 3)) << 3));
            int rb = (wn << 6) + (i << 4) + l15;
            bfr[i] = *(const bf16x8*)(Bs + rb*32 + ((l4 ^ ((rb >> 1) & 3)) << 3));
        }
#pragma unroll
        for (int i = 0; i < 4; ++i)
#pragma unroll
            for (int j = 0; j < 4; ++j)
                acc[i][j] = __builtin_amdgcn_mfma_f32_16x16x32_bf16(af[i], bfr[j], acc[i][j], 0, 0, 0);
        __syncthreads();
    }

    float bcol[4];
#pragma unroll
    for (int j = 0; j < 4; ++j) bcol[j] = bias[col0 + (wn << 6) + (j << 4) + l15];
    int orow0 = row0 + (wm << 6) + (l4 << 2);
    int ocol0 = col0 + (wn << 6) + l15;

    if (mode == 3) {
        ushort* O = (ushort*)Cout;
#pragma unroll
        for (int i = 0; i < 4; ++i)
#pragma unroll
            for (int j = 0; j < 4; ++j)
#pragma unroll
                for (int r = 0; r < 4; ++r) {
                    int row = orow0 + (i << 4) + r;
                    int col = ocol0 + (j << 4);
                    float v = acc[i][j][r] + bcol[j];
                    v = fmaxf(v, 0.f); v *= v;
                    O[(size_t)row*Nc + col] = f2bf(v);
                }
    } else {
        float* O = (float*)Cout;
#pragma unroll
        for (int i = 0; i < 4; ++i)
#pragma unroll
            for (int j = 0; j < 4; ++j)
#pragma unroll
                for (int r = 0; r < 4; ++r) {
                    int row = orow0 + (i << 4) + r;
                    int col = ocol0 + (j << 4);
                    float v = acc[i][j][r] + bcol[j];
                    if (mode == 1) {
                        v += res[(size_t)row*Nc + col];
                    } else if (mode == 2) {
                        int rr = (row >> 10)*L_ + PREF + (row & (T_-1));
                        v += res[(size_t)rr*D_ + col];
                    }
                    O[(size_t)row*Nc + col] = v;
                }
    }
}

// ---------------- RoPE (in place on q_lin and k_lin, fp32) ----------------
__global__ __launch_bounds__(256) void rope_kernel(
    float* __restrict__ q_lin, float* __restrict__ k_lin)
{
    int row = blockIdx.x;
    int pos = row % L_;
    int h = threadIdx.x >> 4, d = threadIdx.x & 15;
    float invf = powf(10000.0f, -(float)d * (1.0f / 16.0f));
    float th = (float)pos * invf;
    float sn, cs;
    sincosf(th, &sn, &cs);
    size_t base = (size_t)row * D_ + h * DH_;
    float a0 = q_lin[base + d], a1 = q_lin[base + d + 16];
    q_lin[base + d]      = a0 * cs - a1 * sn;
    q_lin[base + d + 16] = a1 * cs + a0 * sn;
    float b0 = k_lin[base + d], b1 = k_lin[base + d + 16];
    k_lin[base + d]      = b0 * cs - b1 * sn;
    k_lin[base + d + 16] = b1 * cs + b0 * sn;
}

// ---------------- causal attention (flash-style, fp32, bf16 out) ---------
__global__ __launch_bounds__(256) void attn_kernel(
    const float* __restrict__ q_lin, const float* __restrict__ k_lin,
    const float* __restrict__ v_lin, ushort* __restrict__ attn_bf)
{
    __shared__ float Ks[64][65];
    __shared__ float Vs[64][64];
    __shared__ float qs[16][64];

    int bid = blockIdx.x;
    int qg = bid & 63;
    int h  = (bid >> 6) & (H_ - 1);
    int b  = bid >> 10;
    int tid = threadIdx.x, lane = tid & 63, w = tid >> 6;
    int i0_blk = PREF + (qg << 4);

    {
        int r = tid >> 4, c4 = (tid & 15) << 2;
        float4 qv = *(const float4*)(q_lin + ((size_t)b*L_ + i0_blk + r)*D_ + h*DH_ + c4);
        *(float4*)(&qs[r][c4]) = qv;
    }

    int i_base = i0_blk + (w << 2);
    const int qb = w << 2;
    float acc0=0.f, acc1=0.f, acc2=0.f, acc3=0.f;
    float m0=-INFINITY, m1=-INFINITY, m2=-INFINITY, m3=-INFINITY;
    float l0=0.f, l1=0.f, l2=0.f, l3=0.f;

    int nkb = ((i0_blk + 15) >> 6) + 1;
    for (int jb = 0; jb < nkb; ++jb) {
        int j0 = jb << 6;
        __syncthreads();
#pragma unroll
        for (int s = 0; s < 4; ++s) {
            int idx = (s << 8) + tid;
            int r = idx >> 4, c4 = (idx & 15) << 2;
            size_t goff = ((size_t)b*L_ + j0 + r)*D_ + h*DH_ + c4;
            float4 kv = *(const float4*)(k_lin + goff);
            Ks[r][c4+0] = kv.x; Ks[r][c4+1] = kv.y;
            Ks[r][c4+2] = kv.z; Ks[r][c4+3] = kv.w;
            float4 vv = *(const float4*)(v_lin + goff);
            *(float4*)(&Vs[r][c4]) = vv;
        }
        __syncthreads();

        float s0=0.f, s1=0.f, s2=0.f, s3=0.f;
#pragma unroll 16
        for (int d = 0; d < 64; ++d) {
            float kd = Ks[lane][d];
            s0 = fmaf(qs[qb+0][d], kd, s0);
            s1 = fmaf(qs[qb+1][d], kd, s1);
            s2 = fmaf(qs[qb+2][d], kd, s2);
            s3 = fmaf(qs[qb+3][d], kd, s3);
        }
        int j = j0 + lane;
        s0 = (j <= i_base+0) ? s0 * 0.125f : -INFINITY;
        s1 = (j <= i_base+1) ? s1 * 0.125f : -INFINITY;
        s2 = (j <= i_base+2) ? s2 * 0.125f : -INFINITY;
        s3 = (j <= i_base+3) ? s3 * 0.125f : -INFINITY;

        float bm0=s0, bm1=s1, bm2=s2, bm3=s3;
#pragma unroll
        for (int o = 32; o > 0; o >>= 1) {
            bm0 = fmaxf(bm0, __shfl_xor(bm0, o, 64));
            bm1 = fmaxf(bm1, __shfl_xor(bm1, o, 64));
            bm2 = fmaxf(bm2, __shfl_xor(bm2, o, 64));
            bm3 = fmaxf(bm3, __shfl_xor(bm3, o, 64));
        }
        float nm0 = fmaxf(m0, bm0), nm1 = fmaxf(m1, bm1);
        float nm2 = fmaxf(m2, bm2), nm3 = fmaxf(m3, bm3);
        float c0 = expf(m0 - nm0), c1 = expf(m1 - nm1);
        float c2 = expf(m2 - nm2), c3 = expf(m3 - nm3);
        float p0 = expf(s0 - nm0), p1 = expf(s1 - nm1);
        float p2 = expf(s2 - nm2), p3 = expf(s3 - nm3);
        float ps0=p0, ps1=p1, ps2=p2, ps3=p3;
#pragma unroll
        for (int o = 32; o > 0; o >>= 1) {
            ps0 += __shfl_xor(ps0, o, 64);
            ps1 += __shfl_xor(ps1, o, 64);
            ps2 += __shfl_xor(ps2, o, 64);
            ps3 += __shfl_xor(ps3, o, 64);
        }
        l0 = l0*c0 + ps0; l1 = l1*c1 + ps1;
        l2 = l2*c2 + ps2; l3 = l3*c3 + ps3;
        acc0 *= c0; acc1 *= c1; acc2 *= c2; acc3 *= c3;
#pragma unroll 8
        for (int t = 0; t < 64; ++t) {
            float vv = Vs[t][lane];
            acc0 = fmaf(__shfl(p0, t, 64), vv, acc0);
            acc1 = fmaf(__shfl(p1, t, 64), vv, acc1);
            acc2 = fmaf(__shfl(p2, t, 64), vv, acc2);
            acc3 = fmaf(__shfl(p3, t, 64), vv, acc3);
        }
        m0 = nm0; m1 = nm1; m2 = nm2; m3 = nm3;
    }

    size_t obase = ((size_t)b*T_ + (i_base - PREF)) * D_ + h*DH_ + lane;
    attn_bf[obase]        = f2bf(acc0 / l0);
    attn_bf[obase + D_]   = f2bf(acc1 / l1);
    attn_bf[obase + 2*D_] = f2bf(acc2 / l2);
    attn_bf[obase + 3*D_] = f2bf(acc3 / l3);
}

// ---------------- launch ----------------
extern "C" void kernel_launch(void* const* d_in, const int* in_sizes, int n_in,
                              void* d_out, int out_size, void* d_ws, size_t ws_size,
                              hipStream_t stream) {
    const float* x   = (const float*)d_in[0];
    const float* mem = (const float*)d_in[1];
    const float* nmr = (const float*)d_in[2];
    const float* Wq  = (const float*)d_in[3];
    const float* bq  = (const float*)d_in[4];
    const float* Wk  = (const float*)d_in[5];
    const float* bk  = (const float*)d_in[6];
    const float* Wv  = (const float*)d_in[7];
    const float* bv  = (const float*)d_in[8];
    const float* Wo  = (const float*)d_in[9];
    const float* bo  = (const float*)d_in[10];
    const float* W1  = (const float*)d_in[11];
    const float* b1  = (const float*)d_in[12];
    const float* W2  = (const float*)d_in[13];
    const float* b2  = (const float*)d_in[14];
    const float* g1  = (const float*)d_in[15];
    const float* be1 = (const float*)d_in[16];
    const float* g2  = (const float*)d_in[17];
    const float* be2 = (const float*)d_in[18];
    float* out = (float*)d_out;

    float* f = (float*)d_ws;
    const size_t BLD = (size_t)BL_ * D_;
    const size_t BTD = (size_t)BT_ * D_;
    float* x_full = f;
    float* q_lin  = f + BLD;
    float* k_lin  = f + 2*BLD;
    float* v_lin  = f + 3*BLD;
    float* x2     = f + 4*BLD;                 // BTD floats
    ushort* bfb   = (ushort*)(f + 4*BLD + BTD);
    ushort* xa_bf   = bfb;                     // BLD elems; reused as attn_bf, ln2_bf
    ushort* attn_bf = bfb;
    ushort* ln2_bf  = bfb;
    ushort* h1_bf   = bfb + BLD;               // BT_*FFN_ elems
    ushort* wq_bf = h1_bf + (size_t)BT_*FFN_;
    ushort* wk_bf = wq_bf + (size_t)D_*D_;
    ushort* wv_bf = wk_bf + (size_t)D_*D_;
    ushort* wo_bf = wv_bf + (size_t)D_*D_;
    ushort* w1_bf = wo_bf + (size_t)D_*D_;
    ushort* w2_bf = w1_bf + (size_t)D_*FFN_;

    // weight prep: fp32 [K][N] -> bf16 [N][K]
    wtr_kernel<<<dim3(D_/64,   D_/64),   256, 0, stream>>>(Wq, wq_bf, D_,   D_);
    wtr_kernel<<<dim3(D_/64,   D_/64),   256, 0, stream>>>(Wk, wk_bf, D_,   D_);
    wtr_kernel<<<dim3(D_/64,   D_/64),   256, 0, stream>>>(Wv, wv_bf, D_,   D_);
    wtr_kernel<<<dim3(D_/64,   D_/64),   256, 0, stream>>>(Wo, wo_bf, D_,   D_);
    wtr_kernel<<<dim3(FFN_/64, D_/64),   256, 0, stream>>>(W1, w1_bf, D_,   FFN_);
    wtr_kernel<<<dim3(D_/64,   FFN_/64), 256, 0, stream>>>(W2, w2_bf, FFN_, D_);

    ln1_concat_kernel<<<BL_, 256, 0, stream>>>(x, mem, nmr, g1, be1, x_full, xa_bf);

    gemm_bf16_kernel<<<dim3(D_/128, BL_/128), 256, 0, stream>>>(xa_bf, wq_bf, bq, nullptr, q_lin, BL_, D_, D_, 0);
    gemm_bf16_kernel<<<dim3(D_/128, BL_/128), 256, 0, stream>>>(xa_bf, wk_bf, bk, nullptr, k_lin, BL_, D_, D_, 0);
    gemm_bf16_kernel<<<dim3(D_/128, BL_/128), 256, 0, stream>>>(xa_bf, wv_bf, bv, nullptr, v_lin, BL_, D_, D_, 0);

    rope_kernel<<<BL_, 256, 0, stream>>>(q_lin, k_lin);

    attn_kernel<<<B_*H_*(T_/16), 256, 0, stream>>>(q_lin, k_lin, v_lin, attn_bf);

    // x2 = attn @ Wo + bo + x_full[rows >= pref] (strided residual)
    gemm_bf16_kernel<<<dim3(D_/128, BT_/128), 256, 0, stream>>>(attn_bf, wo_bf, bo, x_full, x2, BT_, D_, D_, 2);

    ln2_kernel<<<BT_, 256, 0, stream>>>(x2, g2, be2, ln2_bf);

    // h1 = relu(xf @ W1 + b1)^2  (bf16 out)
    gemm_bf16_kernel<<<dim3(FFN_/128, BT_/128), 256, 0, stream>>>(ln2_bf, w1_bf, b1, nullptr, h1_bf, BT_, FFN_, D_, 3);

    // out = h1 @ W2 + b2 + x2
    gemm_bf16_kernel<<<dim3(D_/128, BT_/128), 256, 0, stream>>>(h1_bf, w2_bf, b2, x2, out, BT_, D_, FFN_, 1);
}

// Round 3
// 430.660 us; speedup vs baseline: 5.9743x; 3.3081x over previous
//
#include <hip/hip_runtime.h>
#include <hip/hip_bf16.h>
#include <math.h>

#define D_   1024
#define H_   16
#define DH_  64
#define FFN_ 4096
#define B_   4
#define T_   1024
#define M_   128
#define N_   64
#define PREF 192
#define L_   1216
#define BL_  (B_*L_)   // 4864
#define BT_  (B_*T_)   // 4096

typedef __attribute__((ext_vector_type(4))) float f32x4;
typedef __attribute__((ext_vector_type(8))) short bf16x8;
typedef const __attribute__((address_space(1))) void gvoid_t;
typedef __attribute__((address_space(3))) void lvoid_t;

__device__ __forceinline__ void gl_lds16(const void* g, void* l) {
    __builtin_amdgcn_global_load_lds((gvoid_t*)g, (lvoid_t*)l, 16, 0, 0);
}

__device__ __forceinline__ ushort f2bf(float x) {
    union { __hip_bfloat16 h; ushort u; } cv;
    cv.h = __float2bfloat16(x);
    return cv.u;
}

// ---------------- block reduce helper ----------------
__device__ __forceinline__ float block_reduce_sum256(float v, float* sbuf) {
#pragma unroll
    for (int o = 32; o > 0; o >>= 1) v += __shfl_xor(v, o, 64);
    int w = threadIdx.x >> 6;
    if ((threadIdx.x & 63) == 0) sbuf[w] = v;
    __syncthreads();
    float r = sbuf[0] + sbuf[1] + sbuf[2] + sbuf[3];
    __syncthreads();
    return r;
}

// ---------------- weight fp32 [K][Nc] -> bf16 W^T [Nc][K] ----------------
__global__ __launch_bounds__(256) void wtr_kernel(
    const float* __restrict__ W, ushort* __restrict__ Wt, int K, int Nc)
{
    __shared__ float tl[64][65];
    int c0 = blockIdx.x << 6, k0 = blockIdx.y << 6;
    int tid = threadIdx.x;
    int rr = tid >> 4, c4 = (tid & 15) << 2;
#pragma unroll
    for (int p = 0; p < 4; ++p) {
        int r = (p << 4) + rr;
        float4 v = *(const float4*)(W + (size_t)(k0 + r) * Nc + c0 + c4);
        tl[r][c4+0] = v.x; tl[r][c4+1] = v.y; tl[r][c4+2] = v.z; tl[r][c4+3] = v.w;
    }
    __syncthreads();
#pragma unroll
    for (int p = 0; p < 4; ++p) {
        int rT = (p << 4) + rr;
        ushort4 uv;
        uv.x = f2bf(tl[c4+0][rT]);
        uv.y = f2bf(tl[c4+1][rT]);
        uv.z = f2bf(tl[c4+2][rT]);
        uv.w = f2bf(tl[c4+3][rT]);
        *(ushort4*)(Wt + (size_t)(c0 + rT) * K + k0 + c4) = uv;
    }
}

// ---------------- concat + LayerNorm1: x_full f32, xa bf16 ----------------
__global__ __launch_bounds__(256) void ln1_concat_kernel(
    const float* __restrict__ x, const float* __restrict__ mem,
    const float* __restrict__ nmr, const float* __restrict__ g,
    const float* __restrict__ be, float* __restrict__ x_full,
    ushort* __restrict__ xa_bf)
{
    __shared__ float sbuf[4];
    int row = blockIdx.x;
    int b = row / L_, pos = row % L_;
    const float* src;
    if (pos < M_)          src = mem + ((size_t)b*M_ + pos)      * D_;
    else if (pos < M_+N_)  src = nmr + ((size_t)b*N_ + (pos-M_)) * D_;
    else                   src = x   + ((size_t)b*T_ + (pos-PREF))*D_;

    int c = threadIdx.x << 2;
    float4 v = *(const float4*)(src + c);
    float s = v.x + v.y + v.z + v.w;
    s = block_reduce_sum256(s, sbuf);
    float mu = s * (1.0f / D_);
    float dx = v.x - mu, dy = v.y - mu, dz = v.z - mu, dw = v.w - mu;
    float q = dx*dx + dy*dy + dz*dz + dw*dw;
    q = block_reduce_sum256(q, sbuf);
    float inv = rsqrtf(q * (1.0f / D_) + 1e-5f);
    float4 gv = *(const float4*)(g + c);
    float4 bv = *(const float4*)(be + c);
    ushort4 o;
    o.x = f2bf(dx*inv*gv.x + bv.x);
    o.y = f2bf(dy*inv*gv.y + bv.y);
    o.z = f2bf(dz*inv*gv.z + bv.z);
    o.w = f2bf(dw*inv*gv.w + bv.w);
    *(float4*)(x_full + (size_t)row*D_ + c) = v;
    *(ushort4*)(xa_bf + (size_t)row*D_ + c) = o;
}

// ---------------- LayerNorm2: f32 in, bf16 out ----------------
__global__ __launch_bounds__(256) void ln2_kernel(
    const float* __restrict__ src, const float* __restrict__ g,
    const float* __restrict__ be, ushort* __restrict__ dst)
{
    __shared__ float sbuf[4];
    int row = blockIdx.x;
    int c = threadIdx.x << 2;
    float4 v = *(const float4*)(src + (size_t)row*D_ + c);
    float s = v.x + v.y + v.z + v.w;
    s = block_reduce_sum256(s, sbuf);
    float mu = s * (1.0f / D_);
    float dx = v.x - mu, dy = v.y - mu, dz = v.z - mu, dw = v.w - mu;
    float q = dx*dx + dy*dy + dz*dz + dw*dw;
    q = block_reduce_sum256(q, sbuf);
    float inv = rsqrtf(q * (1.0f / D_) + 1e-5f);
    float4 gv = *(const float4*)(g + c);
    float4 bv = *(const float4*)(be + c);
    ushort4 o;
    o.x = f2bf(dx*inv*gv.x + bv.x);
    o.y = f2bf(dy*inv*gv.y + bv.y);
    o.z = f2bf(dz*inv*gv.z + bv.z);
    o.w = f2bf(dw*inv*gv.w + bv.w);
    *(ushort4*)(dst + (size_t)row*D_ + c) = o;
}

// ---------------- bf16 MFMA GEMM: C = A @ Bt^T (+bias, epilogue) ----------
// A: bf16 [Mr][K] row-major. Bt: bf16 [Nc][K] row-major (= W^T).
// mode 0: f32 out, +bias
// mode 1: f32 out, +bias +res (row-major [Mr][Nc])
// mode 2: f32 out, +bias +res strided (x_full row map, Nc==D_)
// mode 3: bf16 out, relu(+bias)^2
// mode 5: bf16 out transposed head-major [b][h][d][L]   (V path)
// mode 6: bf16 out + RoPE, head-major [b][h][pos][64]   (Q/K path)
__global__ __launch_bounds__(256) void gemm_bf16_kernel(
    const ushort* __restrict__ A, const ushort* __restrict__ Bt,
    const float* __restrict__ bias, const float* __restrict__ res,
    void* __restrict__ Cout, int Mr, int Nc, int K, int mode)
{
    __shared__ ushort As[128*32];
    __shared__ ushort Bs[128*32];
    int tid = threadIdx.x;
    int lane = tid & 63, w = tid >> 6;
    int wm = w >> 1, wn = w & 1;
    int row0 = blockIdx.y << 7, col0 = blockIdx.x << 7;
    int l15 = lane & 15, l4 = lane >> 4;

    f32x4 acc[4][4] = {};

    int r_a = tid >> 2;
    int sc  = tid & 3;

    for (int k0 = 0; k0 < K; k0 += 32) {
#pragma unroll
        for (int c = 0; c < 2; ++c) {
            int r = (c << 6) + r_a;
            int lc = sc ^ ((r >> 1) & 3);
            gl_lds16(A  + (size_t)(row0 + r)*K + k0 + (lc << 3),
                     (char*)As + (((c << 8) + tid) << 4));
            gl_lds16(Bt + (size_t)(col0 + r)*K + k0 + (lc << 3),
                     (char*)Bs + (((c << 8) + tid) << 4));
        }
        __syncthreads();
        bf16x8 af[4], bfr[4];
#pragma unroll
        for (int i = 0; i < 4; ++i) {
            int ra = (wm << 6) + (i << 4) + l15;
            af[i]  = *(const bf16x8*)(As + ra*32 + ((l4 ^ ((ra >> 1) & 3)) << 3));
            int rb = (wn << 6) + (i << 4) + l15;
            bfr[i] = *(const bf16x8*)(Bs + rb*32 + ((l4 ^ ((rb >> 1) & 3)) << 3));
        }
#pragma unroll
        for (int i = 0; i < 4; ++i)
#pragma unroll
            for (int j = 0; j < 4; ++j)
                acc[i][j] = __builtin_amdgcn_mfma_f32_16x16x32_bf16(af[i], bfr[j], acc[i][j], 0, 0, 0);
        __syncthreads();
    }

    float bcol[4];
#pragma unroll
    for (int j = 0; j < 4; ++j) bcol[j] = bias[col0 + (wn << 6) + (j << 4) + l15];
    int orow0 = row0 + (wm << 6) + (l4 << 2);
    int ocol0 = col0 + (wn << 6) + l15;

    if (mode == 3) {
        ushort* O = (ushort*)Cout;
#pragma unroll
        for (int i = 0; i < 4; ++i)
#pragma unroll
            for (int j = 0; j < 4; ++j)
#pragma unroll
                for (int r = 0; r < 4; ++r) {
                    int row = orow0 + (i << 4) + r;
                    int col = ocol0 + (j << 4);
                    float v = acc[i][j][r] + bcol[j];
                    v = fmaxf(v, 0.f); v *= v;
                    O[(size_t)row*Nc + col] = f2bf(v);
                }
    } else if (mode == 5) {        // V: bf16 transposed head-major [b][h][d][L]
        ushort* O = (ushort*)Cout;
        int hh = (col0 + (wn << 6)) >> 6;
#pragma unroll
        for (int i = 0; i < 4; ++i)
#pragma unroll
            for (int r = 0; r < 4; ++r) {
                int row = orow0 + (i << 4) + r;
                int bb = row / L_;
                int pos = row - bb * L_;
                size_t base = ((size_t)(bb * H_ + hh) * 64) * L_ + pos;
#pragma unroll
                for (int j = 0; j < 4; ++j) {
                    int d = (j << 4) + l15;
                    O[base + (size_t)d * L_] = f2bf(acc[i][j][r] + bcol[j]);
                }
            }
    } else if (mode == 6) {        // Q/K: RoPE + bf16 head-major [b][h][pos][64]
        ushort* O = (ushort*)Cout;
        int hh = (col0 + (wn << 6)) >> 6;
        float invf = exp2f(-(float)l15 * 0.83048202372f);   // 10000^(-l15/16)
#pragma unroll
        for (int i = 0; i < 4; ++i)
#pragma unroll
            for (int r = 0; r < 4; ++r) {
                int row = orow0 + (i << 4) + r;
                int bb = row / L_;
                int pos = row - bb * L_;
                float sn, cs;
                sincosf((float)pos * invf, &sn, &cs);
                float v0 = acc[i][0][r] + bcol[0];
                float v1 = acc[i][1][r] + bcol[1];
                float v2 = acc[i][2][r] + bcol[2];
                float v3 = acc[i][3][r] + bcol[3];
                size_t base = ((size_t)(bb * H_ + hh) * L_ + pos) << 6;
                O[base + l15]      = f2bf(v0 * cs - v1 * sn);
                O[base + 16 + l15] = f2bf(v1 * cs + v0 * sn);
                O[base + 32 + l15] = f2bf(v2);
                O[base + 48 + l15] = f2bf(v3);
            }
    } else {
        float* O = (float*)Cout;
#pragma unroll
        for (int i = 0; i < 4; ++i)
#pragma unroll
            for (int j = 0; j < 4; ++j)
#pragma unroll
                for (int r = 0; r < 4; ++r) {
                    int row = orow0 + (i << 4) + r;
                    int col = ocol0 + (j << 4);
                    float v = acc[i][j][r] + bcol[j];
                    if (mode == 1) {
                        v += res[(size_t)row*Nc + col];
                    } else if (mode == 2) {
                        int rr = (row >> 10)*L_ + PREF + (row & (T_-1));
                        v += res[(size_t)rr*D_ + col];
                    }
                    O[(size_t)row*Nc + col] = v;
                }
    }
}

// ---------------- MFMA flash attention -----------------------------------
// grid: B*H*(T/64) blocks, 256 threads (4 waves, 16 q-rows each).
// qhd/khd: bf16 [b][h][pos][64]; vt: bf16 [b][h][d][L]; out: bf16 [b*T][D].
// KV tiles of 64 keys; only the last tile needs the causal mask
// (PREF and i0 are 64-aligned, prefix is always fully allowed).
__global__ __launch_bounds__(256) void attn_mfma_kernel(
    const ushort* __restrict__ qhd, const ushort* __restrict__ khd,
    const ushort* __restrict__ vt, ushort* __restrict__ attn_bf)
{
    __shared__ ushort Ks[64*64];      // [key][d], 16B slots XOR-swizzled
    __shared__ ushort Vs[64*64];      // [d][key] (V^T), swizzled
    __shared__ ushort Ps[4*16*64];    // per-wave P tile, swizzled

    int bid = blockIdx.x;
    int qb = 15 - (bid & 15);         // heavy blocks first
    int h  = (bid >> 4) & (H_ - 1);
    int b  = bid >> 8;
    int tid = threadIdx.x, lane = tid & 63, w = tid >> 6;
    int l15 = lane & 15, lg = lane >> 4;
    int i0 = PREF + (qb << 6);
    int wq0 = w << 4;
    size_t bh = (size_t)(b * H_ + h);

    // Q A-fragments: row = l15 (wave-local q), k = c*32 + lg*8
    const ushort* qrow = qhd + (bh * L_ + i0 + wq0 + l15) * 64;
    bf16x8 aq0 = *(const bf16x8*)(qrow + (lg << 3));
    bf16x8 aq1 = *(const bf16x8*)(qrow + 32 + (lg << 3));

    f32x4 acc_o[4] = {};
    float m[4]    = {-INFINITY, -INFINITY, -INFINITY, -INFINITY};
    float lsum[4] = {0.f, 0.f, 0.f, 0.f};

    int srow = tid >> 3;      // 0..31 staging row
    int sslot = tid & 7;
    ushort* Ps_w = Ps + (w << 10);

    int ntile = 4 + qb;
    for (int t = 0; t < ntile; ++t) {
        int j0 = t << 6;
#pragma unroll
        for (int c = 0; c < 2; ++c) {
            int row = (c << 5) + srow;
            int lc = sslot ^ (row & 7);
            gl_lds16(khd + (bh * L_ + j0 + row) * 64 + (lc << 3),
                     (char*)Ks + (((c << 8) + tid) << 4));
            gl_lds16(vt + (bh * 64 + row) * L_ + j0 + (lc << 3),
                     (char*)Vs + (((c << 8) + tid) << 4));
        }
        __syncthreads();

        // S = Q K^T (4 key-subtiles of 16)
        f32x4 s4[4];
#pragma unroll
        for (int st = 0; st < 4; ++st) {
            int rk = (st << 4) + l15;
            bf16x8 bk0 = *(const bf16x8*)(Ks + (rk << 6) + ((lg       ^ (rk & 7)) << 3));
            bf16x8 bk1 = *(const bf16x8*)(Ks + (rk << 6) + (((4 + lg) ^ (rk & 7)) << 3));
            f32x4 z = {};
            z = __builtin_amdgcn_mfma_f32_16x16x32_bf16(aq0, bk0, z, 0, 0, 0);
            z = __builtin_amdgcn_mfma_f32_16x16x32_bf16(aq1, bk1, z, 0, 0, 0);
            s4[st] = z;
        }
        bool diag = (t == ntile - 1);
        float p[4][4];
#pragma unroll
        for (int r = 0; r < 4; ++r) {
            int qloc = wq0 + (lg << 2) + r;
            float sv[4];
#pragma unroll
            for (int st = 0; st < 4; ++st) {
                float s = s4[st][r] * 0.125f;
                if (diag && ((st << 4) + l15 > qloc)) s = -INFINITY;
                sv[st] = s;
            }
            float bm = fmaxf(fmaxf(sv[0], sv[1]), fmaxf(sv[2], sv[3]));
#pragma unroll
            for (int o = 1; o < 16; o <<= 1) bm = fmaxf(bm, __shfl_xor(bm, o, 64));
            float mn = fmaxf(m[r], bm);
            float cr = expf(m[r] - mn);
            m[r] = mn;
            float ps = 0.f;
#pragma unroll
            for (int st = 0; st < 4; ++st) {
                float pe = expf(sv[st] - mn);
                p[st][r] = pe; ps += pe;
            }
#pragma unroll
            for (int o = 1; o < 16; o <<= 1) ps += __shfl_xor(ps, o, 64);
            lsum[r] = lsum[r] * cr + ps;
#pragma unroll
            for (int su = 0; su < 4; ++su) acc_o[su][r] *= cr;
        }
        // P -> LDS (bf16, swizzled); wave-private region, no barrier needed
#pragma unroll
        for (int st = 0; st < 4; ++st) {
            int slot = (st << 1) + (l15 >> 3);
            int k7 = l15 & 7;
#pragma unroll
            for (int r = 0; r < 4; ++r) {
                int q = (lg << 2) + r;
                Ps_w[(q << 6) + ((slot ^ (q & 7)) << 3) + k7] = f2bf(p[st][r]);
            }
        }
        // PV: O += P @ V
        {
            bf16x8 ap0 = *(const bf16x8*)(Ps_w + (l15 << 6) + ((lg       ^ (l15 & 7)) << 3));
            bf16x8 ap1 = *(const bf16x8*)(Ps_w + (l15 << 6) + (((4 + lg) ^ (l15 & 7)) << 3));
#pragma unroll
            for (int su = 0; su < 4; ++su) {
                int rd = (su << 4) + l15;
                bf16x8 bv0 = *(const bf16x8*)(Vs + (rd << 6) + ((lg       ^ (rd & 7)) << 3));
                bf16x8 bv1 = *(const bf16x8*)(Vs + (rd << 6) + (((4 + lg) ^ (rd & 7)) << 3));
                acc_o[su] = __builtin_amdgcn_mfma_f32_16x16x32_bf16(ap0, bv0, acc_o[su], 0, 0, 0);
                acc_o[su] = __builtin_amdgcn_mfma_f32_16x16x32_bf16(ap1, bv1, acc_o[su], 0, 0, 0);
            }
        }
        __syncthreads();
    }

    float rl[4];
#pragma unroll
    for (int r = 0; r < 4; ++r) rl[r] = 1.0f / lsum[r];
    size_t orow = (size_t)b * T_ + (i0 - PREF) + wq0 + (lg << 2);
#pragma unroll
    for (int su = 0; su < 4; ++su)
#pragma unroll
        for (int r = 0; r < 4; ++r)
            attn_bf[(orow + r) * D_ + (h << 6) + (su << 4) + l15] =
                f2bf(acc_o[su][r] * rl[r]);
}

// ---------------- launch ----------------
extern "C" void kernel_launch(void* const* d_in, const int* in_sizes, int n_in,
                              void* d_out, int out_size, void* d_ws, size_t ws_size,
                              hipStream_t stream) {
    const float* x   = (const float*)d_in[0];
    const float* mem = (const float*)d_in[1];
    const float* nmr = (const float*)d_in[2];
    const float* Wq  = (const float*)d_in[3];
    const float* bq  = (const float*)d_in[4];
    const float* Wk  = (const float*)d_in[5];
    const float* bk  = (const float*)d_in[6];
    const float* Wv  = (const float*)d_in[7];
    const float* bv  = (const float*)d_in[8];
    const float* Wo  = (const float*)d_in[9];
    const float* bo  = (const float*)d_in[10];
    const float* W1  = (const float*)d_in[11];
    const float* b1  = (const float*)d_in[12];
    const float* W2  = (const float*)d_in[13];
    const float* b2  = (const float*)d_in[14];
    const float* g1  = (const float*)d_in[15];
    const float* be1 = (const float*)d_in[16];
    const float* g2  = (const float*)d_in[17];
    const float* be2 = (const float*)d_in[18];
    float* out = (float*)d_out;

    float* f = (float*)d_ws;
    const size_t BLD = (size_t)BL_ * D_;
    const size_t BTD = (size_t)BT_ * D_;
    float* x_full = f;                         // BLD f32
    float* x2     = f + BLD;                   // BTD f32
    ushort* bfb   = (ushort*)(f + BLD + BTD);
    ushort* xa_bf   = bfb;                     // BLD
    ushort* qhd     = bfb + BLD;               // BLD
    ushort* khd     = bfb + 2*BLD;             // BLD
    ushort* vt      = bfb + 3*BLD;             // BLD
    ushort* attn_bf = bfb + 4*BLD;             // BTD
    ushort* ln2_bf  = bfb + 4*BLD + BTD;       // BTD
    ushort* h1_bf   = bfb + 4*BLD + 2*BTD;     // BT_*FFN_
    ushort* wq_bf = h1_bf + (size_t)BT_*FFN_;
    ushort* wk_bf = wq_bf + (size_t)D_*D_;
    ushort* wv_bf = wk_bf + (size_t)D_*D_;
    ushort* wo_bf = wv_bf + (size_t)D_*D_;
    ushort* w1_bf = wo_bf + (size_t)D_*D_;
    ushort* w2_bf = w1_bf + (size_t)D_*FFN_;

    // weight prep
    wtr_kernel<<<dim3(D_/64,   D_/64),   256, 0, stream>>>(Wq, wq_bf, D_,   D_);
    wtr_kernel<<<dim3(D_/64,   D_/64),   256, 0, stream>>>(Wk, wk_bf, D_,   D_);
    wtr_kernel<<<dim3(D_/64,   D_/64),   256, 0, stream>>>(Wv, wv_bf, D_,   D_);
    wtr_kernel<<<dim3(D_/64,   D_/64),   256, 0, stream>>>(Wo, wo_bf, D_,   D_);
    wtr_kernel<<<dim3(FFN_/64, D_/64),   256, 0, stream>>>(W1, w1_bf, D_,   FFN_);
    wtr_kernel<<<dim3(D_/64,   FFN_/64), 256, 0, stream>>>(W2, w2_bf, FFN_, D_);

    ln1_concat_kernel<<<BL_, 256, 0, stream>>>(x, mem, nmr, g1, be1, x_full, xa_bf);

    // QKV projections with fused RoPE / head-major layout epilogues
    gemm_bf16_kernel<<<dim3(D_/128, BL_/128), 256, 0, stream>>>(xa_bf, wq_bf, bq, nullptr, qhd, BL_, D_, D_, 6);
    gemm_bf16_kernel<<<dim3(D_/128, BL_/128), 256, 0, stream>>>(xa_bf, wk_bf, bk, nullptr, khd, BL_, D_, D_, 6);
    gemm_bf16_kernel<<<dim3(D_/128, BL_/128), 256, 0, stream>>>(xa_bf, wv_bf, bv, nullptr, vt,  BL_, D_, D_, 5);

    attn_mfma_kernel<<<B_*H_*(T_/64), 256, 0, stream>>>(qhd, khd, vt, attn_bf);

    // x2 = attn @ Wo + bo + x_full[rows >= pref]
    gemm_bf16_kernel<<<dim3(D_/128, BT_/128), 256, 0, stream>>>(attn_bf, wo_bf, bo, x_full, x2, BT_, D_, D_, 2);

    ln2_kernel<<<BT_, 256, 0, stream>>>(x2, g2, be2, ln2_bf);

    // h1 = relu(xf @ W1 + b1)^2
    gemm_bf16_kernel<<<dim3(FFN_/128, BT_/128), 256, 0, stream>>>(ln2_bf, w1_bf, b1, nullptr, h1_bf, BT_, FFN_, D_, 3);

    // out = h1 @ W2 + b2 + x2
    gemm_bf16_kernel<<<dim3(D_/128, BT_/128), 256, 0, stream>>>(h1_bf, w2_bf, b2, x2, out, BT_, D_, FFN_, 1);
}

// Round 4
// 350.191 us; speedup vs baseline: 7.3471x; 1.2298x over previous
//
#include <hip/hip_runtime.h>
#include <hip/hip_bf16.h>
#include <math.h>

#define D_   1024
#define H_   16
#define DH_  64
#define FFN_ 4096
#define B_   4
#define T_   1024
#define M_   128
#define N_   64
#define PREF 192
#define L_   1216
#define BL_  (B_*L_)   // 4864
#define BT_  (B_*T_)   // 4096

typedef __attribute__((ext_vector_type(4))) float f32x4;
typedef __attribute__((ext_vector_type(8))) short bf16x8;
typedef const __attribute__((address_space(1))) void gvoid_t;
typedef __attribute__((address_space(3))) void lvoid_t;

__device__ __forceinline__ void gl_lds16(const void* g, void* l) {
    __builtin_amdgcn_global_load_lds((gvoid_t*)g, (lvoid_t*)l, 16, 0, 0);
}

__device__ __forceinline__ ushort f2bf(float x) {
    union { __hip_bfloat16 h; ushort u; } cv;
    cv.h = __float2bfloat16(x);
    return cv.u;
}

// ---------------- block reduce helper ----------------
__device__ __forceinline__ float block_reduce_sum256(float v, float* sbuf) {
#pragma unroll
    for (int o = 32; o > 0; o >>= 1) v += __shfl_xor(v, o, 64);
    int w = threadIdx.x >> 6;
    if ((threadIdx.x & 63) == 0) sbuf[w] = v;
    __syncthreads();
    float r = sbuf[0] + sbuf[1] + sbuf[2] + sbuf[3];
    __syncthreads();
    return r;
}

// ---------------- weight fp32 [K][Nc] -> bf16 W^T [Nc][K] ----------------
__global__ __launch_bounds__(256) void wtr_kernel(
    const float* __restrict__ W, ushort* __restrict__ Wt, int K, int Nc)
{
    __shared__ float tl[64][65];
    int c0 = blockIdx.x << 6, k0 = blockIdx.y << 6;
    int tid = threadIdx.x;
    int rr = tid >> 4, c4 = (tid & 15) << 2;
#pragma unroll
    for (int p = 0; p < 4; ++p) {
        int r = (p << 4) + rr;
        float4 v = *(const float4*)(W + (size_t)(k0 + r) * Nc + c0 + c4);
        tl[r][c4+0] = v.x; tl[r][c4+1] = v.y; tl[r][c4+2] = v.z; tl[r][c4+3] = v.w;
    }
    __syncthreads();
#pragma unroll
    for (int p = 0; p < 4; ++p) {
        int rT = (p << 4) + rr;
        ushort4 uv;
        uv.x = f2bf(tl[c4+0][rT]);
        uv.y = f2bf(tl[c4+1][rT]);
        uv.z = f2bf(tl[c4+2][rT]);
        uv.w = f2bf(tl[c4+3][rT]);
        *(ushort4*)(Wt + (size_t)(c0 + rT) * K + k0 + c4) = uv;
    }
}

// ---------------- bias concat (bq|bk|bv -> 3072) ----------------
__global__ __launch_bounds__(256) void bias_cat_kernel(
    const float* __restrict__ bq, const float* __restrict__ bk,
    const float* __restrict__ bv, float* __restrict__ o)
{
    int i = blockIdx.x * 256 + threadIdx.x;
    float v = (i < 1024) ? bq[i] : (i < 2048 ? bk[i - 1024] : bv[i - 2048]);
    o[i] = v;
}

// ---------------- concat + LayerNorm1: x_full f32, xa bf16 ----------------
__global__ __launch_bounds__(256) void ln1_concat_kernel(
    const float* __restrict__ x, const float* __restrict__ mem,
    const float* __restrict__ nmr, const float* __restrict__ g,
    const float* __restrict__ be, float* __restrict__ x_full,
    ushort* __restrict__ xa_bf)
{
    __shared__ float sbuf[4];
    int row = blockIdx.x;
    int b = row / L_, pos = row % L_;
    const float* src;
    if (pos < M_)          src = mem + ((size_t)b*M_ + pos)      * D_;
    else if (pos < M_+N_)  src = nmr + ((size_t)b*N_ + (pos-M_)) * D_;
    else                   src = x   + ((size_t)b*T_ + (pos-PREF))*D_;

    int c = threadIdx.x << 2;
    float4 v = *(const float4*)(src + c);
    float s = v.x + v.y + v.z + v.w;
    s = block_reduce_sum256(s, sbuf);
    float mu = s * (1.0f / D_);
    float dx = v.x - mu, dy = v.y - mu, dz = v.z - mu, dw = v.w - mu;
    float q = dx*dx + dy*dy + dz*dz + dw*dw;
    q = block_reduce_sum256(q, sbuf);
    float inv = rsqrtf(q * (1.0f / D_) + 1e-5f);
    float4 gv = *(const float4*)(g + c);
    float4 bv = *(const float4*)(be + c);
    ushort4 o;
    o.x = f2bf(dx*inv*gv.x + bv.x);
    o.y = f2bf(dy*inv*gv.y + bv.y);
    o.z = f2bf(dz*inv*gv.z + bv.z);
    o.w = f2bf(dw*inv*gv.w + bv.w);
    *(float4*)(x_full + (size_t)row*D_ + c) = v;
    *(ushort4*)(xa_bf + (size_t)row*D_ + c) = o;
}

// ---------------- LayerNorm2 (fallback path): f32 in, bf16 out ------------
__global__ __launch_bounds__(256) void ln2_kernel(
    const float* __restrict__ src, const float* __restrict__ g,
    const float* __restrict__ be, ushort* __restrict__ dst)
{
    __shared__ float sbuf[4];
    int row = blockIdx.x;
    int c = threadIdx.x << 2;
    float4 v = *(const float4*)(src + (size_t)row*D_ + c);
    float s = v.x + v.y + v.z + v.w;
    s = block_reduce_sum256(s, sbuf);
    float mu = s * (1.0f / D_);
    float dx = v.x - mu, dy = v.y - mu, dz = v.z - mu, dw = v.w - mu;
    float q = dx*dx + dy*dy + dz*dz + dw*dw;
    q = block_reduce_sum256(q, sbuf);
    float inv = rsqrtf(q * (1.0f / D_) + 1e-5f);
    float4 gv = *(const float4*)(g + c);
    float4 bv = *(const float4*)(be + c);
    ushort4 o;
    o.x = f2bf(dx*inv*gv.x + bv.x);
    o.y = f2bf(dy*inv*gv.y + bv.y);
    o.z = f2bf(dz*inv*gv.z + bv.z);
    o.w = f2bf(dw*inv*gv.w + bv.w);
    *(ushort4*)(dst + (size_t)row*D_ + c) = o;
}

// ---------------- split-K=2 reduce + residual + LayerNorm2 ----------------
// x2 = p0 + p1 + bo + x_full[strided]; ln2_bf = LN(x2)
__global__ __launch_bounds__(256) void reduce2_ln2_kernel(
    const float* __restrict__ part, const float* __restrict__ bo,
    const float* __restrict__ x_full, const float* __restrict__ g,
    const float* __restrict__ be, float* __restrict__ x2,
    ushort* __restrict__ ln2_bf)
{
    __shared__ float sbuf[4];
    int row = blockIdx.x;
    int c = threadIdx.x << 2;
    size_t o = (size_t)row * D_ + c;
    float4 a  = *(const float4*)(part + o);
    float4 b2 = *(const float4*)(part + (size_t)BT_*D_ + o);
    float4 bb = *(const float4*)(bo + c);
    int rr = (row >> 10)*L_ + PREF + (row & (T_-1));
    float4 rv = *(const float4*)(x_full + (size_t)rr*D_ + c);
    float4 v;
    v.x = a.x + b2.x + bb.x + rv.x;
    v.y = a.y + b2.y + bb.y + rv.y;
    v.z = a.z + b2.z + bb.z + rv.z;
    v.w = a.w + b2.w + bb.w + rv.w;
    *(float4*)(x2 + o) = v;

    float s = v.x + v.y + v.z + v.w;
    s = block_reduce_sum256(s, sbuf);
    float mu = s * (1.0f / D_);
    float dx = v.x - mu, dy = v.y - mu, dz = v.z - mu, dw = v.w - mu;
    float q = dx*dx + dy*dy + dz*dz + dw*dw;
    q = block_reduce_sum256(q, sbuf);
    float inv = rsqrtf(q * (1.0f / D_) + 1e-5f);
    float4 gv = *(const float4*)(g + c);
    float4 bv = *(const float4*)(be + c);
    ushort4 ov;
    ov.x = f2bf(dx*inv*gv.x + bv.x);
    ov.y = f2bf(dy*inv*gv.y + bv.y);
    ov.z = f2bf(dz*inv*gv.z + bv.z);
    ov.w = f2bf(dw*inv*gv.w + bv.w);
    *(ushort4*)(ln2_bf + o) = ov;
}

// ---------------- split-K=4 reduce + bias + residual -> out ----------------
__global__ __launch_bounds__(256) void reduce4_out_kernel(
    const float* __restrict__ part, const float* __restrict__ b2,
    const float* __restrict__ x2, float* __restrict__ out)
{
    int row = blockIdx.x;
    int c = threadIdx.x << 2;
    size_t o = (size_t)row * D_ + c;
    const size_t S = (size_t)BT_ * D_;
    float4 p0 = *(const float4*)(part + o);
    float4 p1 = *(const float4*)(part + S + o);
    float4 p2 = *(const float4*)(part + 2*S + o);
    float4 p3 = *(const float4*)(part + 3*S + o);
    float4 bb = *(const float4*)(b2 + c);
    float4 rv = *(const float4*)(x2 + o);
    float4 v;
    v.x = p0.x + p1.x + p2.x + p3.x + bb.x + rv.x;
    v.y = p0.y + p1.y + p2.y + p3.y + bb.y + rv.y;
    v.z = p0.z + p1.z + p2.z + p3.z + bb.z + rv.z;
    v.w = p0.w + p1.w + p2.w + p3.w + bb.w + rv.w;
    *(float4*)(out + o) = v;
}

// ---------------- bf16 MFMA GEMM, 2-phase double-buffered -----------------
// A: bf16 [*][Kstride] row-major. Bt: bf16 [*][Kstride] row-major (= W^T).
// K-chunk: kbase = blockIdx.z*Klen, inner loop over Klen.
// mode 1: f32 out, +bias +res (row-major)
// mode 2: f32 out, +bias +res strided (x_full row map)
// mode 3: bf16 out, relu(+bias)^2
// mode 4: f32 partial (no bias), out += blockIdx.z*BT_*D_
// mode 7: fused QKV epilogue (col0<1024: Q+RoPE, <2048: K+RoPE, else V^T)
__global__ __launch_bounds__(256) void gemm_bf16_kernel(
    const ushort* __restrict__ A, const ushort* __restrict__ Bt,
    const float* __restrict__ bias, const float* __restrict__ res,
    void* __restrict__ Cout, int Nc, int Kstride, int Klen, int mode)
{
    __shared__ ushort As[2][128*32];
    __shared__ ushort Bs[2][128*32];
    int tid = threadIdx.x;
    int lane = tid & 63, w = tid >> 6;
    int wm = w >> 1, wn = w & 1;
    int row0 = blockIdx.y << 7, col0 = blockIdx.x << 7;
    int l15 = lane & 15, l4 = lane >> 4;
    int kbase = blockIdx.z * Klen;

    f32x4 acc[4][4] = {};

    int r_a = tid >> 2;
    int sc  = tid & 3;
    int lcOff = (sc ^ ((r_a >> 1) & 3)) << 3;     // swizzled k-chunk (ushorts)
    const ushort* Arow  = A  + (size_t)(row0 + r_a)      * Kstride + kbase;
    const ushort* Arow2 = A  + (size_t)(row0 + 64 + r_a) * Kstride + kbase;
    const ushort* Brow  = Bt + (size_t)(col0 + r_a)      * Kstride + kbase;
    const ushort* Brow2 = Bt + (size_t)(col0 + 64 + r_a) * Kstride + kbase;

#define STAGE(buf, k0rel)                                                      \
    do {                                                                       \
        gl_lds16(Arow  + (k0rel) + lcOff, (char*)As[buf] + (tid << 4));        \
        gl_lds16(Arow2 + (k0rel) + lcOff, (char*)As[buf] + ((256+tid) << 4));  \
        gl_lds16(Brow  + (k0rel) + lcOff, (char*)Bs[buf] + (tid << 4));        \
        gl_lds16(Brow2 + (k0rel) + lcOff, (char*)Bs[buf] + ((256+tid) << 4));  \
    } while (0)

    STAGE(0, 0);
    __syncthreads();
    int cur = 0;
    for (int k0 = 0; k0 < Klen; k0 += 32) {
        if (k0 + 32 < Klen) STAGE(cur ^ 1, k0 + 32);
        bf16x8 af[4], bfr[4];
#pragma unroll
        for (int i = 0; i < 4; ++i) {
            int ra = (wm << 6) + (i << 4) + l15;
            af[i]  = *(const bf16x8*)(&As[cur][ra*32 + ((l4 ^ ((ra >> 1) & 3)) << 3)]);
            int rb = (wn << 6) + (i << 4) + l15;
            bfr[i] = *(const bf16x8*)(&Bs[cur][rb*32 + ((l4 ^ ((rb >> 1) & 3)) << 3)]);
        }
#pragma unroll
        for (int i = 0; i < 4; ++i)
#pragma unroll
            for (int j = 0; j < 4; ++j)
                acc[i][j] = __builtin_amdgcn_mfma_f32_16x16x32_bf16(af[i], bfr[j], acc[i][j], 0, 0, 0);
        __syncthreads();
        cur ^= 1;
    }
#undef STAGE

    float bcol[4] = {0.f, 0.f, 0.f, 0.f};
    if (mode != 4) {
#pragma unroll
        for (int j = 0; j < 4; ++j) bcol[j] = bias[col0 + (wn << 6) + (j << 4) + l15];
    }
    int orow0 = row0 + (wm << 6) + (l4 << 2);
    int ocol0 = col0 + (wn << 6) + l15;

    if (mode == 3) {
        ushort* O = (ushort*)Cout;
#pragma unroll
        for (int i = 0; i < 4; ++i)
#pragma unroll
            for (int j = 0; j < 4; ++j)
#pragma unroll
                for (int r = 0; r < 4; ++r) {
                    int row = orow0 + (i << 4) + r;
                    int col = ocol0 + (j << 4);
                    float v = acc[i][j][r] + bcol[j];
                    v = fmaxf(v, 0.f); v *= v;
                    O[(size_t)row*Nc + col] = f2bf(v);
                }
    } else if (mode == 4) {
        float* O = (float*)Cout + (size_t)blockIdx.z * ((size_t)BT_ * D_);
#pragma unroll
        for (int i = 0; i < 4; ++i)
#pragma unroll
            for (int j = 0; j < 4; ++j)
#pragma unroll
                for (int r = 0; r < 4; ++r) {
                    int row = orow0 + (i << 4) + r;
                    int col = ocol0 + (j << 4);
                    O[(size_t)row*Nc + col] = acc[i][j][r];
                }
    } else if (mode == 7) {
        int which = col0 >> 10;                     // 0 Q, 1 K, 2 V
        int lcol0 = col0 & 1023;
        ushort* O = (ushort*)Cout + (size_t)which * ((size_t)BL_ * D_);
        int hh = (lcol0 + (wn << 6)) >> 6;
        if (which < 2) {        // Q/K: RoPE + head-major [b][h][pos][64]
            float invf = exp2f(-(float)l15 * 0.83048202372f);  // 10000^(-l15/16)
#pragma unroll
            for (int i = 0; i < 4; ++i)
#pragma unroll
                for (int r = 0; r < 4; ++r) {
                    int row = orow0 + (i << 4) + r;
                    int bb = row / L_;
                    int pos = row - bb * L_;
                    float sn, cs;
                    sincosf((float)pos * invf, &sn, &cs);
                    float v0 = acc[i][0][r] + bcol[0];
                    float v1 = acc[i][1][r] + bcol[1];
                    float v2 = acc[i][2][r] + bcol[2];
                    float v3 = acc[i][3][r] + bcol[3];
                    size_t base = ((size_t)(bb * H_ + hh) * L_ + pos) << 6;
                    O[base + l15]      = f2bf(v0 * cs - v1 * sn);
                    O[base + 16 + l15] = f2bf(v1 * cs + v0 * sn);
                    O[base + 32 + l15] = f2bf(v2);
                    O[base + 48 + l15] = f2bf(v3);
                }
        } else {                // V: transposed head-major [b][h][d][L]
#pragma unroll
            for (int i = 0; i < 4; ++i)
#pragma unroll
                for (int r = 0; r < 4; ++r) {
                    int row = orow0 + (i << 4) + r;
                    int bb = row / L_;
                    int pos = row - bb * L_;
                    size_t base = ((size_t)(bb * H_ + hh) * 64) * L_ + pos;
#pragma unroll
                    for (int j = 0; j < 4; ++j) {
                        int d = (j << 4) + l15;
                        O[base + (size_t)d * L_] = f2bf(acc[i][j][r] + bcol[j]);
                    }
                }
        }
    } else {
        float* O = (float*)Cout;
#pragma unroll
        for (int i = 0; i < 4; ++i)
#pragma unroll
            for (int j = 0; j < 4; ++j)
#pragma unroll
                for (int r = 0; r < 4; ++r) {
                    int row = orow0 + (i << 4) + r;
                    int col = ocol0 + (j << 4);
                    float v = acc[i][j][r] + bcol[j];
                    if (mode == 1) {
                        v += res[(size_t)row*Nc + col];
                    } else if (mode == 2) {
                        int rr = (row >> 10)*L_ + PREF + (row & (T_-1));
                        v += res[(size_t)rr*D_ + col];
                    }
                    O[(size_t)row*Nc + col] = v;
                }
    }
}

// ---------------- MFMA flash attention -----------------------------------
__global__ __launch_bounds__(256) void attn_mfma_kernel(
    const ushort* __restrict__ qhd, const ushort* __restrict__ khd,
    const ushort* __restrict__ vt, ushort* __restrict__ attn_bf)
{
    __shared__ ushort Ks[64*64];
    __shared__ ushort Vs[64*64];
    __shared__ ushort Ps[4*16*64];

    int bid = blockIdx.x;
    int qb = 15 - (bid & 15);
    int h  = (bid >> 4) & (H_ - 1);
    int b  = bid >> 8;
    int tid = threadIdx.x, lane = tid & 63, w = tid >> 6;
    int l15 = lane & 15, lg = lane >> 4;
    int i0 = PREF + (qb << 6);
    int wq0 = w << 4;
    size_t bh = (size_t)(b * H_ + h);

    const ushort* qrow = qhd + (bh * L_ + i0 + wq0 + l15) * 64;
    bf16x8 aq0 = *(const bf16x8*)(qrow + (lg << 3));
    bf16x8 aq1 = *(const bf16x8*)(qrow + 32 + (lg << 3));

    f32x4 acc_o[4] = {};
    float m[4]    = {-INFINITY, -INFINITY, -INFINITY, -INFINITY};
    float lsum[4] = {0.f, 0.f, 0.f, 0.f};

    int srow = tid >> 3;
    int sslot = tid & 7;
    ushort* Ps_w = Ps + (w << 10);

    int ntile = 4 + qb;
    for (int t = 0; t < ntile; ++t) {
        int j0 = t << 6;
#pragma unroll
        for (int c = 0; c < 2; ++c) {
            int row = (c << 5) + srow;
            int lc = sslot ^ (row & 7);
            gl_lds16(khd + (bh * L_ + j0 + row) * 64 + (lc << 3),
                     (char*)Ks + (((c << 8) + tid) << 4));
            gl_lds16(vt + (bh * 64 + row) * L_ + j0 + (lc << 3),
                     (char*)Vs + (((c << 8) + tid) << 4));
        }
        __syncthreads();

        f32x4 s4[4];
#pragma unroll
        for (int st = 0; st < 4; ++st) {
            int rk = (st << 4) + l15;
            bf16x8 bk0 = *(const bf16x8*)(Ks + (rk << 6) + ((lg       ^ (rk & 7)) << 3));
            bf16x8 bk1 = *(const bf16x8*)(Ks + (rk << 6) + (((4 + lg) ^ (rk & 7)) << 3));
            f32x4 z = {};
            z = __builtin_amdgcn_mfma_f32_16x16x32_bf16(aq0, bk0, z, 0, 0, 0);
            z = __builtin_amdgcn_mfma_f32_16x16x32_bf16(aq1, bk1, z, 0, 0, 0);
            s4[st] = z;
        }
        bool diag = (t == ntile - 1);
        float p[4][4];
#pragma unroll
        for (int r = 0; r < 4; ++r) {
            int qloc = wq0 + (lg << 2) + r;
            float sv[4];
#pragma unroll
            for (int st = 0; st < 4; ++st) {
                float s = s4[st][r] * 0.125f;
                if (diag && ((st << 4) + l15 > qloc)) s = -INFINITY;
                sv[st] = s;
            }
            float bm = fmaxf(fmaxf(sv[0], sv[1]), fmaxf(sv[2], sv[3]));
#pragma unroll
            for (int o = 1; o < 16; o <<= 1) bm = fmaxf(bm, __shfl_xor(bm, o, 64));
            float mn = fmaxf(m[r], bm);
            float cr = expf(m[r] - mn);
            m[r] = mn;
            float ps = 0.f;
#pragma unroll
            for (int st = 0; st < 4; ++st) {
                float pe = expf(sv[st] - mn);
                p[st][r] = pe; ps += pe;
            }
#pragma unroll
            for (int o = 1; o < 16; o <<= 1) ps += __shfl_xor(ps, o, 64);
            lsum[r] = lsum[r] * cr + ps;
#pragma unroll
            for (int su = 0; su < 4; ++su) acc_o[su][r] *= cr;
        }
#pragma unroll
        for (int st = 0; st < 4; ++st) {
            int slot = (st << 1) + (l15 >> 3);
            int k7 = l15 & 7;
#pragma unroll
            for (int r = 0; r < 4; ++r) {
                int q = (lg << 2) + r;
                Ps_w[(q << 6) + ((slot ^ (q & 7)) << 3) + k7] = f2bf(p[st][r]);
            }
        }
        {
            bf16x8 ap0 = *(const bf16x8*)(Ps_w + (l15 << 6) + ((lg       ^ (l15 & 7)) << 3));
            bf16x8 ap1 = *(const bf16x8*)(Ps_w + (l15 << 6) + (((4 + lg) ^ (l15 & 7)) << 3));
#pragma unroll
            for (int su = 0; su < 4; ++su) {
                int rd = (su << 4) + l15;
                bf16x8 bv0 = *(const bf16x8*)(Vs + (rd << 6) + ((lg       ^ (rd & 7)) << 3));
                bf16x8 bv1 = *(const bf16x8*)(Vs + (rd << 6) + (((4 + lg) ^ (rd & 7)) << 3));
                acc_o[su] = __builtin_amdgcn_mfma_f32_16x16x32_bf16(ap0, bv0, acc_o[su], 0, 0, 0);
                acc_o[su] = __builtin_amdgcn_mfma_f32_16x16x32_bf16(ap1, bv1, acc_o[su], 0, 0, 0);
            }
        }
        __syncthreads();
    }

    float rl[4];
#pragma unroll
    for (int r = 0; r < 4; ++r) rl[r] = 1.0f / lsum[r];
    size_t orow = (size_t)b * T_ + (i0 - PREF) + wq0 + (lg << 2);
#pragma unroll
    for (int su = 0; su < 4; ++su)
#pragma unroll
        for (int r = 0; r < 4; ++r)
            attn_bf[(orow + r) * D_ + (h << 6) + (su << 4) + l15] =
                f2bf(acc_o[su][r] * rl[r]);
}

// ---------------- launch ----------------
extern "C" void kernel_launch(void* const* d_in, const int* in_sizes, int n_in,
                              void* d_out, int out_size, void* d_ws, size_t ws_size,
                              hipStream_t stream) {
    const float* x   = (const float*)d_in[0];
    const float* mem = (const float*)d_in[1];
    const float* nmr = (const float*)d_in[2];
    const float* Wq  = (const float*)d_in[3];
    const float* bq  = (const float*)d_in[4];
    const float* Wk  = (const float*)d_in[5];
    const float* bk  = (const float*)d_in[6];
    const float* Wv  = (const float*)d_in[7];
    const float* bv  = (const float*)d_in[8];
    const float* Wo  = (const float*)d_in[9];
    const float* bo  = (const float*)d_in[10];
    const float* W1  = (const float*)d_in[11];
    const float* b1  = (const float*)d_in[12];
    const float* W2  = (const float*)d_in[13];
    const float* b2  = (const float*)d_in[14];
    const float* g1  = (const float*)d_in[15];
    const float* be1 = (const float*)d_in[16];
    const float* g2  = (const float*)d_in[17];
    const float* be2 = (const float*)d_in[18];
    float* out = (float*)d_out;

    const size_t BLD = (size_t)BL_ * D_;
    const size_t BTD = (size_t)BT_ * D_;

    float* f = (float*)d_ws;
    float* x_full = f;                         // BLD f32
    float* x2     = f + BLD;                   // BTD f32
    float* bqkv   = x2 + BTD;                  // 4096 f32 (3072 used)
    ushort* bfb   = (ushort*)(bqkv + 4096);
    ushort* xa_bf   = bfb;                     // BLD  (reused as attn_bf)
    ushort* qhd     = bfb + BLD;               // BLD  (reused as ln2_bf)
    ushort* khd     = bfb + 2*BLD;             // BLD
    ushort* vt      = bfb + 3*BLD;             // BLD
    ushort* h1_bf   = bfb + 4*BLD;             // BT_*FFN_
    ushort* wq_bf = h1_bf + (size_t)BT_*FFN_;  // Q|K|V weights contiguous
    ushort* wk_bf = wq_bf + (size_t)D_*D_;
    ushort* wv_bf = wk_bf + (size_t)D_*D_;
    ushort* wo_bf = wv_bf + (size_t)D_*D_;
    ushort* w1_bf = wo_bf + (size_t)D_*D_;
    ushort* w2_bf = w1_bf + (size_t)D_*FFN_;
    float* partials = (float*)(w2_bf + (size_t)FFN_*D_);   // 4*BTD f32
    ushort* attn_bf = xa_bf;
    ushort* ln2_bf  = qhd;

    size_t need = (size_t)((char*)(partials + 4*BTD) - (char*)d_ws);
    bool use_split = (ws_size >= need);

    // weight prep
    wtr_kernel<<<dim3(D_/64,   D_/64),   256, 0, stream>>>(Wq, wq_bf, D_,   D_);
    wtr_kernel<<<dim3(D_/64,   D_/64),   256, 0, stream>>>(Wk, wk_bf, D_,   D_);
    wtr_kernel<<<dim3(D_/64,   D_/64),   256, 0, stream>>>(Wv, wv_bf, D_,   D_);
    wtr_kernel<<<dim3(D_/64,   D_/64),   256, 0, stream>>>(Wo, wo_bf, D_,   D_);
    wtr_kernel<<<dim3(FFN_/64, D_/64),   256, 0, stream>>>(W1, w1_bf, D_,   FFN_);
    wtr_kernel<<<dim3(D_/64,   FFN_/64), 256, 0, stream>>>(W2, w2_bf, FFN_, D_);
    bias_cat_kernel<<<12, 256, 0, stream>>>(bq, bk, bv, bqkv);

    ln1_concat_kernel<<<BL_, 256, 0, stream>>>(x, mem, nmr, g1, be1, x_full, xa_bf);

    // fused QKV projection (N=3072) with RoPE / layout epilogues
    gemm_bf16_kernel<<<dim3(3072/128, BL_/128), 256, 0, stream>>>(
        xa_bf, wq_bf, bqkv, nullptr, qhd, D_, D_, D_, 7);

    attn_mfma_kernel<<<B_*H_*(T_/64), 256, 0, stream>>>(qhd, khd, vt, attn_bf);

    if (use_split) {
        // Wo split-K=2 -> partials; reduce fused with residual + LN2
        gemm_bf16_kernel<<<dim3(D_/128, BT_/128, 2), 256, 0, stream>>>(
            attn_bf, wo_bf, nullptr, nullptr, partials, D_, D_, D_/2, 4);
        reduce2_ln2_kernel<<<BT_, 256, 0, stream>>>(partials, bo, x_full, g2, be2, x2, ln2_bf);
    } else {
        gemm_bf16_kernel<<<dim3(D_/128, BT_/128), 256, 0, stream>>>(
            attn_bf, wo_bf, bo, x_full, x2, D_, D_, D_, 2);
        ln2_kernel<<<BT_, 256, 0, stream>>>(x2, g2, be2, ln2_bf);
    }

    // h1 = relu(xf @ W1 + b1)^2
    gemm_bf16_kernel<<<dim3(FFN_/128, BT_/128), 256, 0, stream>>>(
        ln2_bf, w1_bf, b1, nullptr, h1_bf, FFN_, D_, D_, 3);

    if (use_split) {
        // FFN2 split-K=4 -> partials; reduce fused with bias + residual
        gemm_bf16_kernel<<<dim3(D_/128, BT_/128, 4), 256, 0, stream>>>(
            h1_bf, w2_bf, nullptr, nullptr, partials, D_, FFN_, FFN_/4, 4);
        reduce4_out_kernel<<<BT_, 256, 0, stream>>>(partials, b2, x2, out);
    } else {
        gemm_bf16_kernel<<<dim3(D_/128, BT_/128), 256, 0, stream>>>(
            h1_bf, w2_bf, b2, x2, out, D_, FFN_, FFN_, 1);
    }
}

// Round 5
// 307.820 us; speedup vs baseline: 8.3584x; 1.1376x over previous
//
#include <hip/hip_runtime.h>
#include <hip/hip_bf16.h>
#include <math.h>

#define D_   1024
#define H_   16
#define DH_  64
#define FFN_ 4096
#define B_   4
#define T_   1024
#define M_   128
#define N_   64
#define PREF 192
#define L_   1216
#define BL_  (B_*L_)   // 4864
#define BT_  (B_*T_)   // 4096

typedef __attribute__((ext_vector_type(4))) float f32x4;
typedef __attribute__((ext_vector_type(8))) short bf16x8;
typedef const __attribute__((address_space(1))) void gvoid_t;
typedef __attribute__((address_space(3))) void lvoid_t;

__device__ __forceinline__ void gl_lds16(const void* g, void* l) {
    __builtin_amdgcn_global_load_lds((gvoid_t*)g, (lvoid_t*)l, 16, 0, 0);
}

__device__ __forceinline__ ushort f2bf(float x) {
    union { __hip_bfloat16 h; ushort u; } cv;
    cv.h = __float2bfloat16(x);
    return cv.u;
}

// ---------------- block reduce helper ----------------
__device__ __forceinline__ float block_reduce_sum256(float v, float* sbuf) {
#pragma unroll
    for (int o = 32; o > 0; o >>= 1) v += __shfl_xor(v, o, 64);
    int w = threadIdx.x >> 6;
    if ((threadIdx.x & 63) == 0) sbuf[w] = v;
    __syncthreads();
    float r = sbuf[0] + sbuf[1] + sbuf[2] + sbuf[3];
    __syncthreads();
    return r;
}

// ---------------- weight fp32 [K][Nc] -> bf16 W^T [Nc][K] ----------------
__global__ __launch_bounds__(256) void wtr_kernel(
    const float* __restrict__ W, ushort* __restrict__ Wt, int K, int Nc)
{
    __shared__ float tl[64][65];
    int c0 = blockIdx.x << 6, k0 = blockIdx.y << 6;
    int tid = threadIdx.x;
    int rr = tid >> 4, c4 = (tid & 15) << 2;
#pragma unroll
    for (int p = 0; p < 4; ++p) {
        int r = (p << 4) + rr;
        float4 v = *(const float4*)(W + (size_t)(k0 + r) * Nc + c0 + c4);
        tl[r][c4+0] = v.x; tl[r][c4+1] = v.y; tl[r][c4+2] = v.z; tl[r][c4+3] = v.w;
    }
    __syncthreads();
#pragma unroll
    for (int p = 0; p < 4; ++p) {
        int rT = (p << 4) + rr;
        ushort4 uv;
        uv.x = f2bf(tl[c4+0][rT]);
        uv.y = f2bf(tl[c4+1][rT]);
        uv.z = f2bf(tl[c4+2][rT]);
        uv.w = f2bf(tl[c4+3][rT]);
        *(ushort4*)(Wt + (size_t)(c0 + rT) * K + k0 + c4) = uv;
    }
}

// ---------------- bias concat (bq|bk|bv -> 3072) ----------------
__global__ __launch_bounds__(256) void bias_cat_kernel(
    const float* __restrict__ bq, const float* __restrict__ bk,
    const float* __restrict__ bv, float* __restrict__ o)
{
    int i = blockIdx.x * 256 + threadIdx.x;
    float v = (i < 1024) ? bq[i] : (i < 2048 ? bk[i - 1024] : bv[i - 2048]);
    o[i] = v;
}

// ---------------- concat + LayerNorm1: x_full f32, xa bf16 ----------------
__global__ __launch_bounds__(256) void ln1_concat_kernel(
    const float* __restrict__ x, const float* __restrict__ mem,
    const float* __restrict__ nmr, const float* __restrict__ g,
    const float* __restrict__ be, float* __restrict__ x_full,
    ushort* __restrict__ xa_bf)
{
    __shared__ float sbuf[4];
    int row = blockIdx.x;
    int b = row / L_, pos = row % L_;
    const float* src;
    if (pos < M_)          src = mem + ((size_t)b*M_ + pos)      * D_;
    else if (pos < M_+N_)  src = nmr + ((size_t)b*N_ + (pos-M_)) * D_;
    else                   src = x   + ((size_t)b*T_ + (pos-PREF))*D_;

    int c = threadIdx.x << 2;
    float4 v = *(const float4*)(src + c);
    float s = v.x + v.y + v.z + v.w;
    s = block_reduce_sum256(s, sbuf);
    float mu = s * (1.0f / D_);
    float dx = v.x - mu, dy = v.y - mu, dz = v.z - mu, dw = v.w - mu;
    float q = dx*dx + dy*dy + dz*dz + dw*dw;
    q = block_reduce_sum256(q, sbuf);
    float inv = rsqrtf(q * (1.0f / D_) + 1e-5f);
    float4 gv = *(const float4*)(g + c);
    float4 bv = *(const float4*)(be + c);
    ushort4 o;
    o.x = f2bf(dx*inv*gv.x + bv.x);
    o.y = f2bf(dy*inv*gv.y + bv.y);
    o.z = f2bf(dz*inv*gv.z + bv.z);
    o.w = f2bf(dw*inv*gv.w + bv.w);
    *(float4*)(x_full + (size_t)row*D_ + c) = v;
    *(ushort4*)(xa_bf + (size_t)row*D_ + c) = o;
}

// ---------------- LayerNorm2 (fallback path): f32 in, bf16 out ------------
__global__ __launch_bounds__(256) void ln2_kernel(
    const float* __restrict__ src, const float* __restrict__ g,
    const float* __restrict__ be, ushort* __restrict__ dst)
{
    __shared__ float sbuf[4];
    int row = blockIdx.x;
    int c = threadIdx.x << 2;
    float4 v = *(const float4*)(src + (size_t)row*D_ + c);
    float s = v.x + v.y + v.z + v.w;
    s = block_reduce_sum256(s, sbuf);
    float mu = s * (1.0f / D_);
    float dx = v.x - mu, dy = v.y - mu, dz = v.z - mu, dw = v.w - mu;
    float q = dx*dx + dy*dy + dz*dz + dw*dw;
    q = block_reduce_sum256(q, sbuf);
    float inv = rsqrtf(q * (1.0f / D_) + 1e-5f);
    float4 gv = *(const float4*)(g + c);
    float4 bv = *(const float4*)(be + c);
    ushort4 o;
    o.x = f2bf(dx*inv*gv.x + bv.x);
    o.y = f2bf(dy*inv*gv.y + bv.y);
    o.z = f2bf(dz*inv*gv.z + bv.z);
    o.w = f2bf(dw*inv*gv.w + bv.w);
    *(ushort4*)(dst + (size_t)row*D_ + c) = o;
}

// ---------------- split-K=2 reduce + residual + LayerNorm2 ----------------
__global__ __launch_bounds__(256) void reduce2_ln2_kernel(
    const float* __restrict__ part, const float* __restrict__ bo,
    const float* __restrict__ x_full, const float* __restrict__ g,
    const float* __restrict__ be, float* __restrict__ x2,
    ushort* __restrict__ ln2_bf)
{
    __shared__ float sbuf[4];
    int row = blockIdx.x;
    int c = threadIdx.x << 2;
    size_t o = (size_t)row * D_ + c;
    float4 a  = *(const float4*)(part + o);
    float4 b2 = *(const float4*)(part + (size_t)BT_*D_ + o);
    float4 bb = *(const float4*)(bo + c);
    int rr = (row >> 10)*L_ + PREF + (row & (T_-1));
    float4 rv = *(const float4*)(x_full + (size_t)rr*D_ + c);
    float4 v;
    v.x = a.x + b2.x + bb.x + rv.x;
    v.y = a.y + b2.y + bb.y + rv.y;
    v.z = a.z + b2.z + bb.z + rv.z;
    v.w = a.w + b2.w + bb.w + rv.w;
    *(float4*)(x2 + o) = v;

    float s = v.x + v.y + v.z + v.w;
    s = block_reduce_sum256(s, sbuf);
    float mu = s * (1.0f / D_);
    float dx = v.x - mu, dy = v.y - mu, dz = v.z - mu, dw = v.w - mu;
    float q = dx*dx + dy*dy + dz*dz + dw*dw;
    q = block_reduce_sum256(q, sbuf);
    float inv = rsqrtf(q * (1.0f / D_) + 1e-5f);
    float4 gv = *(const float4*)(g + c);
    float4 bv = *(const float4*)(be + c);
    ushort4 ov;
    ov.x = f2bf(dx*inv*gv.x + bv.x);
    ov.y = f2bf(dy*inv*gv.y + bv.y);
    ov.z = f2bf(dz*inv*gv.z + bv.z);
    ov.w = f2bf(dw*inv*gv.w + bv.w);
    *(ushort4*)(ln2_bf + o) = ov;
}

// ---------------- split-K=4 reduce + bias + residual -> out ----------------
__global__ __launch_bounds__(256) void reduce4_out_kernel(
    const float* __restrict__ part, const float* __restrict__ b2,
    const float* __restrict__ x2, float* __restrict__ out)
{
    int row = blockIdx.x;
    int c = threadIdx.x << 2;
    size_t o = (size_t)row * D_ + c;
    const size_t S = (size_t)BT_ * D_;
    float4 p0 = *(const float4*)(part + o);
    float4 p1 = *(const float4*)(part + S + o);
    float4 p2 = *(const float4*)(part + 2*S + o);
    float4 p3 = *(const float4*)(part + 3*S + o);
    float4 bb = *(const float4*)(b2 + c);
    float4 rv = *(const float4*)(x2 + o);
    float4 v;
    v.x = p0.x + p1.x + p2.x + p3.x + bb.x + rv.x;
    v.y = p0.y + p1.y + p2.y + p3.y + bb.y + rv.y;
    v.z = p0.z + p1.z + p2.z + p3.z + bb.z + rv.z;
    v.w = p0.w + p1.w + p2.w + p3.w + bb.w + rv.w;
    *(float4*)(out + o) = v;
}

// ---------------- bf16 MFMA GEMM, 2-phase double-buffered -----------------
__global__ __launch_bounds__(256) void gemm_bf16_kernel(
    const ushort* __restrict__ A, const ushort* __restrict__ Bt,
    const float* __restrict__ bias, const float* __restrict__ res,
    void* __restrict__ Cout, int Nc, int Kstride, int Klen, int mode)
{
    __shared__ ushort As[2][128*32];
    __shared__ ushort Bs[2][128*32];
    int tid = threadIdx.x;
    int lane = tid & 63, w = tid >> 6;
    int wm = w >> 1, wn = w & 1;
    int row0 = blockIdx.y << 7, col0 = blockIdx.x << 7;
    int l15 = lane & 15, l4 = lane >> 4;
    int kbase = blockIdx.z * Klen;

    f32x4 acc[4][4] = {};

    int r_a = tid >> 2;
    int sc  = tid & 3;
    int lcOff = (sc ^ ((r_a >> 1) & 3)) << 3;
    const ushort* Arow  = A  + (size_t)(row0 + r_a)      * Kstride + kbase;
    const ushort* Arow2 = A  + (size_t)(row0 + 64 + r_a) * Kstride + kbase;
    const ushort* Brow  = Bt + (size_t)(col0 + r_a)      * Kstride + kbase;
    const ushort* Brow2 = Bt + (size_t)(col0 + 64 + r_a) * Kstride + kbase;

#define STAGE(buf, k0rel)                                                      \
    do {                                                                       \
        gl_lds16(Arow  + (k0rel) + lcOff, (char*)As[buf] + (tid << 4));        \
        gl_lds16(Arow2 + (k0rel) + lcOff, (char*)As[buf] + ((256+tid) << 4));  \
        gl_lds16(Brow  + (k0rel) + lcOff, (char*)Bs[buf] + (tid << 4));        \
        gl_lds16(Brow2 + (k0rel) + lcOff, (char*)Bs[buf] + ((256+tid) << 4));  \
    } while (0)

    STAGE(0, 0);
    __syncthreads();
    int cur = 0;
    for (int k0 = 0; k0 < Klen; k0 += 32) {
        if (k0 + 32 < Klen) STAGE(cur ^ 1, k0 + 32);
        bf16x8 af[4], bfr[4];
#pragma unroll
        for (int i = 0; i < 4; ++i) {
            int ra = (wm << 6) + (i << 4) + l15;
            af[i]  = *(const bf16x8*)(&As[cur][ra*32 + ((l4 ^ ((ra >> 1) & 3)) << 3)]);
            int rb = (wn << 6) + (i << 4) + l15;
            bfr[i] = *(const bf16x8*)(&Bs[cur][rb*32 + ((l4 ^ ((rb >> 1) & 3)) << 3)]);
        }
#pragma unroll
        for (int i = 0; i < 4; ++i)
#pragma unroll
            for (int j = 0; j < 4; ++j)
                acc[i][j] = __builtin_amdgcn_mfma_f32_16x16x32_bf16(af[i], bfr[j], acc[i][j], 0, 0, 0);
        __syncthreads();
        cur ^= 1;
    }
#undef STAGE

    float bcol[4] = {0.f, 0.f, 0.f, 0.f};
    if (mode != 4) {
#pragma unroll
        for (int j = 0; j < 4; ++j) bcol[j] = bias[col0 + (wn << 6) + (j << 4) + l15];
    }
    int orow0 = row0 + (wm << 6) + (l4 << 2);
    int ocol0 = col0 + (wn << 6) + l15;

    if (mode == 3) {
        ushort* O = (ushort*)Cout;
#pragma unroll
        for (int i = 0; i < 4; ++i)
#pragma unroll
            for (int j = 0; j < 4; ++j)
#pragma unroll
                for (int r = 0; r < 4; ++r) {
                    int row = orow0 + (i << 4) + r;
                    int col = ocol0 + (j << 4);
                    float v = acc[i][j][r] + bcol[j];
                    v = fmaxf(v, 0.f); v *= v;
                    O[(size_t)row*Nc + col] = f2bf(v);
                }
    } else if (mode == 4) {
        float* O = (float*)Cout + (size_t)blockIdx.z * ((size_t)BT_ * D_);
#pragma unroll
        for (int i = 0; i < 4; ++i)
#pragma unroll
            for (int j = 0; j < 4; ++j)
#pragma unroll
                for (int r = 0; r < 4; ++r) {
                    int row = orow0 + (i << 4) + r;
                    int col = ocol0 + (j << 4);
                    O[(size_t)row*Nc + col] = acc[i][j][r];
                }
    } else if (mode == 7) {
        int which = col0 >> 10;
        int lcol0 = col0 & 1023;
        ushort* O = (ushort*)Cout + (size_t)which * ((size_t)BL_ * D_);
        int hh = (lcol0 + (wn << 6)) >> 6;
        if (which < 2) {
            float invf = exp2f(-(float)l15 * 0.83048202372f);
#pragma unroll
            for (int i = 0; i < 4; ++i)
#pragma unroll
                for (int r = 0; r < 4; ++r) {
                    int row = orow0 + (i << 4) + r;
                    int bb = row / L_;
                    int pos = row - bb * L_;
                    float sn, cs;
                    sincosf((float)pos * invf, &sn, &cs);
                    float v0 = acc[i][0][r] + bcol[0];
                    float v1 = acc[i][1][r] + bcol[1];
                    float v2 = acc[i][2][r] + bcol[2];
                    float v3 = acc[i][3][r] + bcol[3];
                    size_t base = ((size_t)(bb * H_ + hh) * L_ + pos) << 6;
                    O[base + l15]      = f2bf(v0 * cs - v1 * sn);
                    O[base + 16 + l15] = f2bf(v1 * cs + v0 * sn);
                    O[base + 32 + l15] = f2bf(v2);
                    O[base + 48 + l15] = f2bf(v3);
                }
        } else {
#pragma unroll
            for (int i = 0; i < 4; ++i)
#pragma unroll
                for (int r = 0; r < 4; ++r) {
                    int row = orow0 + (i << 4) + r;
                    int bb = row / L_;
                    int pos = row - bb * L_;
                    size_t base = ((size_t)(bb * H_ + hh) * 64) * L_ + pos;
#pragma unroll
                    for (int j = 0; j < 4; ++j) {
                        int d = (j << 4) + l15;
                        O[base + (size_t)d * L_] = f2bf(acc[i][j][r] + bcol[j]);
                    }
                }
        }
    } else {
        float* O = (float*)Cout;
#pragma unroll
        for (int i = 0; i < 4; ++i)
#pragma unroll
            for (int j = 0; j < 4; ++j)
#pragma unroll
                for (int r = 0; r < 4; ++r) {
                    int row = orow0 + (i << 4) + r;
                    int col = ocol0 + (j << 4);
                    float v = acc[i][j][r] + bcol[j];
                    if (mode == 1) {
                        v += res[(size_t)row*Nc + col];
                    } else if (mode == 2) {
                        int rr = (row >> 10)*L_ + PREF + (row & (T_-1));
                        v += res[(size_t)rr*D_ + col];
                    }
                    O[(size_t)row*Nc + col] = v;
                }
    }
}

// ---------------- MFMA flash attention, swapped-operand softmax ----------
// grid: B*H*(T/64), 256 threads (4 waves, 16 q each). S^T = K Q^T so each
// lane owns one q-row (l15) and 16 keys; softmax = in-lane tree + 2 shfl.
// PV swapped too: O^T = V^T P^T; P repacked via wave-private swizzled LDS.
__global__ __launch_bounds__(256) void attn_mfma_kernel(
    const ushort* __restrict__ qhd, const ushort* __restrict__ khd,
    const ushort* __restrict__ vt, ushort* __restrict__ attn_bf)
{
    __shared__ ushort Ks[2][64*64];   // [key][d], swizzled 16B slots
    __shared__ ushort Vs[2][64*64];   // [d][key] (V^T), swizzled
    __shared__ ushort Ps[4*16*64];    // per-wave P^T repack [q][key], swizzled

    int bid = blockIdx.x;
    int qb = 15 - (bid & 15);         // heavy q-blocks first
    int h  = (bid >> 4) & (H_ - 1);
    int b  = bid >> 8;
    int tid = threadIdx.x, lane = tid & 63, w = tid >> 6;
    int l15 = lane & 15, lg = lane >> 4;
    int i0 = PREF + (qb << 6);
    int wq0 = w << 4;
    size_t bh = (size_t)(b * H_ + h);

    // Q as B-fragment: col = l15 (q), k-dims lg*8.. / 32+lg*8..
    const ushort* qrow = qhd + (bh * L_ + i0 + wq0 + l15) * 64;
    bf16x8 bq0 = *(const bf16x8*)(qrow + (lg << 3));
    bf16x8 bq1 = *(const bf16x8*)(qrow + 32 + (lg << 3));

    f32x4 acc[4] = {};            // O^T: d = su*16+lg*4+r, q = l15
    float mrun = -INFINITY;       // running max (log2-scaled domain)
    float lsum = 0.f;

    int srow = tid >> 3;
    int sslot = tid & 7;
    ushort* Ps_w = Ps + (w << 10);
    const float SC = 0.125f * 1.4426950408889634f;   // scale * log2(e)
    int qcap = i0 + wq0 + l15;    // causal cap for this lane's q

#define STAGE_T(buf, t)                                                     \
    do { int j0s = (t) << 6;                                                \
        gl_lds16(khd + (bh * L_ + j0s + srow) * 64 + ((sslot ^ (srow & 7)) << 3),      \
                 (char*)Ks[buf] + (tid << 4));                              \
        gl_lds16(khd + (bh * L_ + j0s + 32 + srow) * 64 + ((sslot ^ ((32+srow) & 7)) << 3), \
                 (char*)Ks[buf] + ((256 + tid) << 4));                      \
        gl_lds16(vt + (bh * 64 + srow) * L_ + j0s + ((sslot ^ (srow & 7)) << 3),       \
                 (char*)Vs[buf] + (tid << 4));                              \
        gl_lds16(vt + (bh * 64 + 32 + srow) * L_ + j0s + ((sslot ^ ((32+srow) & 7)) << 3), \
                 (char*)Vs[buf] + ((256 + tid) << 4));                      \
    } while (0)

    int ntile = 4 + qb;
    STAGE_T(0, 0);
    __syncthreads();
    int cur = 0;
    for (int t = 0; t < ntile; ++t) {
        if (t + 1 < ntile) STAGE_T(cur ^ 1, t + 1);
        const ushort* Kc = Ks[cur];
        const ushort* Vc = Vs[cur];

        // S^T = K Q^T per key-subtile; lane holds q=l15, keys st*16+lg*4+r
        f32x4 s4[4];
        __builtin_amdgcn_s_setprio(1);
#pragma unroll
        for (int st = 0; st < 4; ++st) {
            int rk = (st << 4) + l15;
            bf16x8 ak0 = *(const bf16x8*)(Kc + (rk << 6) + ((lg       ^ (rk & 7)) << 3));
            bf16x8 ak1 = *(const bf16x8*)(Kc + (rk << 6) + (((4 + lg) ^ (rk & 7)) << 3));
            f32x4 z = {};
            z = __builtin_amdgcn_mfma_f32_16x16x32_bf16(ak0, bq0, z, 0, 0, 0);
            z = __builtin_amdgcn_mfma_f32_16x16x32_bf16(ak1, bq1, z, 0, 0, 0);
            s4[st] = z;
        }
        __builtin_amdgcn_s_setprio(0);

        int j0 = t << 6;
        float sv[4][4];
        bool diag = (t == ntile - 1);
        int kb = j0 + (lg << 2);
#pragma unroll
        for (int st = 0; st < 4; ++st)
#pragma unroll
            for (int r = 0; r < 4; ++r) {
                float s = s4[st][r] * SC;
                if (diag && (kb + (st << 4) + r > qcap)) s = -INFINITY;
                sv[st][r] = s;
            }
        // in-lane max tree + 2 cross-lane steps
        float bm;
        {
            float t0 = fmaxf(fmaxf(sv[0][0], sv[0][1]), fmaxf(sv[0][2], sv[0][3]));
            float t1 = fmaxf(fmaxf(sv[1][0], sv[1][1]), fmaxf(sv[1][2], sv[1][3]));
            float t2 = fmaxf(fmaxf(sv[2][0], sv[2][1]), fmaxf(sv[2][2], sv[2][3]));
            float t3 = fmaxf(fmaxf(sv[3][0], sv[3][1]), fmaxf(sv[3][2], sv[3][3]));
            bm = fmaxf(fmaxf(t0, t1), fmaxf(t2, t3));
        }
        bm = fmaxf(bm, __shfl_xor(bm, 16, 64));
        bm = fmaxf(bm, __shfl_xor(bm, 32, 64));

        float mn = fmaxf(mrun, bm);
        float cr = exp2f(mrun - mn);
        mrun = mn;
        float pe[4][4];
        float ps = 0.f;
#pragma unroll
        for (int st = 0; st < 4; ++st)
#pragma unroll
            for (int r = 0; r < 4; ++r) {
                float e = exp2f(sv[st][r] - mn);
                pe[st][r] = e; ps += e;
            }
        ps += __shfl_xor(ps, 16, 64);
        ps += __shfl_xor(ps, 32, 64);
        lsum = lsum * cr + ps;
#pragma unroll
        for (int su = 0; su < 4; ++su) acc[su] *= cr;

        // pack P^T pairs -> wave-private swizzled LDS [q=l15][key]
#pragma unroll
        for (int st = 0; st < 4; ++st) {
            int slot = (st << 1) + (lg >> 1);
            int sb = ((lg & 1) << 3);
#pragma unroll
            for (int rp = 0; rp < 2; ++rp) {
                uint u = (uint)f2bf(pe[st][2*rp]) | ((uint)f2bf(pe[st][2*rp+1]) << 16);
                *(uint*)((char*)Ps_w + l15*128 + ((slot ^ (l15 & 7)) << 4) + sb + (rp << 2)) = u;
            }
        }
        // PV: O^T += V^T P^T
        {
            bf16x8 bp0 = *(const bf16x8*)((char*)Ps_w + l15*128 + ((lg       ^ (l15 & 7)) << 4));
            bf16x8 bp1 = *(const bf16x8*)((char*)Ps_w + l15*128 + (((4 + lg) ^ (l15 & 7)) << 4));
            __builtin_amdgcn_s_setprio(1);
#pragma unroll
            for (int su = 0; su < 4; ++su) {
                int rd = (su << 4) + l15;
                bf16x8 av0 = *(const bf16x8*)(Vc + (rd << 6) + ((lg       ^ (rd & 7)) << 3));
                bf16x8 av1 = *(const bf16x8*)(Vc + (rd << 6) + (((4 + lg) ^ (rd & 7)) << 3));
                acc[su] = __builtin_amdgcn_mfma_f32_16x16x32_bf16(av0, bp0, acc[su], 0, 0, 0);
                acc[su] = __builtin_amdgcn_mfma_f32_16x16x32_bf16(av1, bp1, acc[su], 0, 0, 0);
            }
            __builtin_amdgcn_s_setprio(0);
        }
        __syncthreads();
        cur ^= 1;
    }
#undef STAGE_T

    float rl = 1.0f / lsum;
    size_t orow = (size_t)b * T_ + (i0 - PREF) + wq0 + l15;
#pragma unroll
    for (int su = 0; su < 4; ++su) {
        ushort4 o4;
        o4.x = f2bf(acc[su][0] * rl);
        o4.y = f2bf(acc[su][1] * rl);
        o4.z = f2bf(acc[su][2] * rl);
        o4.w = f2bf(acc[su][3] * rl);
        *(ushort4*)(attn_bf + orow * D_ + (h << 6) + (su << 4) + (lg << 2)) = o4;
    }
}

// ---------------- launch ----------------
extern "C" void kernel_launch(void* const* d_in, const int* in_sizes, int n_in,
                              void* d_out, int out_size, void* d_ws, size_t ws_size,
                              hipStream_t stream) {
    const float* x   = (const float*)d_in[0];
    const float* mem = (const float*)d_in[1];
    const float* nmr = (const float*)d_in[2];
    const float* Wq  = (const float*)d_in[3];
    const float* bq  = (const float*)d_in[4];
    const float* Wk  = (const float*)d_in[5];
    const float* bk  = (const float*)d_in[6];
    const float* Wv  = (const float*)d_in[7];
    const float* bv  = (const float*)d_in[8];
    const float* Wo  = (const float*)d_in[9];
    const float* bo  = (const float*)d_in[10];
    const float* W1  = (const float*)d_in[11];
    const float* b1  = (const float*)d_in[12];
    const float* W2  = (const float*)d_in[13];
    const float* b2  = (const float*)d_in[14];
    const float* g1  = (const float*)d_in[15];
    const float* be1 = (const float*)d_in[16];
    const float* g2  = (const float*)d_in[17];
    const float* be2 = (const float*)d_in[18];
    float* out = (float*)d_out;

    const size_t BLD = (size_t)BL_ * D_;
    const size_t BTD = (size_t)BT_ * D_;

    float* f = (float*)d_ws;
    float* x_full = f;                         // BLD f32
    float* x2     = f + BLD;                   // BTD f32
    float* bqkv   = x2 + BTD;                  // 4096 f32 (3072 used)
    ushort* bfb   = (ushort*)(bqkv + 4096);
    ushort* xa_bf   = bfb;                     // BLD  (reused as attn_bf)
    ushort* qhd     = bfb + BLD;               // BLD  (reused as ln2_bf)
    ushort* khd     = bfb + 2*BLD;             // BLD
    ushort* vt      = bfb + 3*BLD;             // BLD
    ushort* h1_bf   = bfb + 4*BLD;             // BT_*FFN_
    ushort* wq_bf = h1_bf + (size_t)BT_*FFN_;  // Q|K|V weights contiguous
    ushort* wk_bf = wq_bf + (size_t)D_*D_;
    ushort* wv_bf = wk_bf + (size_t)D_*D_;
    ushort* wo_bf = wv_bf + (size_t)D_*D_;
    ushort* w1_bf = wo_bf + (size_t)D_*D_;
    ushort* w2_bf = w1_bf + (size_t)D_*FFN_;
    float* partials = (float*)(w2_bf + (size_t)FFN_*D_);   // 4*BTD f32
    ushort* attn_bf = xa_bf;
    ushort* ln2_bf  = qhd;

    size_t need = (size_t)((char*)(partials + 4*BTD) - (char*)d_ws);
    bool use_split = (ws_size >= need);

    // weight prep
    wtr_kernel<<<dim3(D_/64,   D_/64),   256, 0, stream>>>(Wq, wq_bf, D_,   D_);
    wtr_kernel<<<dim3(D_/64,   D_/64),   256, 0, stream>>>(Wk, wk_bf, D_,   D_);
    wtr_kernel<<<dim3(D_/64,   D_/64),   256, 0, stream>>>(Wv, wv_bf, D_,   D_);
    wtr_kernel<<<dim3(D_/64,   D_/64),   256, 0, stream>>>(Wo, wo_bf, D_,   D_);
    wtr_kernel<<<dim3(FFN_/64, D_/64),   256, 0, stream>>>(W1, w1_bf, D_,   FFN_);
    wtr_kernel<<<dim3(D_/64,   FFN_/64), 256, 0, stream>>>(W2, w2_bf, FFN_, D_);
    bias_cat_kernel<<<12, 256, 0, stream>>>(bq, bk, bv, bqkv);

    ln1_concat_kernel<<<BL_, 256, 0, stream>>>(x, mem, nmr, g1, be1, x_full, xa_bf);

    // fused QKV projection (N=3072) with RoPE / layout epilogues
    gemm_bf16_kernel<<<dim3(3072/128, BL_/128), 256, 0, stream>>>(
        xa_bf, wq_bf, bqkv, nullptr, qhd, D_, D_, D_, 7);

    attn_mfma_kernel<<<B_*H_*(T_/64), 256, 0, stream>>>(qhd, khd, vt, attn_bf);

    if (use_split) {
        gemm_bf16_kernel<<<dim3(D_/128, BT_/128, 2), 256, 0, stream>>>(
            attn_bf, wo_bf, nullptr, nullptr, partials, D_, D_, D_/2, 4);
        reduce2_ln2_kernel<<<BT_, 256, 0, stream>>>(partials, bo, x_full, g2, be2, x2, ln2_bf);
    } else {
        gemm_bf16_kernel<<<dim3(D_/128, BT_/128), 256, 0, stream>>>(
            attn_bf, wo_bf, bo, x_full, x2, D_, D_, D_, 2);
        ln2_kernel<<<BT_, 256, 0, stream>>>(x2, g2, be2, ln2_bf);
    }

    // h1 = relu(xf @ W1 + b1)^2
    gemm_bf16_kernel<<<dim3(FFN_/128, BT_/128), 256, 0, stream>>>(
        ln2_bf, w1_bf, b1, nullptr, h1_bf, FFN_, D_, D_, 3);

    if (use_split) {
        gemm_bf16_kernel<<<dim3(D_/128, BT_/128, 4), 256, 0, stream>>>(
            h1_bf, w2_bf, nullptr, nullptr, partials, D_, FFN_, FFN_/4, 4);
        reduce4_out_kernel<<<BT_, 256, 0, stream>>>(partials, b2, x2, out);
    } else {
        gemm_bf16_kernel<<<dim3(D_/128, BT_/128), 256, 0, stream>>>(
            h1_bf, w2_bf, b2, x2, out, D_, FFN_, FFN_, 1);
    }
}

// Round 6
// 303.267 us; speedup vs baseline: 8.4839x; 1.0150x over previous
//
#include <hip/hip_runtime.h>
#include <hip/hip_bf16.h>
#include <math.h>

#define D_   1024
#define H_   16
#define DH_  64
#define FFN_ 4096
#define B_   4
#define T_   1024
#define M_   128
#define N_   64
#define PREF 192
#define L_   1216
#define BL_  (B_*L_)   // 4864
#define BT_  (B_*T_)   // 4096

typedef __attribute__((ext_vector_type(4))) float f32x4;
typedef __attribute__((ext_vector_type(8))) short bf16x8;
typedef __attribute__((ext_vector_type(8))) unsigned short u16x8;
typedef const __attribute__((address_space(1))) void gvoid_t;
typedef __attribute__((address_space(3))) void lvoid_t;

#define LGKM0 asm volatile("s_waitcnt lgkmcnt(0)" ::: "memory")

__device__ __forceinline__ void gl_lds16(const void* g, void* l) {
    __builtin_amdgcn_global_load_lds((gvoid_t*)g, (lvoid_t*)l, 16, 0, 0);
}

__device__ __forceinline__ ushort f2bf(float x) {
    union { __hip_bfloat16 h; ushort u; } cv;
    cv.h = __float2bfloat16(x);
    return cv.u;
}

__device__ __forceinline__ u16x8 pack8(float4 a, float4 b) {
    u16x8 r;
    r[0]=f2bf(a.x); r[1]=f2bf(a.y); r[2]=f2bf(a.z); r[3]=f2bf(a.w);
    r[4]=f2bf(b.x); r[5]=f2bf(b.y); r[6]=f2bf(b.z); r[7]=f2bf(b.w);
    return r;
}

// ---------------- block reduce helper ----------------
__device__ __forceinline__ float block_reduce_sum256(float v, float* sbuf) {
#pragma unroll
    for (int o = 32; o > 0; o >>= 1) v += __shfl_xor(v, o, 64);
    int w = threadIdx.x >> 6;
    if ((threadIdx.x & 63) == 0) sbuf[w] = v;
    __syncthreads();
    float r = sbuf[0] + sbuf[1] + sbuf[2] + sbuf[3];
    __syncthreads();
    return r;
}

// ---------------- weight fp32 [K][Nc] -> bf16 W^T [Nc][K] ----------------
__device__ __forceinline__ void wtr_body(const float* __restrict__ W,
                                         ushort* __restrict__ Wt, int K, int Nc)
{
    __shared__ float tl[64][65];
    int c0 = blockIdx.x << 6, k0 = blockIdx.y << 6;
    int tid = threadIdx.x;
    int rr = tid >> 4, c4 = (tid & 15) << 2;
#pragma unroll
    for (int p = 0; p < 4; ++p) {
        int r = (p << 4) + rr;
        float4 v = *(const float4*)(W + (size_t)(k0 + r) * Nc + c0 + c4);
        tl[r][c4+0] = v.x; tl[r][c4+1] = v.y; tl[r][c4+2] = v.z; tl[r][c4+3] = v.w;
    }
    __syncthreads();
#pragma unroll
    for (int p = 0; p < 4; ++p) {
        int rT = (p << 4) + rr;
        ushort4 uv;
        uv.x = f2bf(tl[c4+0][rT]);
        uv.y = f2bf(tl[c4+1][rT]);
        uv.z = f2bf(tl[c4+2][rT]);
        uv.w = f2bf(tl[c4+3][rT]);
        *(ushort4*)(Wt + (size_t)(c0 + rT) * K + k0 + c4) = uv;
    }
}

__global__ __launch_bounds__(256) void wtr_kernel(
    const float* __restrict__ W, ushort* __restrict__ Wt, int K, int Nc)
{ wtr_body(W, Wt, K, Nc); }

__global__ __launch_bounds__(256) void wtr4_kernel(
    const float* __restrict__ W0, const float* __restrict__ W1,
    const float* __restrict__ W2, const float* __restrict__ W3,
    ushort* __restrict__ T0, ushort* __restrict__ T1,
    ushort* __restrict__ T2, ushort* __restrict__ T3)
{
    const float* W; ushort* T;
    switch (blockIdx.z) {
        case 0: W = W0; T = T0; break;
        case 1: W = W1; T = T1; break;
        case 2: W = W2; T = T2; break;
        default: W = W3; T = T3; break;
    }
    wtr_body(W, T, D_, D_);
}

// ---------------- RoPE cos/sin table: [pos][0..15]=cos, [16..31]=sin ------
__global__ __launch_bounds__(256) void ropetab_kernel(float* __restrict__ tab)
{
    int i = blockIdx.x * 256 + threadIdx.x;
    if (i >= L_ * 32) return;
    int pos = i >> 5, idx = i & 31;
    int fi = idx & 15;
    float invf = exp2f(-(float)fi * 0.83048202372f);   // 10000^(-fi/16)
    float th = (float)pos * invf;
    tab[i] = (idx < 16) ? cosf(th) : sinf(th);
}

// ---------------- bias concat (bq|bk|bv -> 3072) ----------------
__global__ __launch_bounds__(256) void bias_cat_kernel(
    const float* __restrict__ bq, const float* __restrict__ bk,
    const float* __restrict__ bv, float* __restrict__ o)
{
    int i = blockIdx.x * 256 + threadIdx.x;
    float v = (i < 1024) ? bq[i] : (i < 2048 ? bk[i - 1024] : bv[i - 2048]);
    o[i] = v;
}

// ---------------- concat + LayerNorm1: x_full f32, xa bf16 ----------------
__global__ __launch_bounds__(256) void ln1_concat_kernel(
    const float* __restrict__ x, const float* __restrict__ mem,
    const float* __restrict__ nmr, const float* __restrict__ g,
    const float* __restrict__ be, float* __restrict__ x_full,
    ushort* __restrict__ xa_bf)
{
    __shared__ float sbuf[4];
    int row = blockIdx.x;
    int b = row / L_, pos = row % L_;
    const float* src;
    if (pos < M_)          src = mem + ((size_t)b*M_ + pos)      * D_;
    else if (pos < M_+N_)  src = nmr + ((size_t)b*N_ + (pos-M_)) * D_;
    else                   src = x   + ((size_t)b*T_ + (pos-PREF))*D_;

    int c = threadIdx.x << 2;
    float4 v = *(const float4*)(src + c);
    float s = v.x + v.y + v.z + v.w;
    s = block_reduce_sum256(s, sbuf);
    float mu = s * (1.0f / D_);
    float dx = v.x - mu, dy = v.y - mu, dz = v.z - mu, dw = v.w - mu;
    float q = dx*dx + dy*dy + dz*dz + dw*dw;
    q = block_reduce_sum256(q, sbuf);
    float inv = rsqrtf(q * (1.0f / D_) + 1e-5f);
    float4 gv = *(const float4*)(g + c);
    float4 bv = *(const float4*)(be + c);
    ushort4 o;
    o.x = f2bf(dx*inv*gv.x + bv.x);
    o.y = f2bf(dy*inv*gv.y + bv.y);
    o.z = f2bf(dz*inv*gv.z + bv.z);
    o.w = f2bf(dw*inv*gv.w + bv.w);
    *(float4*)(x_full + (size_t)row*D_ + c) = v;
    *(ushort4*)(xa_bf + (size_t)row*D_ + c) = o;
}

// ---------------- LayerNorm2 (fallback path): f32 in, bf16 out ------------
__global__ __launch_bounds__(256) void ln2_kernel(
    const float* __restrict__ src, const float* __restrict__ g,
    const float* __restrict__ be, ushort* __restrict__ dst)
{
    __shared__ float sbuf[4];
    int row = blockIdx.x;
    int c = threadIdx.x << 2;
    float4 v = *(const float4*)(src + (size_t)row*D_ + c);
    float s = v.x + v.y + v.z + v.w;
    s = block_reduce_sum256(s, sbuf);
    float mu = s * (1.0f / D_);
    float dx = v.x - mu, dy = v.y - mu, dz = v.z - mu, dw = v.w - mu;
    float q = dx*dx + dy*dy + dz*dz + dw*dw;
    q = block_reduce_sum256(q, sbuf);
    float inv = rsqrtf(q * (1.0f / D_) + 1e-5f);
    float4 gv = *(const float4*)(g + c);
    float4 bv = *(const float4*)(be + c);
    ushort4 o;
    o.x = f2bf(dx*inv*gv.x + bv.x);
    o.y = f2bf(dy*inv*gv.y + bv.y);
    o.z = f2bf(dz*inv*gv.z + bv.z);
    o.w = f2bf(dw*inv*gv.w + bv.w);
    *(ushort4*)(dst + (size_t)row*D_ + c) = o;
}

// ---------------- split-K=2 reduce + residual + LayerNorm2 ----------------
__global__ __launch_bounds__(256) void reduce2_ln2_kernel(
    const float* __restrict__ part, const float* __restrict__ bo,
    const float* __restrict__ x_full, const float* __restrict__ g,
    const float* __restrict__ be, float* __restrict__ x2,
    ushort* __restrict__ ln2_bf)
{
    __shared__ float sbuf[4];
    int row = blockIdx.x;
    int c = threadIdx.x << 2;
    size_t o = (size_t)row * D_ + c;
    float4 a  = *(const float4*)(part + o);
    float4 b2 = *(const float4*)(part + (size_t)BT_*D_ + o);
    float4 bb = *(const float4*)(bo + c);
    int rr = (row >> 10)*L_ + PREF + (row & (T_-1));
    float4 rv = *(const float4*)(x_full + (size_t)rr*D_ + c);
    float4 v;
    v.x = a.x + b2.x + bb.x + rv.x;
    v.y = a.y + b2.y + bb.y + rv.y;
    v.z = a.z + b2.z + bb.z + rv.z;
    v.w = a.w + b2.w + bb.w + rv.w;
    *(float4*)(x2 + o) = v;

    float s = v.x + v.y + v.z + v.w;
    s = block_reduce_sum256(s, sbuf);
    float mu = s * (1.0f / D_);
    float dx = v.x - mu, dy = v.y - mu, dz = v.z - mu, dw = v.w - mu;
    float q = dx*dx + dy*dy + dz*dz + dw*dw;
    q = block_reduce_sum256(q, sbuf);
    float inv = rsqrtf(q * (1.0f / D_) + 1e-5f);
    float4 gv = *(const float4*)(g + c);
    float4 bv = *(const float4*)(be + c);
    ushort4 ov;
    ov.x = f2bf(dx*inv*gv.x + bv.x);
    ov.y = f2bf(dy*inv*gv.y + bv.y);
    ov.z = f2bf(dz*inv*gv.z + bv.z);
    ov.w = f2bf(dw*inv*gv.w + bv.w);
    *(ushort4*)(ln2_bf + o) = ov;
}

// ---------------- split-K=4 reduce + bias + residual -> out ----------------
__global__ __launch_bounds__(256) void reduce4_out_kernel(
    const float* __restrict__ part, const float* __restrict__ b2,
    const float* __restrict__ x2, float* __restrict__ out)
{
    int row = blockIdx.x;
    int c = threadIdx.x << 2;
    size_t o = (size_t)row * D_ + c;
    const size_t S = (size_t)BT_ * D_;
    float4 p0 = *(const float4*)(part + o);
    float4 p1 = *(const float4*)(part + S + o);
    float4 p2 = *(const float4*)(part + 2*S + o);
    float4 p3 = *(const float4*)(part + 3*S + o);
    float4 bb = *(const float4*)(b2 + c);
    float4 rv = *(const float4*)(x2 + o);
    float4 v;
    v.x = p0.x + p1.x + p2.x + p3.x + bb.x + rv.x;
    v.y = p0.y + p1.y + p2.y + p3.y + bb.y + rv.y;
    v.z = p0.z + p1.z + p2.z + p3.z + bb.z + rv.z;
    v.w = p0.w + p1.w + p2.w + p3.w + bb.w + rv.w;
    *(float4*)(out + o) = v;
}

// ---------------- bf16 MFMA GEMM, 2-phase dbuf, wide LDS-transposed epilogue
// modes: 1 f32+bias+res(row-major) | 2 f32+bias+res(strided x_full) |
//        3 bf16 relu(+bias)^2 | 4 f32 partial (z-offset) |
//        7 fused QKV (Q/K RoPE via table, V transposed head-major)
__global__ __launch_bounds__(256) void gemm_bf16_kernel(
    const ushort* __restrict__ A, const ushort* __restrict__ Bt,
    const float* __restrict__ bias, const float* __restrict__ res,
    const float* __restrict__ rtab, void* __restrict__ Cout,
    int Nc, int Kstride, int Klen, int mode)
{
    __shared__ ushort SM[16384];    // 32 KiB: A dbuf (16K) | B dbuf (16K)
    int tid = threadIdx.x;
    int lane = tid & 63, w = tid >> 6;
    int wm = w >> 1, wn = w & 1;
    int row0 = blockIdx.y << 7, col0 = blockIdx.x << 7;
    int l15 = lane & 15, l4 = lane >> 4;
    int kbase = blockIdx.z * Klen;

    f32x4 acc[4][4] = {};

    int r_a = tid >> 2;
    int sc  = tid & 3;
    int lcOff = (sc ^ ((r_a >> 1) & 3)) << 3;
    const ushort* Arow  = A  + (size_t)(row0 + r_a)      * Kstride + kbase;
    const ushort* Arow2 = A  + (size_t)(row0 + 64 + r_a) * Kstride + kbase;
    const ushort* Brow  = Bt + (size_t)(col0 + r_a)      * Kstride + kbase;
    const ushort* Brow2 = Bt + (size_t)(col0 + 64 + r_a) * Kstride + kbase;

#define STAGE(buf, k0rel)                                                          \
    do {                                                                           \
        gl_lds16(Arow  + (k0rel) + lcOff, (char*)(SM + (buf)*4096) + (tid << 4));  \
        gl_lds16(Arow2 + (k0rel) + lcOff, (char*)(SM + (buf)*4096) + ((256+tid) << 4)); \
        gl_lds16(Brow  + (k0rel) + lcOff, (char*)(SM + 8192 + (buf)*4096) + (tid << 4)); \
        gl_lds16(Brow2 + (k0rel) + lcOff, (char*)(SM + 8192 + (buf)*4096) + ((256+tid) << 4)); \
    } while (0)

    STAGE(0, 0);
    __syncthreads();
    int cur = 0;
    for (int k0 = 0; k0 < Klen; k0 += 32) {
        if (k0 + 32 < Klen) STAGE(cur ^ 1, k0 + 32);
        const ushort* As = SM + cur*4096;
        const ushort* Bs = SM + 8192 + cur*4096;
        bf16x8 af[4], bfr[4];
#pragma unroll
        for (int i = 0; i < 4; ++i) {
            int ra = (wm << 6) + (i << 4) + l15;
            af[i]  = *(const bf16x8*)(&As[ra*32 + ((l4 ^ ((ra >> 1) & 3)) << 3)]);
            int rb = (wn << 6) + (i << 4) + l15;
            bfr[i] = *(const bf16x8*)(&Bs[rb*32 + ((l4 ^ ((rb >> 1) & 3)) << 3)]);
        }
#pragma unroll
        for (int i = 0; i < 4; ++i)
#pragma unroll
            for (int j = 0; j < 4; ++j)
                acc[i][j] = __builtin_amdgcn_mfma_f32_16x16x32_bf16(af[i], bfr[j], acc[i][j], 0, 0, 0);
        __syncthreads();
        cur ^= 1;
    }
#undef STAGE

    float bcol[4] = {0.f, 0.f, 0.f, 0.f};
    if (mode != 4) {
#pragma unroll
        for (int j = 0; j < 4; ++j) bcol[j] = bias[col0 + (wn << 6) + (j << 4) + l15];
    }

    // ---- epilogue: per-wave 16x68 f32 LDS transpose -> wide stores ----
    float* scr = (float*)SM + w * 1088;
    int rr = lane >> 2, cseg = lane & 3;
    int colbase = col0 + (wn << 6);
    int hh = ((col0 & 1023) + (wn << 6)) >> 6;     // head (mode 7)
    int which = col0 >> 10;                         // 0 Q, 1 K, 2 V (mode 7)

#pragma unroll
    for (int i = 0; i < 4; ++i) {
        LGKM0;   // prior chunk's scratch reads done before overwrite
#pragma unroll
        for (int j = 0; j < 4; ++j)
#pragma unroll
            for (int r = 0; r < 4; ++r) {
                float v = acc[i][j][r];
                if (mode != 4) v += bcol[j];
                if (mode == 3) { v = fmaxf(v, 0.f); v *= v; }
                scr[((l4 << 2) + r)*68 + (j << 4) + l15] = v;
            }
        LGKM0;
        int grow = row0 + (wm << 6) + (i << 4) + rr;

        if (mode == 7 && which == 2) {
            // V^T: lane owns d = lane; read scratch column, 16 contiguous pos
            int r0g = row0 + (wm << 6) + (i << 4);
            int bb = r0g / L_;
            int posb = r0g - bb * L_;              // 16-aligned, never straddles
            float4 v0, v1, v2, v3;
            v0.x = scr[ 0*68 + lane]; v0.y = scr[ 1*68 + lane];
            v0.z = scr[ 2*68 + lane]; v0.w = scr[ 3*68 + lane];
            v1.x = scr[ 4*68 + lane]; v1.y = scr[ 5*68 + lane];
            v1.z = scr[ 6*68 + lane]; v1.w = scr[ 7*68 + lane];
            v2.x = scr[ 8*68 + lane]; v2.y = scr[ 9*68 + lane];
            v2.z = scr[10*68 + lane]; v2.w = scr[11*68 + lane];
            v3.x = scr[12*68 + lane]; v3.y = scr[13*68 + lane];
            v3.z = scr[14*68 + lane]; v3.w = scr[15*68 + lane];
            ushort* O = (ushort*)Cout + 2*(size_t)BL_*D_;
            size_t base = ((size_t)(bb*H_ + hh)*64 + lane)*L_ + posb;
            *(u16x8*)(O + base)     = pack8(v0, v1);
            *(u16x8*)(O + base + 8) = pack8(v2, v3);
        } else if (mode == 7) {
            // Q/K: lane owns one pos row, 16 cols; RoPE from table
            int bb = grow / L_;
            int pos = grow - bb * L_;
            float4 a0 = *(float4*)&scr[rr*68 + (cseg << 4) + 0];
            float4 a1 = *(float4*)&scr[rr*68 + (cseg << 4) + 4];
            float4 a2 = *(float4*)&scr[rr*68 + (cseg << 4) + 8];
            float4 a3 = *(float4*)&scr[rr*68 + (cseg << 4) + 12];
            if (cseg < 2) {
                int oseg = cseg ^ 1;
                float4 p0 = *(float4*)&scr[rr*68 + (oseg << 4) + 0];
                float4 p1 = *(float4*)&scr[rr*68 + (oseg << 4) + 4];
                float4 p2 = *(float4*)&scr[rr*68 + (oseg << 4) + 8];
                float4 p3 = *(float4*)&scr[rr*68 + (oseg << 4) + 12];
                const float* tb = rtab + pos*32;
                float4 c0 = *(const float4*)(tb + 0),  c1 = *(const float4*)(tb + 4);
                float4 c2 = *(const float4*)(tb + 8),  c3 = *(const float4*)(tb + 12);
                float4 s0 = *(const float4*)(tb + 16), s1 = *(const float4*)(tb + 20);
                float4 s2 = *(const float4*)(tb + 24), s3 = *(const float4*)(tb + 28);
                float sg = (cseg == 0) ? -1.f : 1.f;
                a0.x = a0.x*c0.x + sg*p0.x*s0.x; a0.y = a0.y*c0.y + sg*p0.y*s0.y;
                a0.z = a0.z*c0.z + sg*p0.z*s0.z; a0.w = a0.w*c0.w + sg*p0.w*s0.w;
                a1.x = a1.x*c1.x + sg*p1.x*s1.x; a1.y = a1.y*c1.y + sg*p1.y*s1.y;
                a1.z = a1.z*c1.z + sg*p1.z*s1.z; a1.w = a1.w*c1.w + sg*p1.w*s1.w;
                a2.x = a2.x*c2.x + sg*p2.x*s2.x; a2.y = a2.y*c2.y + sg*p2.y*s2.y;
                a2.z = a2.z*c2.z + sg*p2.z*s2.z; a2.w = a2.w*c2.w + sg*p2.w*s2.w;
                a3.x = a3.x*c3.x + sg*p3.x*s3.x; a3.y = a3.y*c3.y + sg*p3.y*s3.y;
                a3.z = a3.z*c3.z + sg*p3.z*s3.z; a3.w = a3.w*c3.w + sg*p3.w*s3.w;
            }
            ushort* O = (ushort*)Cout + (size_t)which * ((size_t)BL_*D_);
            size_t base = (((size_t)(bb*H_ + hh)*L_ + pos) << 6) + (cseg << 4);
            *(u16x8*)(O + base)     = pack8(a0, a1);
            *(u16x8*)(O + base + 8) = pack8(a2, a3);
        } else {
            float4 q0 = *(float4*)&scr[rr*68 + (cseg << 4) + 0];
            float4 q1 = *(float4*)&scr[rr*68 + (cseg << 4) + 4];
            float4 q2 = *(float4*)&scr[rr*68 + (cseg << 4) + 8];
            float4 q3 = *(float4*)&scr[rr*68 + (cseg << 4) + 12];
            int gcol = colbase + (cseg << 4);
            if (mode == 3) {
                ushort* O = (ushort*)Cout;
                *(u16x8*)(O + (size_t)grow*Nc + gcol)     = pack8(q0, q1);
                *(u16x8*)(O + (size_t)grow*Nc + gcol + 8) = pack8(q2, q3);
            } else {
                if (mode == 1 || mode == 2) {
                    size_t roff;
                    if (mode == 2) {
                        int rs = (grow >> 10)*L_ + PREF + (grow & (T_-1));
                        roff = (size_t)rs*D_ + gcol;
                    } else {
                        roff = (size_t)grow*Nc + gcol;
                    }
                    float4 r0 = *(const float4*)(res + roff);
                    float4 r1 = *(const float4*)(res + roff + 4);
                    float4 r2 = *(const float4*)(res + roff + 8);
                    float4 r3 = *(const float4*)(res + roff + 12);
                    q0.x += r0.x; q0.y += r0.y; q0.z += r0.z; q0.w += r0.w;
                    q1.x += r1.x; q1.y += r1.y; q1.z += r1.z; q1.w += r1.w;
                    q2.x += r2.x; q2.y += r2.y; q2.z += r2.z; q2.w += r2.w;
                    q3.x += r3.x; q3.y += r3.y; q3.z += r3.z; q3.w += r3.w;
                }
                float* O = (float*)Cout;
                if (mode == 4) O += (size_t)blockIdx.z * ((size_t)BT_ * D_);
                size_t o = (size_t)grow*Nc + gcol;
                *(float4*)(O + o)      = q0;
                *(float4*)(O + o + 4)  = q1;
                *(float4*)(O + o + 8)  = q2;
                *(float4*)(O + o + 12) = q3;
            }
        }
    }
}

// ---------------- MFMA flash attention, swapped-operand softmax ----------
__global__ __launch_bounds__(256) void attn_mfma_kernel(
    const ushort* __restrict__ qhd, const ushort* __restrict__ khd,
    const ushort* __restrict__ vt, ushort* __restrict__ attn_bf)
{
    __shared__ ushort Ks[2][64*64];
    __shared__ ushort Vs[2][64*64];
    __shared__ ushort Ps[4*16*64];

    int bid = blockIdx.x;
    int qb = 15 - (bid & 15);
    int h  = (bid >> 4) & (H_ - 1);
    int b  = bid >> 8;
    int tid = threadIdx.x, lane = tid & 63, w = tid >> 6;
    int l15 = lane & 15, lg = lane >> 4;
    int i0 = PREF + (qb << 6);
    int wq0 = w << 4;
    size_t bh = (size_t)(b * H_ + h);

    const ushort* qrow = qhd + (bh * L_ + i0 + wq0 + l15) * 64;
    bf16x8 bq0 = *(const bf16x8*)(qrow + (lg << 3));
    bf16x8 bq1 = *(const bf16x8*)(qrow + 32 + (lg << 3));

    f32x4 acc[4] = {};
    float mrun = -INFINITY;
    float lsum = 0.f;

    int srow = tid >> 3;
    int sslot = tid & 7;
    ushort* Ps_w = Ps + (w << 10);
    const float SC = 0.125f * 1.4426950408889634f;
    int qcap = i0 + wq0 + l15;

#define STAGE_T(buf, t)                                                     \
    do { int j0s = (t) << 6;                                                \
        gl_lds16(khd + (bh * L_ + j0s + srow) * 64 + ((sslot ^ (srow & 7)) << 3),      \
                 (char*)Ks[buf] + (tid << 4));                              \
        gl_lds16(khd + (bh * L_ + j0s + 32 + srow) * 64 + ((sslot ^ ((32+srow) & 7)) << 3), \
                 (char*)Ks[buf] + ((256 + tid) << 4));                      \
        gl_lds16(vt + (bh * 64 + srow) * L_ + j0s + ((sslot ^ (srow & 7)) << 3),       \
                 (char*)Vs[buf] + (tid << 4));                              \
        gl_lds16(vt + (bh * 64 + 32 + srow) * L_ + j0s + ((sslot ^ ((32+srow) & 7)) << 3), \
                 (char*)Vs[buf] + ((256 + tid) << 4));                      \
    } while (0)

    int ntile = 4 + qb;
    STAGE_T(0, 0);
    __syncthreads();
    int cur = 0;
    for (int t = 0; t < ntile; ++t) {
        if (t + 1 < ntile) STAGE_T(cur ^ 1, t + 1);
        const ushort* Kc = Ks[cur];
        const ushort* Vc = Vs[cur];

        f32x4 s4[4];
        __builtin_amdgcn_s_setprio(1);
#pragma unroll
        for (int st = 0; st < 4; ++st) {
            int rk = (st << 4) + l15;
            bf16x8 ak0 = *(const bf16x8*)(Kc + (rk << 6) + ((lg       ^ (rk & 7)) << 3));
            bf16x8 ak1 = *(const bf16x8*)(Kc + (rk << 6) + (((4 + lg) ^ (rk & 7)) << 3));
            f32x4 z = {};
            z = __builtin_amdgcn_mfma_f32_16x16x32_bf16(ak0, bq0, z, 0, 0, 0);
            z = __builtin_amdgcn_mfma_f32_16x16x32_bf16(ak1, bq1, z, 0, 0, 0);
            s4[st] = z;
        }
        __builtin_amdgcn_s_setprio(0);

        int j0 = t << 6;
        float sv[4][4];
        bool diag = (t == ntile - 1);
        int kb = j0 + (lg << 2);
#pragma unroll
        for (int st = 0; st < 4; ++st)
#pragma unroll
            for (int r = 0; r < 4; ++r) {
                float s = s4[st][r] * SC;
                if (diag && (kb + (st << 4) + r > qcap)) s = -INFINITY;
                sv[st][r] = s;
            }
        float bm;
        {
            float t0 = fmaxf(fmaxf(sv[0][0], sv[0][1]), fmaxf(sv[0][2], sv[0][3]));
            float t1 = fmaxf(fmaxf(sv[1][0], sv[1][1]), fmaxf(sv[1][2], sv[1][3]));
            float t2 = fmaxf(fmaxf(sv[2][0], sv[2][1]), fmaxf(sv[2][2], sv[2][3]));
            float t3 = fmaxf(fmaxf(sv[3][0], sv[3][1]), fmaxf(sv[3][2], sv[3][3]));
            bm = fmaxf(fmaxf(t0, t1), fmaxf(t2, t3));
        }
        bm = fmaxf(bm, __shfl_xor(bm, 16, 64));
        bm = fmaxf(bm, __shfl_xor(bm, 32, 64));

        float mn = fmaxf(mrun, bm);
        float cr = exp2f(mrun - mn);
        mrun = mn;
        float pe[4][4];
        float ps = 0.f;
#pragma unroll
        for (int st = 0; st < 4; ++st)
#pragma unroll
            for (int r = 0; r < 4; ++r) {
                float e = exp2f(sv[st][r] - mn);
                pe[st][r] = e; ps += e;
            }
        ps += __shfl_xor(ps, 16, 64);
        ps += __shfl_xor(ps, 32, 64);
        lsum = lsum * cr + ps;
#pragma unroll
        for (int su = 0; su < 4; ++su) acc[su] *= cr;

#pragma unroll
        for (int st = 0; st < 4; ++st) {
            int slot = (st << 1) + (lg >> 1);
            int sb = ((lg & 1) << 3);
#pragma unroll
            for (int rp = 0; rp < 2; ++rp) {
                uint u = (uint)f2bf(pe[st][2*rp]) | ((uint)f2bf(pe[st][2*rp+1]) << 16);
                *(uint*)((char*)Ps_w + l15*128 + ((slot ^ (l15 & 7)) << 4) + sb + (rp << 2)) = u;
            }
        }
        {
            bf16x8 bp0 = *(const bf16x8*)((char*)Ps_w + l15*128 + ((lg       ^ (l15 & 7)) << 4));
            bf16x8 bp1 = *(const bf16x8*)((char*)Ps_w + l15*128 + (((4 + lg) ^ (l15 & 7)) << 4));
            __builtin_amdgcn_s_setprio(1);
#pragma unroll
            for (int su = 0; su < 4; ++su) {
                int rd = (su << 4) + l15;
                bf16x8 av0 = *(const bf16x8*)(Vc + (rd << 6) + ((lg       ^ (rd & 7)) << 3));
                bf16x8 av1 = *(const bf16x8*)(Vc + (rd << 6) + (((4 + lg) ^ (rd & 7)) << 3));
                acc[su] = __builtin_amdgcn_mfma_f32_16x16x32_bf16(av0, bp0, acc[su], 0, 0, 0);
                acc[su] = __builtin_amdgcn_mfma_f32_16x16x32_bf16(av1, bp1, acc[su], 0, 0, 0);
            }
            __builtin_amdgcn_s_setprio(0);
        }
        __syncthreads();
        cur ^= 1;
    }
#undef STAGE_T

    float rl = 1.0f / lsum;
    size_t orow = (size_t)b * T_ + (i0 - PREF) + wq0 + l15;
#pragma unroll
    for (int su = 0; su < 4; ++su) {
        ushort4 o4;
        o4.x = f2bf(acc[su][0] * rl);
        o4.y = f2bf(acc[su][1] * rl);
        o4.z = f2bf(acc[su][2] * rl);
        o4.w = f2bf(acc[su][3] * rl);
        *(ushort4*)(attn_bf + orow * D_ + (h << 6) + (su << 4) + (lg << 2)) = o4;
    }
}

// ---------------- launch ----------------
extern "C" void kernel_launch(void* const* d_in, const int* in_sizes, int n_in,
                              void* d_out, int out_size, void* d_ws, size_t ws_size,
                              hipStream_t stream) {
    const float* x   = (const float*)d_in[0];
    const float* mem = (const float*)d_in[1];
    const float* nmr = (const float*)d_in[2];
    const float* Wq  = (const float*)d_in[3];
    const float* bq  = (const float*)d_in[4];
    const float* Wk  = (const float*)d_in[5];
    const float* bk  = (const float*)d_in[6];
    const float* Wv  = (const float*)d_in[7];
    const float* bv  = (const float*)d_in[8];
    const float* Wo  = (const float*)d_in[9];
    const float* bo  = (const float*)d_in[10];
    const float* W1  = (const float*)d_in[11];
    const float* b1  = (const float*)d_in[12];
    const float* W2  = (const float*)d_in[13];
    const float* b2  = (const float*)d_in[14];
    const float* g1  = (const float*)d_in[15];
    const float* be1 = (const float*)d_in[16];
    const float* g2  = (const float*)d_in[17];
    const float* be2 = (const float*)d_in[18];
    float* out = (float*)d_out;

    const size_t BLD = (size_t)BL_ * D_;
    const size_t BTD = (size_t)BT_ * D_;

    float* f = (float*)d_ws;
    float* x_full = f;                         // BLD f32
    float* x2     = f + BLD;                   // BTD f32
    float* bqkv   = x2 + BTD;                  // 4096 f32 (3072 used)
    float* rtab   = bqkv + 4096;               // L_*32 f32
    ushort* bfb   = (ushort*)(rtab + (size_t)L_*32);
    ushort* xa_bf   = bfb;                     // BLD  (reused as attn_bf)
    ushort* qhd     = bfb + BLD;               // BLD  (reused as ln2_bf)
    ushort* khd     = bfb + 2*BLD;             // BLD
    ushort* vt      = bfb + 3*BLD;             // BLD
    ushort* h1_bf   = bfb + 4*BLD;             // BT_*FFN_
    ushort* wq_bf = h1_bf + (size_t)BT_*FFN_;  // Q|K|V|Wo|W1|W2 contiguous
    ushort* wk_bf = wq_bf + (size_t)D_*D_;
    ushort* wv_bf = wk_bf + (size_t)D_*D_;
    ushort* wo_bf = wv_bf + (size_t)D_*D_;
    ushort* w1_bf = wo_bf + (size_t)D_*D_;
    ushort* w2_bf = w1_bf + (size_t)D_*FFN_;
    float* partials = (float*)(w2_bf + (size_t)FFN_*D_);   // 4*BTD f32
    ushort* attn_bf = xa_bf;
    ushort* ln2_bf  = qhd;

    size_t need = (size_t)((char*)(partials + 4*BTD) - (char*)d_ws);
    bool use_split = (ws_size >= need);

    // weight prep + tables
    wtr4_kernel<<<dim3(16, 16, 4), 256, 0, stream>>>(Wq, Wk, Wv, Wo,
                                                     wq_bf, wk_bf, wv_bf, wo_bf);
    wtr_kernel<<<dim3(FFN_/64, D_/64),   256, 0, stream>>>(W1, w1_bf, D_,   FFN_);
    wtr_kernel<<<dim3(D_/64,   FFN_/64), 256, 0, stream>>>(W2, w2_bf, FFN_, D_);
    ropetab_kernel<<<(L_*32 + 255)/256, 256, 0, stream>>>(rtab);
    bias_cat_kernel<<<12, 256, 0, stream>>>(bq, bk, bv, bqkv);

    ln1_concat_kernel<<<BL_, 256, 0, stream>>>(x, mem, nmr, g1, be1, x_full, xa_bf);

    // fused QKV projection (N=3072) with table-RoPE / layout epilogues
    gemm_bf16_kernel<<<dim3(3072/128, BL_/128), 256, 0, stream>>>(
        xa_bf, wq_bf, bqkv, nullptr, rtab, qhd, D_, D_, D_, 7);

    attn_mfma_kernel<<<B_*H_*(T_/64), 256, 0, stream>>>(qhd, khd, vt, attn_bf);

    if (use_split) {
        gemm_bf16_kernel<<<dim3(D_/128, BT_/128, 2), 256, 0, stream>>>(
            attn_bf, wo_bf, nullptr, nullptr, nullptr, partials, D_, D_, D_/2, 4);
        reduce2_ln2_kernel<<<BT_, 256, 0, stream>>>(partials, bo, x_full, g2, be2, x2, ln2_bf);
    } else {
        gemm_bf16_kernel<<<dim3(D_/128, BT_/128), 256, 0, stream>>>(
            attn_bf, wo_bf, bo, x_full, nullptr, x2, D_, D_, D_, 2);
        ln2_kernel<<<BT_, 256, 0, stream>>>(x2, g2, be2, ln2_bf);
    }

    // h1 = relu(xf @ W1 + b1)^2
    gemm_bf16_kernel<<<dim3(FFN_/128, BT_/128), 256, 0, stream>>>(
        ln2_bf, w1_bf, b1, nullptr, nullptr, h1_bf, FFN_, D_, D_, 3);

    if (use_split) {
        gemm_bf16_kernel<<<dim3(D_/128, BT_/128, 4), 256, 0, stream>>>(
            h1_bf, w2_bf, nullptr, nullptr, nullptr, partials, D_, FFN_, FFN_/4, 4);
        reduce4_out_kernel<<<BT_, 256, 0, stream>>>(partials, b2, x2, out);
    } else {
        gemm_bf16_kernel<<<dim3(D_/128, BT_/128), 256, 0, stream>>>(
            h1_bf, w2_bf, b2, x2, nullptr, out, D_, FFN_, FFN_, 1);
    }
}

// Round 7
// 272.196 us; speedup vs baseline: 9.4523x; 1.1141x over previous
//
#include <hip/hip_runtime.h>
#include <hip/hip_bf16.h>
#include <math.h>

#define D_   1024
#define H_   16
#define DH_  64
#define FFN_ 4096
#define B_   4
#define T_   1024
#define M_   128
#define N_   64
#define PREF 192
#define L_   1216
#define BL_  (B_*L_)   // 4864
#define BT_  (B_*T_)   // 4096

typedef __attribute__((ext_vector_type(4))) float f32x4;
typedef __attribute__((ext_vector_type(8))) short bf16x8;
typedef __attribute__((ext_vector_type(8))) unsigned short u16x8;
typedef const __attribute__((address_space(1))) void gvoid_t;
typedef __attribute__((address_space(3))) void lvoid_t;

#define LGKM0 asm volatile("s_waitcnt lgkmcnt(0)" ::: "memory")

__device__ __forceinline__ void gl_lds16(const void* g, void* l) {
    __builtin_amdgcn_global_load_lds((gvoid_t*)g, (lvoid_t*)l, 16, 0, 0);
}

__device__ __forceinline__ ushort f2bf(float x) {
    union { __hip_bfloat16 h; ushort u; } cv;
    cv.h = __float2bfloat16(x);
    return cv.u;
}

__device__ __forceinline__ u16x8 pack8(float4 a, float4 b) {
    u16x8 r;
    r[0]=f2bf(a.x); r[1]=f2bf(a.y); r[2]=f2bf(a.z); r[3]=f2bf(a.w);
    r[4]=f2bf(b.x); r[5]=f2bf(b.y); r[6]=f2bf(b.z); r[7]=f2bf(b.w);
    return r;
}

// ---------------- block reduce helper ----------------
__device__ __forceinline__ float block_reduce_sum256(float v, float* sbuf) {
#pragma unroll
    for (int o = 32; o > 0; o >>= 1) v += __shfl_xor(v, o, 64);
    int w = threadIdx.x >> 6;
    if ((threadIdx.x & 63) == 0) sbuf[w] = v;
    __syncthreads();
    float r = sbuf[0] + sbuf[1] + sbuf[2] + sbuf[3];
    __syncthreads();
    return r;
}

// ---------------- weight fp32 [K][Nc] -> bf16 W^T [Nc][K] ----------------
__device__ __forceinline__ void wtr_body(const float* __restrict__ W,
                                         ushort* __restrict__ Wt, int K, int Nc)
{
    __shared__ float tl[64][65];
    int c0 = blockIdx.x << 6, k0 = blockIdx.y << 6;
    int tid = threadIdx.x;
    int rr = tid >> 4, c4 = (tid & 15) << 2;
#pragma unroll
    for (int p = 0; p < 4; ++p) {
        int r = (p << 4) + rr;
        float4 v = *(const float4*)(W + (size_t)(k0 + r) * Nc + c0 + c4);
        tl[r][c4+0] = v.x; tl[r][c4+1] = v.y; tl[r][c4+2] = v.z; tl[r][c4+3] = v.w;
    }
    __syncthreads();
#pragma unroll
    for (int p = 0; p < 4; ++p) {
        int rT = (p << 4) + rr;
        ushort4 uv;
        uv.x = f2bf(tl[c4+0][rT]);
        uv.y = f2bf(tl[c4+1][rT]);
        uv.z = f2bf(tl[c4+2][rT]);
        uv.w = f2bf(tl[c4+3][rT]);
        *(ushort4*)(Wt + (size_t)(c0 + rT) * K + k0 + c4) = uv;
    }
}

__global__ __launch_bounds__(256) void wtr_kernel(
    const float* __restrict__ W, ushort* __restrict__ Wt, int K, int Nc)
{ wtr_body(W, Wt, K, Nc); }

__global__ __launch_bounds__(256) void wtr4_kernel(
    const float* __restrict__ W0, const float* __restrict__ W1,
    const float* __restrict__ W2, const float* __restrict__ W3,
    ushort* __restrict__ T0, ushort* __restrict__ T1,
    ushort* __restrict__ T2, ushort* __restrict__ T3)
{
    const float* W; ushort* T;
    switch (blockIdx.z) {
        case 0: W = W0; T = T0; break;
        case 1: W = W1; T = T1; break;
        case 2: W = W2; T = T2; break;
        default: W = W3; T = T3; break;
    }
    wtr_body(W, T, D_, D_);
}

// ---------------- RoPE cos/sin table: [pos][0..15]=cos, [16..31]=sin ------
__global__ __launch_bounds__(256) void ropetab_kernel(float* __restrict__ tab)
{
    int i = blockIdx.x * 256 + threadIdx.x;
    if (i >= L_ * 32) return;
    int pos = i >> 5, idx = i & 31;
    int fi = idx & 15;
    float invf = exp2f(-(float)fi * 0.83048202372f);   // 10000^(-fi/16)
    float th = (float)pos * invf;
    tab[i] = (idx < 16) ? cosf(th) : sinf(th);
}

// ---------------- bias concat (bq|bk|bv -> 3072) ----------------
__global__ __launch_bounds__(256) void bias_cat_kernel(
    const float* __restrict__ bq, const float* __restrict__ bk,
    const float* __restrict__ bv, float* __restrict__ o)
{
    int i = blockIdx.x * 256 + threadIdx.x;
    float v = (i < 1024) ? bq[i] : (i < 2048 ? bk[i - 1024] : bv[i - 2048]);
    o[i] = v;
}

// ---------------- concat + LayerNorm1: x_full f32, xa bf16 ----------------
__global__ __launch_bounds__(256) void ln1_concat_kernel(
    const float* __restrict__ x, const float* __restrict__ mem,
    const float* __restrict__ nmr, const float* __restrict__ g,
    const float* __restrict__ be, float* __restrict__ x_full,
    ushort* __restrict__ xa_bf)
{
    __shared__ float sbuf[4];
    int row = blockIdx.x;
    int b = row / L_, pos = row % L_;
    const float* src;
    if (pos < M_)          src = mem + ((size_t)b*M_ + pos)      * D_;
    else if (pos < M_+N_)  src = nmr + ((size_t)b*N_ + (pos-M_)) * D_;
    else                   src = x   + ((size_t)b*T_ + (pos-PREF))*D_;

    int c = threadIdx.x << 2;
    float4 v = *(const float4*)(src + c);
    float s = v.x + v.y + v.z + v.w;
    s = block_reduce_sum256(s, sbuf);
    float mu = s * (1.0f / D_);
    float dx = v.x - mu, dy = v.y - mu, dz = v.z - mu, dw = v.w - mu;
    float q = dx*dx + dy*dy + dz*dz + dw*dw;
    q = block_reduce_sum256(q, sbuf);
    float inv = rsqrtf(q * (1.0f / D_) + 1e-5f);
    float4 gv = *(const float4*)(g + c);
    float4 bv = *(const float4*)(be + c);
    ushort4 o;
    o.x = f2bf(dx*inv*gv.x + bv.x);
    o.y = f2bf(dy*inv*gv.y + bv.y);
    o.z = f2bf(dz*inv*gv.z + bv.z);
    o.w = f2bf(dw*inv*gv.w + bv.w);
    *(float4*)(x_full + (size_t)row*D_ + c) = v;
    *(ushort4*)(xa_bf + (size_t)row*D_ + c) = o;
}

// ---------------- LayerNorm2: f32 in, bf16 out ----------------------------
__global__ __launch_bounds__(256) void ln2_kernel(
    const float* __restrict__ src, const float* __restrict__ g,
    const float* __restrict__ be, ushort* __restrict__ dst)
{
    __shared__ float sbuf[4];
    int row = blockIdx.x;
    int c = threadIdx.x << 2;
    float4 v = *(const float4*)(src + (size_t)row*D_ + c);
    float s = v.x + v.y + v.z + v.w;
    s = block_reduce_sum256(s, sbuf);
    float mu = s * (1.0f / D_);
    float dx = v.x - mu, dy = v.y - mu, dz = v.z - mu, dw = v.w - mu;
    float q = dx*dx + dy*dy + dz*dz + dw*dw;
    q = block_reduce_sum256(q, sbuf);
    float inv = rsqrtf(q * (1.0f / D_) + 1e-5f);
    float4 gv = *(const float4*)(g + c);
    float4 bv = *(const float4*)(be + c);
    ushort4 o;
    o.x = f2bf(dx*inv*gv.x + bv.x);
    o.y = f2bf(dy*inv*gv.y + bv.y);
    o.z = f2bf(dz*inv*gv.z + bv.z);
    o.w = f2bf(dw*inv*gv.w + bv.w);
    *(ushort4*)(dst + (size_t)row*D_ + c) = o;
}

// ---------------- 256-thr bf16 MFMA GEMM (QKV path, mode 7) ---------------
__global__ __launch_bounds__(256) void gemm_bf16_kernel(
    const ushort* __restrict__ A, const ushort* __restrict__ Bt,
    const float* __restrict__ bias, const float* __restrict__ rtab,
    void* __restrict__ Cout, int Nc, int Kstride, int Klen, int mode)
{
    __shared__ ushort SM[16384];    // A dbuf 16K | B dbuf 16K (bytes: 32K)
    int tid = threadIdx.x;
    int lane = tid & 63, w = tid >> 6;
    int wm = w >> 1, wn = w & 1;
    // XCD-aware bijective swizzle (grids are %8==0)
    int nx = gridDim.x;
    int flat = blockIdx.y * nx + blockIdx.x;
    int cpx = (nx * gridDim.y) >> 3;
    int sz = (flat & 7) * cpx + (flat >> 3);
    int row0 = (sz / nx) << 7, col0 = (sz % nx) << 7;
    int l15 = lane & 15, l4 = lane >> 4;

    f32x4 acc[4][4] = {};

    int r_a = tid >> 2;
    int sc  = tid & 3;
    int lcOff = (sc ^ ((r_a >> 1) & 3)) << 3;
    const ushort* Arow  = A  + (size_t)(row0 + r_a)      * Kstride;
    const ushort* Arow2 = A  + (size_t)(row0 + 64 + r_a) * Kstride;
    const ushort* Brow  = Bt + (size_t)(col0 + r_a)      * Kstride;
    const ushort* Brow2 = Bt + (size_t)(col0 + 64 + r_a) * Kstride;

#define STAGE(buf, k0rel)                                                          \
    do {                                                                           \
        gl_lds16(Arow  + (k0rel) + lcOff, (char*)(SM + (buf)*4096) + (tid << 4));  \
        gl_lds16(Arow2 + (k0rel) + lcOff, (char*)(SM + (buf)*4096) + ((256+tid) << 4)); \
        gl_lds16(Brow  + (k0rel) + lcOff, (char*)(SM + 8192 + (buf)*4096) + (tid << 4)); \
        gl_lds16(Brow2 + (k0rel) + lcOff, (char*)(SM + 8192 + (buf)*4096) + ((256+tid) << 4)); \
    } while (0)

    STAGE(0, 0);
    __syncthreads();
    int cur = 0;
    for (int k0 = 0; k0 < Klen; k0 += 32) {
        if (k0 + 32 < Klen) STAGE(cur ^ 1, k0 + 32);
        const ushort* As = SM + cur*4096;
        const ushort* Bs = SM + 8192 + cur*4096;
        bf16x8 af[4], bfr[4];
#pragma unroll
        for (int i = 0; i < 4; ++i) {
            int ra = (wm << 6) + (i << 4) + l15;
            af[i]  = *(const bf16x8*)(&As[ra*32 + ((l4 ^ ((ra >> 1) & 3)) << 3)]);
            int rb = (wn << 6) + (i << 4) + l15;
            bfr[i] = *(const bf16x8*)(&Bs[rb*32 + ((l4 ^ ((rb >> 1) & 3)) << 3)]);
        }
#pragma unroll
        for (int i = 0; i < 4; ++i)
#pragma unroll
            for (int j = 0; j < 4; ++j)
                acc[i][j] = __builtin_amdgcn_mfma_f32_16x16x32_bf16(af[i], bfr[j], acc[i][j], 0, 0, 0);
        __syncthreads();
        cur ^= 1;
    }
#undef STAGE

    float bcol[4];
#pragma unroll
    for (int j = 0; j < 4; ++j) bcol[j] = bias[col0 + (wn << 6) + (j << 4) + l15];

    // epilogue: per-wave 16x68 f32 LDS transpose -> wide stores
    float* scr = (float*)SM + w * 1088;
    int rr = lane >> 2, cseg = lane & 3;
    int hh = ((col0 & 1023) + (wn << 6)) >> 6;
    int which = col0 >> 10;                         // 0 Q, 1 K, 2 V

#pragma unroll
    for (int i = 0; i < 4; ++i) {
        LGKM0;
#pragma unroll
        for (int j = 0; j < 4; ++j)
#pragma unroll
            for (int r = 0; r < 4; ++r)
                scr[((l4 << 2) + r)*68 + (j << 4) + l15] = acc[i][j][r] + bcol[j];
        LGKM0;
        int grow = row0 + (wm << 6) + (i << 4) + rr;

        if (which == 2) {
            // V^T: lane owns d = lane; 16 contiguous pos per chunk
            int r0g = row0 + (wm << 6) + (i << 4);
            int bb = r0g / L_;
            int posb = r0g - bb * L_;
            float4 v0, v1, v2, v3;
            v0.x = scr[ 0*68 + lane]; v0.y = scr[ 1*68 + lane];
            v0.z = scr[ 2*68 + lane]; v0.w = scr[ 3*68 + lane];
            v1.x = scr[ 4*68 + lane]; v1.y = scr[ 5*68 + lane];
            v1.z = scr[ 6*68 + lane]; v1.w = scr[ 7*68 + lane];
            v2.x = scr[ 8*68 + lane]; v2.y = scr[ 9*68 + lane];
            v2.z = scr[10*68 + lane]; v2.w = scr[11*68 + lane];
            v3.x = scr[12*68 + lane]; v3.y = scr[13*68 + lane];
            v3.z = scr[14*68 + lane]; v3.w = scr[15*68 + lane];
            ushort* O = (ushort*)Cout + 2*(size_t)BL_*D_;
            size_t base = ((size_t)(bb*H_ + hh)*64 + lane)*L_ + posb;
            *(u16x8*)(O + base)     = pack8(v0, v1);
            *(u16x8*)(O + base + 8) = pack8(v2, v3);
        } else {
            int bb = grow / L_;
            int pos = grow - bb * L_;
            float4 a0 = *(float4*)&scr[rr*68 + (cseg << 4) + 0];
            float4 a1 = *(float4*)&scr[rr*68 + (cseg << 4) + 4];
            float4 a2 = *(float4*)&scr[rr*68 + (cseg << 4) + 8];
            float4 a3 = *(float4*)&scr[rr*68 + (cseg << 4) + 12];
            if (cseg < 2) {
                int oseg = cseg ^ 1;
                float4 p0 = *(float4*)&scr[rr*68 + (oseg << 4) + 0];
                float4 p1 = *(float4*)&scr[rr*68 + (oseg << 4) + 4];
                float4 p2 = *(float4*)&scr[rr*68 + (oseg << 4) + 8];
                float4 p3 = *(float4*)&scr[rr*68 + (oseg << 4) + 12];
                const float* tb = rtab + pos*32;
                float4 c0 = *(const float4*)(tb + 0),  c1 = *(const float4*)(tb + 4);
                float4 c2 = *(const float4*)(tb + 8),  c3 = *(const float4*)(tb + 12);
                float4 s0 = *(const float4*)(tb + 16), s1 = *(const float4*)(tb + 20);
                float4 s2 = *(const float4*)(tb + 24), s3 = *(const float4*)(tb + 28);
                float sg = (cseg == 0) ? -1.f : 1.f;
                a0.x = a0.x*c0.x + sg*p0.x*s0.x; a0.y = a0.y*c0.y + sg*p0.y*s0.y;
                a0.z = a0.z*c0.z + sg*p0.z*s0.z; a0.w = a0.w*c0.w + sg*p0.w*s0.w;
                a1.x = a1.x*c1.x + sg*p1.x*s1.x; a1.y = a1.y*c1.y + sg*p1.y*s1.y;
                a1.z = a1.z*c1.z + sg*p1.z*s1.z; a1.w = a1.w*c1.w + sg*p1.w*s1.w;
                a2.x = a2.x*c2.x + sg*p2.x*s2.x; a2.y = a2.y*c2.y + sg*p2.y*s2.y;
                a2.z = a2.z*c2.z + sg*p2.z*s2.z; a2.w = a2.w*c2.w + sg*p2.w*s2.w;
                a3.x = a3.x*c3.x + sg*p3.x*s3.x; a3.y = a3.y*c3.y + sg*p3.y*s3.y;
                a3.z = a3.z*c3.z + sg*p3.z*s3.z; a3.w = a3.w*c3.w + sg*p3.w*s3.w;
            }
            ushort* O = (ushort*)Cout + (size_t)which * ((size_t)BL_*D_);
            size_t base = (((size_t)(bb*H_ + hh)*L_ + pos) << 6) + (cseg << 4);
            *(u16x8*)(O + base)     = pack8(a0, a1);
            *(u16x8*)(O + base + 8) = pack8(a2, a3);
        }
    }
}

// ---------------- 512-thr GEMM: KG=1 -> 128x256 tile (FFN1);  -------------
// KG=2 -> 128x128 tile, in-block split-K (Wo / FFN2), no global partials.
// modes: 1 f32 +bias +res(row-major) | 2 f32 +bias +res(strided x_full) |
//        3 bf16 relu(+bias)^2
template<int KG>
__global__ __launch_bounds__(512) void gemm512_kernel(
    const ushort* __restrict__ A, const ushort* __restrict__ Bt,
    const float* __restrict__ bias, const float* __restrict__ res,
    void* __restrict__ Cout, int Nc, int Kstride, int Klen, int mode)
{
    constexpr int TN  = (KG == 1) ? 256 : 128;
    constexpr int SMU = (KG == 1) ? 41984 : 67584;   // ushorts
    __shared__ ushort SM[SMU];
    char* SMb = (char*)SM;

    int tid = threadIdx.x;
    int lane = tid & 63, w = tid >> 6;
    int l15 = lane & 15, l4 = lane >> 4;

    // XCD-aware bijective swizzle (grids are %8==0)
    int nx = gridDim.x;
    int flat = blockIdx.y * nx + blockIdx.x;
    int cpx = (nx * gridDim.y) >> 3;
    int sz = (flat & 7) * cpx + (flat >> 3);
    int row0 = (sz / nx) << 7, col0 = (sz % nx) * TN;

    int wm, wn, g;
    if (KG == 1) { g = 0; wm = w >> 2; wn = w & 3; }
    else         { g = w >> 2; wm = (w >> 1) & 1; wn = w & 1; }

    f32x4 acc[4][4] = {};
    const int kl = (KG == 2) ? (Klen >> 1) : Klen;
    const int kb = (KG == 2) ? g * kl : 0;

    int cur = 0;
    if (KG == 1) {
        int rA = tid >> 2, scA = tid & 3;
        int lcA = (scA ^ ((rA >> 1) & 3)) << 3;
        const ushort* Ar = A + (size_t)(row0 + rA) * Kstride + lcA;
        int lcB1 = (scA ^ (((128 + rA) >> 1) & 3)) << 3;
        const ushort* Br0 = Bt + (size_t)(col0 + rA)       * Kstride + lcA;
        const ushort* Br1 = Bt + (size_t)(col0 + 128 + rA) * Kstride + lcB1;
#define STG1(buf, k0rel)                                                        \
        do {                                                                    \
            gl_lds16(Ar  + (k0rel), SMb + (buf)*8192 + (tid << 4));             \
            gl_lds16(Br0 + (k0rel), SMb + 16384 + (buf)*16384 + (tid << 4));    \
            gl_lds16(Br1 + (k0rel), SMb + 16384 + (buf)*16384 + 8192 + (tid << 4)); \
        } while (0)
        STG1(0, 0);
        __syncthreads();
        for (int k0 = 0; k0 < kl; k0 += 32) {
            if (k0 + 32 < kl) STG1(cur ^ 1, k0 + 32);
            const ushort* As = (const ushort*)(SMb + cur*8192);
            const ushort* Bs = (const ushort*)(SMb + 16384 + cur*16384);
            bf16x8 af[4], bfr[4];
#pragma unroll
            for (int i = 0; i < 4; ++i) {
                int ra = (wm << 6) + (i << 4) + l15;
                af[i]  = *(const bf16x8*)(&As[ra*32 + ((l4 ^ ((ra >> 1) & 3)) << 3)]);
                int rb = (wn << 6) + (i << 4) + l15;
                bfr[i] = *(const bf16x8*)(&Bs[rb*32 + ((l4 ^ ((rb >> 1) & 3)) << 3)]);
            }
#pragma unroll
            for (int i = 0; i < 4; ++i)
#pragma unroll
                for (int j = 0; j < 4; ++j)
                    acc[i][j] = __builtin_amdgcn_mfma_f32_16x16x32_bf16(af[i], bfr[j], acc[i][j], 0, 0, 0);
            __syncthreads();
            cur ^= 1;
        }
#undef STG1
    } else {
        int gt = tid & 255;
        int rA = gt >> 2, scA = gt & 3;
        int lc = (scA ^ ((rA >> 1) & 3)) << 3;
        const ushort* Ar0 = A  + (size_t)(row0 + rA)      * Kstride + kb + lc;
        const ushort* Ar1 = A  + (size_t)(row0 + 64 + rA) * Kstride + kb + lc;
        const ushort* Br0 = Bt + (size_t)(col0 + rA)      * Kstride + kb + lc;
        const ushort* Br1 = Bt + (size_t)(col0 + 64 + rA) * Kstride + kb + lc;
#define STG2(buf, k0rel)                                                        \
        do { int rbase = (g*2 + (buf)) * 8192;                                  \
            gl_lds16(Ar0 + (k0rel), SMb + rbase + (gt << 4));                   \
            gl_lds16(Ar1 + (k0rel), SMb + rbase + 4096 + (gt << 4));            \
            gl_lds16(Br0 + (k0rel), SMb + 32768 + rbase + (gt << 4));           \
            gl_lds16(Br1 + (k0rel), SMb + 32768 + rbase + 4096 + (gt << 4));    \
        } while (0)
        STG2(0, 0);
        __syncthreads();
        for (int k0 = 0; k0 < kl; k0 += 32) {
            if (k0 + 32 < kl) STG2(cur ^ 1, k0 + 32);
            const ushort* As = (const ushort*)(SMb + (g*2 + cur)*8192);
            const ushort* Bs = (const ushort*)(SMb + 32768 + (g*2 + cur)*8192);
            bf16x8 af[4], bfr[4];
#pragma unroll
            for (int i = 0; i < 4; ++i) {
                int ra = (wm << 6) + (i << 4) + l15;
                af[i]  = *(const bf16x8*)(&As[ra*32 + ((l4 ^ ((ra >> 1) & 3)) << 3)]);
                int rb = (wn << 6) + (i << 4) + l15;
                bfr[i] = *(const bf16x8*)(&Bs[rb*32 + ((l4 ^ ((rb >> 1) & 3)) << 3)]);
            }
#pragma unroll
            for (int i = 0; i < 4; ++i)
#pragma unroll
                for (int j = 0; j < 4; ++j)
                    acc[i][j] = __builtin_amdgcn_mfma_f32_16x16x32_bf16(af[i], bfr[j], acc[i][j], 0, 0, 0);
            __syncthreads();
            cur ^= 1;
        }
#undef STG2
    }

    // scratch (per-wave for epilogue; per wave-pair slot for KG=2 reduce)
    float* scr;
    if (KG == 1) scr = (float*)(SMb + 49152) + w * 1088;
    else         scr = (float*)(SMb + 65536) + (w & 3) * (64 * 68);

    if (KG == 2) {
        // group 1 hands accumulators to group 0 through LDS
        if (g == 1) {
#pragma unroll
            for (int i = 0; i < 4; ++i)
#pragma unroll
                for (int j = 0; j < 4; ++j)
#pragma unroll
                    for (int r = 0; r < 4; ++r)
                        scr[((i << 4) + (l4 << 2) + r)*68 + (j << 4) + l15] = acc[i][j][r];
        }
        __syncthreads();
        if (g == 1) return;
#pragma unroll
        for (int i = 0; i < 4; ++i)
#pragma unroll
            for (int j = 0; j < 4; ++j)
#pragma unroll
                for (int r = 0; r < 4; ++r)
                    acc[i][j][r] += scr[((i << 4) + (l4 << 2) + r)*68 + (j << 4) + l15];
    }

    float bcol[4];
#pragma unroll
    for (int j = 0; j < 4; ++j) bcol[j] = bias[col0 + (wn << 6) + (j << 4) + l15];
    int rr = lane >> 2, cseg = lane & 3;
    int colbase = col0 + (wn << 6);

#pragma unroll
    for (int i = 0; i < 4; ++i) {
        LGKM0;
#pragma unroll
        for (int j = 0; j < 4; ++j)
#pragma unroll
            for (int r = 0; r < 4; ++r) {
                float v = acc[i][j][r] + bcol[j];
                if (mode == 3) { v = fmaxf(v, 0.f); v *= v; }
                scr[((l4 << 2) + r)*68 + (j << 4) + l15] = v;
            }
        LGKM0;
        int grow = row0 + (wm << 6) + (i << 4) + rr;
        float4 q0 = *(float4*)&scr[rr*68 + (cseg << 4) + 0];
        float4 q1 = *(float4*)&scr[rr*68 + (cseg << 4) + 4];
        float4 q2 = *(float4*)&scr[rr*68 + (cseg << 4) + 8];
        float4 q3 = *(float4*)&scr[rr*68 + (cseg << 4) + 12];
        int gcol = colbase + (cseg << 4);
        if (mode == 3) {
            ushort* O = (ushort*)Cout;
            *(u16x8*)(O + (size_t)grow*Nc + gcol)     = pack8(q0, q1);
            *(u16x8*)(O + (size_t)grow*Nc + gcol + 8) = pack8(q2, q3);
        } else {
            size_t roff;
            if (mode == 2) {
                int rs = (grow >> 10)*L_ + PREF + (grow & (T_-1));
                roff = (size_t)rs*D_ + gcol;
            } else {
                roff = (size_t)grow*Nc + gcol;
            }
            float4 r0 = *(const float4*)(res + roff);
            float4 r1 = *(const float4*)(res + roff + 4);
            float4 r2 = *(const float4*)(res + roff + 8);
            float4 r3 = *(const float4*)(res + roff + 12);
            q0.x += r0.x; q0.y += r0.y; q0.z += r0.z; q0.w += r0.w;
            q1.x += r1.x; q1.y += r1.y; q1.z += r1.z; q1.w += r1.w;
            q2.x += r2.x; q2.y += r2.y; q2.z += r2.z; q2.w += r2.w;
            q3.x += r3.x; q3.y += r3.y; q3.z += r3.z; q3.w += r3.w;
            float* O = (float*)Cout;
            size_t o = (size_t)grow*Nc + gcol;
            *(float4*)(O + o)      = q0;
            *(float4*)(O + o + 4)  = q1;
            *(float4*)(O + o + 8)  = q2;
            *(float4*)(O + o + 12) = q3;
        }
    }
}

// ---------------- MFMA flash attention, swapped-operand softmax ----------
__global__ __launch_bounds__(256) void attn_mfma_kernel(
    const ushort* __restrict__ qhd, const ushort* __restrict__ khd,
    const ushort* __restrict__ vt, ushort* __restrict__ attn_bf)
{
    __shared__ ushort Ks[2][64*64];
    __shared__ ushort Vs[2][64*64];
    __shared__ ushort Ps[4*16*64];

    // XCD swizzle: consecutive (b,h) stay on one XCD for KV L2 reuse
    int bid0 = blockIdx.x;
    int bid = (bid0 & 7) * (gridDim.x >> 3) + (bid0 >> 3);
    int qb = 15 - (bid & 15);
    int h  = (bid >> 4) & (H_ - 1);
    int b  = bid >> 8;
    int tid = threadIdx.x, lane = tid & 63, w = tid >> 6;
    int l15 = lane & 15, lg = lane >> 4;
    int i0 = PREF + (qb << 6);
    int wq0 = w << 4;
    size_t bh = (size_t)(b * H_ + h);

    const ushort* qrow = qhd + (bh * L_ + i0 + wq0 + l15) * 64;
    bf16x8 bq0 = *(const bf16x8*)(qrow + (lg << 3));
    bf16x8 bq1 = *(const bf16x8*)(qrow + 32 + (lg << 3));

    f32x4 acc[4] = {};
    float mrun = -INFINITY;
    float lsum = 0.f;

    int srow = tid >> 3;
    int sslot = tid & 7;
    ushort* Ps_w = Ps + (w << 10);
    const float SC = 0.125f * 1.4426950408889634f;
    int qcap = i0 + wq0 + l15;

#define STAGE_T(buf, t)                                                     \
    do { int j0s = (t) << 6;                                                \
        gl_lds16(khd + (bh * L_ + j0s + srow) * 64 + ((sslot ^ (srow & 7)) << 3),      \
                 (char*)Ks[buf] + (tid << 4));                              \
        gl_lds16(khd + (bh * L_ + j0s + 32 + srow) * 64 + ((sslot ^ ((32+srow) & 7)) << 3), \
                 (char*)Ks[buf] + ((256 + tid) << 4));                      \
        gl_lds16(vt + (bh * 64 + srow) * L_ + j0s + ((sslot ^ (srow & 7)) << 3),       \
                 (char*)Vs[buf] + (tid << 4));                              \
        gl_lds16(vt + (bh * 64 + 32 + srow) * L_ + j0s + ((sslot ^ ((32+srow) & 7)) << 3), \
                 (char*)Vs[buf] + ((256 + tid) << 4));                      \
    } while (0)

    int ntile = 4 + qb;
    STAGE_T(0, 0);
    __syncthreads();
    int cur = 0;
    for (int t = 0; t < ntile; ++t) {
        if (t + 1 < ntile) STAGE_T(cur ^ 1, t + 1);
        const ushort* Kc = Ks[cur];
        const ushort* Vc = Vs[cur];

        f32x4 s4[4];
        __builtin_amdgcn_s_setprio(1);
#pragma unroll
        for (int st = 0; st < 4; ++st) {
            int rk = (st << 4) + l15;
            bf16x8 ak0 = *(const bf16x8*)(Kc + (rk << 6) + ((lg       ^ (rk & 7)) << 3));
            bf16x8 ak1 = *(const bf16x8*)(Kc + (rk << 6) + (((4 + lg) ^ (rk & 7)) << 3));
            f32x4 z = {};
            z = __builtin_amdgcn_mfma_f32_16x16x32_bf16(ak0, bq0, z, 0, 0, 0);
            z = __builtin_amdgcn_mfma_f32_16x16x32_bf16(ak1, bq1, z, 0, 0, 0);
            s4[st] = z;
        }
        __builtin_amdgcn_s_setprio(0);

        int j0 = t << 6;
        float sv[4][4];
        bool diag = (t == ntile - 1);
        int kbq = j0 + (lg << 2);
#pragma unroll
        for (int st = 0; st < 4; ++st)
#pragma unroll
            for (int r = 0; r < 4; ++r) {
                float s = s4[st][r] * SC;
                if (diag && (kbq + (st << 4) + r > qcap)) s = -INFINITY;
                sv[st][r] = s;
            }
        float bm;
        {
            float t0 = fmaxf(fmaxf(sv[0][0], sv[0][1]), fmaxf(sv[0][2], sv[0][3]));
            float t1 = fmaxf(fmaxf(sv[1][0], sv[1][1]), fmaxf(sv[1][2], sv[1][3]));
            float t2 = fmaxf(fmaxf(sv[2][0], sv[2][1]), fmaxf(sv[2][2], sv[2][3]));
            float t3 = fmaxf(fmaxf(sv[3][0], sv[3][1]), fmaxf(sv[3][2], sv[3][3]));
            bm = fmaxf(fmaxf(t0, t1), fmaxf(t2, t3));
        }
        bm = fmaxf(bm, __shfl_xor(bm, 16, 64));
        bm = fmaxf(bm, __shfl_xor(bm, 32, 64));

        float mn = fmaxf(mrun, bm);
        float cr = exp2f(mrun - mn);
        mrun = mn;
        float pe[4][4];
        float ps = 0.f;
#pragma unroll
        for (int st = 0; st < 4; ++st)
#pragma unroll
            for (int r = 0; r < 4; ++r) {
                float e = exp2f(sv[st][r] - mn);
                pe[st][r] = e; ps += e;
            }
        ps += __shfl_xor(ps, 16, 64);
        ps += __shfl_xor(ps, 32, 64);
        lsum = lsum * cr + ps;
#pragma unroll
        for (int su = 0; su < 4; ++su) acc[su] *= cr;

#pragma unroll
        for (int st = 0; st < 4; ++st) {
            int slot = (st << 1) + (lg >> 1);
            int sb = ((lg & 1) << 3);
#pragma unroll
            for (int rp = 0; rp < 2; ++rp) {
                uint u = (uint)f2bf(pe[st][2*rp]) | ((uint)f2bf(pe[st][2*rp+1]) << 16);
                *(uint*)((char*)Ps_w + l15*128 + ((slot ^ (l15 & 7)) << 4) + sb + (rp << 2)) = u;
            }
        }
        {
            bf16x8 bp0 = *(const bf16x8*)((char*)Ps_w + l15*128 + ((lg       ^ (l15 & 7)) << 4));
            bf16x8 bp1 = *(const bf16x8*)((char*)Ps_w + l15*128 + (((4 + lg) ^ (l15 & 7)) << 4));
            __builtin_amdgcn_s_setprio(1);
#pragma unroll
            for (int su = 0; su < 4; ++su) {
                int rd = (su << 4) + l15;
                bf16x8 av0 = *(const bf16x8*)(Vc + (rd << 6) + ((lg       ^ (rd & 7)) << 3));
                bf16x8 av1 = *(const bf16x8*)(Vc + (rd << 6) + (((4 + lg) ^ (rd & 7)) << 3));
                acc[su] = __builtin_amdgcn_mfma_f32_16x16x32_bf16(av0, bp0, acc[su], 0, 0, 0);
                acc[su] = __builtin_amdgcn_mfma_f32_16x16x32_bf16(av1, bp1, acc[su], 0, 0, 0);
            }
            __builtin_amdgcn_s_setprio(0);
        }
        __syncthreads();
        cur ^= 1;
    }
#undef STAGE_T

    float rl = 1.0f / lsum;
    size_t orow = (size_t)b * T_ + (i0 - PREF) + wq0 + l15;
#pragma unroll
    for (int su = 0; su < 4; ++su) {
        ushort4 o4;
        o4.x = f2bf(acc[su][0] * rl);
        o4.y = f2bf(acc[su][1] * rl);
        o4.z = f2bf(acc[su][2] * rl);
        o4.w = f2bf(acc[su][3] * rl);
        *(ushort4*)(attn_bf + orow * D_ + (h << 6) + (su << 4) + (lg << 2)) = o4;
    }
}

// ---------------- launch ----------------
extern "C" void kernel_launch(void* const* d_in, const int* in_sizes, int n_in,
                              void* d_out, int out_size, void* d_ws, size_t ws_size,
                              hipStream_t stream) {
    const float* x   = (const float*)d_in[0];
    const float* mem = (const float*)d_in[1];
    const float* nmr = (const float*)d_in[2];
    const float* Wq  = (const float*)d_in[3];
    const float* bq  = (const float*)d_in[4];
    const float* Wk  = (const float*)d_in[5];
    const float* bk  = (const float*)d_in[6];
    const float* Wv  = (const float*)d_in[7];
    const float* bv  = (const float*)d_in[8];
    const float* Wo  = (const float*)d_in[9];
    const float* bo  = (const float*)d_in[10];
    const float* W1  = (const float*)d_in[11];
    const float* b1  = (const float*)d_in[12];
    const float* W2  = (const float*)d_in[13];
    const float* b2  = (const float*)d_in[14];
    const float* g1  = (const float*)d_in[15];
    const float* be1 = (const float*)d_in[16];
    const float* g2  = (const float*)d_in[17];
    const float* be2 = (const float*)d_in[18];
    float* out = (float*)d_out;

    const size_t BLD = (size_t)BL_ * D_;
    const size_t BTD = (size_t)BT_ * D_;

    float* f = (float*)d_ws;
    float* x_full = f;                         // BLD f32
    float* x2     = f + BLD;                   // BTD f32
    float* bqkv   = x2 + BTD;                  // 4096 f32 (3072 used)
    float* rtab   = bqkv + 4096;               // L_*32 f32
    ushort* bfb   = (ushort*)(rtab + (size_t)L_*32);
    ushort* xa_bf   = bfb;                     // BLD  (reused as attn_bf)
    ushort* qhd     = bfb + BLD;               // BLD  (reused as ln2_bf)
    ushort* khd     = bfb + 2*BLD;             // BLD
    ushort* vt      = bfb + 3*BLD;             // BLD
    ushort* h1_bf   = bfb + 4*BLD;             // BT_*FFN_
    ushort* wq_bf = h1_bf + (size_t)BT_*FFN_;  // Q|K|V|Wo|W1|W2 contiguous
    ushort* wk_bf = wq_bf + (size_t)D_*D_;
    ushort* wv_bf = wk_bf + (size_t)D_*D_;
    ushort* wo_bf = wv_bf + (size_t)D_*D_;
    ushort* w1_bf = wo_bf + (size_t)D_*D_;
    ushort* w2_bf = w1_bf + (size_t)D_*FFN_;
    ushort* attn_bf = xa_bf;
    ushort* ln2_bf  = qhd;

    // weight prep + tables
    wtr4_kernel<<<dim3(16, 16, 4), 256, 0, stream>>>(Wq, Wk, Wv, Wo,
                                                     wq_bf, wk_bf, wv_bf, wo_bf);
    wtr_kernel<<<dim3(FFN_/64, D_/64),   256, 0, stream>>>(W1, w1_bf, D_,   FFN_);
    wtr_kernel<<<dim3(D_/64,   FFN_/64), 256, 0, stream>>>(W2, w2_bf, FFN_, D_);
    ropetab_kernel<<<(L_*32 + 255)/256, 256, 0, stream>>>(rtab);
    bias_cat_kernel<<<12, 256, 0, stream>>>(bq, bk, bv, bqkv);

    ln1_concat_kernel<<<BL_, 256, 0, stream>>>(x, mem, nmr, g1, be1, x_full, xa_bf);

    // fused QKV projection (N=3072) with table-RoPE / layout epilogues
    gemm_bf16_kernel<<<dim3(3072/128, BL_/128), 256, 0, stream>>>(
        xa_bf, wq_bf, bqkv, rtab, qhd, D_, D_, D_, 7);

    attn_mfma_kernel<<<B_*H_*(T_/64), 256, 0, stream>>>(qhd, khd, vt, attn_bf);

    // x2 = attn @ Wo + bo + x_full[strided]   (in-block split-K=2)
    gemm512_kernel<2><<<dim3(D_/128, BT_/128), 512, 0, stream>>>(
        attn_bf, wo_bf, bo, x_full, x2, D_, D_, D_, 2);

    ln2_kernel<<<BT_, 256, 0, stream>>>(x2, g2, be2, ln2_bf);

    // h1 = relu(xf @ W1 + b1)^2   (128x256 tile)
    gemm512_kernel<1><<<dim3(FFN_/256, BT_/128), 512, 0, stream>>>(
        ln2_bf, w1_bf, b1, nullptr, h1_bf, FFN_, D_, D_, 3);

    // out = h1 @ W2 + b2 + x2   (in-block split-K=2)
    gemm512_kernel<2><<<dim3(D_/128, BT_/128), 512, 0, stream>>>(
        h1_bf, w2_bf, b2, x2, out, D_, FFN_, FFN_, 1);
}

// Round 8
// 254.223 us; speedup vs baseline: 10.1206x; 1.0707x over previous
//
#include <hip/hip_runtime.h>
#include <hip/hip_bf16.h>
#include <math.h>

#define D_   1024
#define H_   16
#define DH_  64
#define FFN_ 4096
#define B_   4
#define T_   1024
#define M_   128
#define N_   64
#define PREF 192
#define L_   1216
#define BL_  (B_*L_)   // 4864
#define BT_  (B_*T_)   // 4096

typedef __attribute__((ext_vector_type(4))) float f32x4;
typedef __attribute__((ext_vector_type(8))) short bf16x8;
typedef __attribute__((ext_vector_type(8))) unsigned short u16x8;
typedef const __attribute__((address_space(1))) void gvoid_t;
typedef __attribute__((address_space(3))) void lvoid_t;

#define LGKM0 asm volatile("s_waitcnt lgkmcnt(0)" ::: "memory")

__device__ __forceinline__ void gl_lds16(const void* g, void* l) {
    __builtin_amdgcn_global_load_lds((gvoid_t*)g, (lvoid_t*)l, 16, 0, 0);
}

__device__ __forceinline__ ushort f2bf(float x) {
    union { __hip_bfloat16 h; ushort u; } cv;
    cv.h = __float2bfloat16(x);
    return cv.u;
}

__device__ __forceinline__ u16x8 pack8(float4 a, float4 b) {
    u16x8 r;
    r[0]=f2bf(a.x); r[1]=f2bf(a.y); r[2]=f2bf(a.z); r[3]=f2bf(a.w);
    r[4]=f2bf(b.x); r[5]=f2bf(b.y); r[6]=f2bf(b.z); r[7]=f2bf(b.w);
    return r;
}

// ---------------- block reduce helper ----------------
__device__ __forceinline__ float block_reduce_sum256(float v, float* sbuf) {
#pragma unroll
    for (int o = 32; o > 0; o >>= 1) v += __shfl_xor(v, o, 64);
    int w = threadIdx.x >> 6;
    if ((threadIdx.x & 63) == 0) sbuf[w] = v;
    __syncthreads();
    float r = sbuf[0] + sbuf[1] + sbuf[2] + sbuf[3];
    __syncthreads();
    return r;
}

// ---------------- weight fp32 [K][Nc] -> bf16 W^T [Nc][K] ----------------
__device__ __forceinline__ void wtr_body(const float* __restrict__ W,
                                         ushort* __restrict__ Wt, int K, int Nc)
{
    __shared__ float tl[64][65];
    int c0 = blockIdx.x << 6, k0 = blockIdx.y << 6;
    int tid = threadIdx.x;
    int rr = tid >> 4, c4 = (tid & 15) << 2;
#pragma unroll
    for (int p = 0; p < 4; ++p) {
        int r = (p << 4) + rr;
        float4 v = *(const float4*)(W + (size_t)(k0 + r) * Nc + c0 + c4);
        tl[r][c4+0] = v.x; tl[r][c4+1] = v.y; tl[r][c4+2] = v.z; tl[r][c4+3] = v.w;
    }
    __syncthreads();
#pragma unroll
    for (int p = 0; p < 4; ++p) {
        int rT = (p << 4) + rr;
        ushort4 uv;
        uv.x = f2bf(tl[c4+0][rT]);
        uv.y = f2bf(tl[c4+1][rT]);
        uv.z = f2bf(tl[c4+2][rT]);
        uv.w = f2bf(tl[c4+3][rT]);
        *(ushort4*)(Wt + (size_t)(c0 + rT) * K + k0 + c4) = uv;
    }
}

__global__ __launch_bounds__(256) void wtr_kernel(
    const float* __restrict__ W, ushort* __restrict__ Wt, int K, int Nc)
{ wtr_body(W, Wt, K, Nc); }

__global__ __launch_bounds__(256) void wtr4_kernel(
    const float* __restrict__ W0, const float* __restrict__ W1,
    const float* __restrict__ W2, const float* __restrict__ W3,
    ushort* __restrict__ T0, ushort* __restrict__ T1,
    ushort* __restrict__ T2, ushort* __restrict__ T3)
{
    const float* W; ushort* T;
    switch (blockIdx.z) {
        case 0: W = W0; T = T0; break;
        case 1: W = W1; T = T1; break;
        case 2: W = W2; T = T2; break;
        default: W = W3; T = T3; break;
    }
    wtr_body(W, T, D_, D_);
}

// ---------------- RoPE table + bias concat (merged prep) ------------------
__global__ __launch_bounds__(256) void prep_kernel(
    float* __restrict__ tab, const float* __restrict__ bq,
    const float* __restrict__ bk, const float* __restrict__ bv,
    float* __restrict__ ob)
{
    int i = blockIdx.x * 256 + threadIdx.x;
    if (i < L_ * 32) {
        int pos = i >> 5, idx = i & 31;
        int fi = idx & 15;
        float invf = exp2f(-(float)fi * 0.83048202372f);   // 10000^(-fi/16)
        float th = (float)pos * invf;
        tab[i] = (idx < 16) ? cosf(th) : sinf(th);
    } else {
        int j = i - L_ * 32;
        if (j < 3072) {
            float v = (j < 1024) ? bq[j] : (j < 2048 ? bk[j - 1024] : bv[j - 2048]);
            ob[j] = v;
        }
    }
}

// ---------------- concat + LayerNorm1: x_full f32, xa bf16 ----------------
__global__ __launch_bounds__(256) void ln1_concat_kernel(
    const float* __restrict__ x, const float* __restrict__ mem,
    const float* __restrict__ nmr, const float* __restrict__ g,
    const float* __restrict__ be, float* __restrict__ x_full,
    ushort* __restrict__ xa_bf)
{
    __shared__ float sbuf[4];
    int row = blockIdx.x;
    int b = row / L_, pos = row % L_;
    const float* src;
    if (pos < M_)          src = mem + ((size_t)b*M_ + pos)      * D_;
    else if (pos < M_+N_)  src = nmr + ((size_t)b*N_ + (pos-M_)) * D_;
    else                   src = x   + ((size_t)b*T_ + (pos-PREF))*D_;

    int c = threadIdx.x << 2;
    float4 v = *(const float4*)(src + c);
    float s = v.x + v.y + v.z + v.w;
    s = block_reduce_sum256(s, sbuf);
    float mu = s * (1.0f / D_);
    float dx = v.x - mu, dy = v.y - mu, dz = v.z - mu, dw = v.w - mu;
    float q = dx*dx + dy*dy + dz*dz + dw*dw;
    q = block_reduce_sum256(q, sbuf);
    float inv = rsqrtf(q * (1.0f / D_) + 1e-5f);
    float4 gv = *(const float4*)(g + c);
    float4 bv = *(const float4*)(be + c);
    ushort4 o;
    o.x = f2bf(dx*inv*gv.x + bv.x);
    o.y = f2bf(dy*inv*gv.y + bv.y);
    o.z = f2bf(dz*inv*gv.z + bv.z);
    o.w = f2bf(dw*inv*gv.w + bv.w);
    *(float4*)(x_full + (size_t)row*D_ + c) = v;
    *(ushort4*)(xa_bf + (size_t)row*D_ + c) = o;
}

// ---------------- LayerNorm2: f32 in, bf16 out ----------------------------
__global__ __launch_bounds__(256) void ln2_kernel(
    const float* __restrict__ src, const float* __restrict__ g,
    const float* __restrict__ be, ushort* __restrict__ dst)
{
    __shared__ float sbuf[4];
    int row = blockIdx.x;
    int c = threadIdx.x << 2;
    float4 v = *(const float4*)(src + (size_t)row*D_ + c);
    float s = v.x + v.y + v.z + v.w;
    s = block_reduce_sum256(s, sbuf);
    float mu = s * (1.0f / D_);
    float dx = v.x - mu, dy = v.y - mu, dz = v.z - mu, dw = v.w - mu;
    float q = dx*dx + dy*dy + dz*dz + dw*dw;
    q = block_reduce_sum256(q, sbuf);
    float inv = rsqrtf(q * (1.0f / D_) + 1e-5f);
    float4 gv = *(const float4*)(g + c);
    float4 bv = *(const float4*)(be + c);
    ushort4 o;
    o.x = f2bf(dx*inv*gv.x + bv.x);
    o.y = f2bf(dy*inv*gv.y + bv.y);
    o.z = f2bf(dz*inv*gv.z + bv.z);
    o.w = f2bf(dw*inv*gv.w + bv.w);
    *(ushort4*)(dst + (size_t)row*D_ + c) = o;
}

// ---------------- 256-thr bf16 MFMA GEMM (QKV path, mode 7) ---------------
__global__ __launch_bounds__(256) void gemm_bf16_kernel(
    const ushort* __restrict__ A, const ushort* __restrict__ Bt,
    const float* __restrict__ bias, const float* __restrict__ rtab,
    void* __restrict__ Cout, int Nc, int Kstride, int Klen, int mode)
{
    __shared__ ushort SM[16384];    // A dbuf 16K | B dbuf 16K (bytes: 32K)
    int tid = threadIdx.x;
    int lane = tid & 63, w = tid >> 6;
    int wm = w >> 1, wn = w & 1;
    // XCD-aware bijective swizzle (grids are %8==0)
    int nx = gridDim.x;
    int flat = blockIdx.y * nx + blockIdx.x;
    int cpx = (nx * gridDim.y) >> 3;
    int sz = (flat & 7) * cpx + (flat >> 3);
    int row0 = (sz / nx) << 7, col0 = (sz % nx) << 7;
    int l15 = lane & 15, l4 = lane >> 4;

    f32x4 acc[4][4] = {};

    int r_a = tid >> 2;
    int sc  = tid & 3;
    int lcOff = (sc ^ ((r_a >> 1) & 3)) << 3;
    const ushort* Arow  = A  + (size_t)(row0 + r_a)      * Kstride;
    const ushort* Arow2 = A  + (size_t)(row0 + 64 + r_a) * Kstride;
    const ushort* Brow  = Bt + (size_t)(col0 + r_a)      * Kstride;
    const ushort* Brow2 = Bt + (size_t)(col0 + 64 + r_a) * Kstride;

#define STAGE(buf, k0rel)                                                          \
    do {                                                                           \
        gl_lds16(Arow  + (k0rel) + lcOff, (char*)(SM + (buf)*4096) + (tid << 4));  \
        gl_lds16(Arow2 + (k0rel) + lcOff, (char*)(SM + (buf)*4096) + ((256+tid) << 4)); \
        gl_lds16(Brow  + (k0rel) + lcOff, (char*)(SM + 8192 + (buf)*4096) + (tid << 4)); \
        gl_lds16(Brow2 + (k0rel) + lcOff, (char*)(SM + 8192 + (buf)*4096) + ((256+tid) << 4)); \
    } while (0)

    STAGE(0, 0);
    __syncthreads();
    int cur = 0;
    for (int k0 = 0; k0 < Klen; k0 += 32) {
        if (k0 + 32 < Klen) STAGE(cur ^ 1, k0 + 32);
        const ushort* As = SM + cur*4096;
        const ushort* Bs = SM + 8192 + cur*4096;
        bf16x8 af[4], bfr[4];
#pragma unroll
        for (int i = 0; i < 4; ++i) {
            int ra = (wm << 6) + (i << 4) + l15;
            af[i]  = *(const bf16x8*)(&As[ra*32 + ((l4 ^ ((ra >> 1) & 3)) << 3)]);
            int rb = (wn << 6) + (i << 4) + l15;
            bfr[i] = *(const bf16x8*)(&Bs[rb*32 + ((l4 ^ ((rb >> 1) & 3)) << 3)]);
        }
#pragma unroll
        for (int i = 0; i < 4; ++i)
#pragma unroll
            for (int j = 0; j < 4; ++j)
                acc[i][j] = __builtin_amdgcn_mfma_f32_16x16x32_bf16(af[i], bfr[j], acc[i][j], 0, 0, 0);
        __syncthreads();
        cur ^= 1;
    }
#undef STAGE

    float bcol[4];
#pragma unroll
    for (int j = 0; j < 4; ++j) bcol[j] = bias[col0 + (wn << 6) + (j << 4) + l15];

    // epilogue: per-wave 16x68 f32 LDS transpose -> wide stores
    float* scr = (float*)SM + w * 1088;
    int rr = lane >> 2, cseg = lane & 3;
    int hh = ((col0 & 1023) + (wn << 6)) >> 6;
    int which = col0 >> 10;                         // 0 Q, 1 K, 2 V

#pragma unroll
    for (int i = 0; i < 4; ++i) {
        LGKM0;
#pragma unroll
        for (int j = 0; j < 4; ++j)
#pragma unroll
            for (int r = 0; r < 4; ++r)
                scr[((l4 << 2) + r)*68 + (j << 4) + l15] = acc[i][j][r] + bcol[j];
        LGKM0;
        int grow = row0 + (wm << 6) + (i << 4) + rr;

        if (which == 2) {
            // V^T: lane owns d = lane; 16 contiguous pos per chunk
            int r0g = row0 + (wm << 6) + (i << 4);
            int bb = r0g / L_;
            int posb = r0g - bb * L_;
            float4 v0, v1, v2, v3;
            v0.x = scr[ 0*68 + lane]; v0.y = scr[ 1*68 + lane];
            v0.z = scr[ 2*68 + lane]; v0.w = scr[ 3*68 + lane];
            v1.x = scr[ 4*68 + lane]; v1.y = scr[ 5*68 + lane];
            v1.z = scr[ 6*68 + lane]; v1.w = scr[ 7*68 + lane];
            v2.x = scr[ 8*68 + lane]; v2.y = scr[ 9*68 + lane];
            v2.z = scr[10*68 + lane]; v2.w = scr[11*68 + lane];
            v3.x = scr[12*68 + lane]; v3.y = scr[13*68 + lane];
            v3.z = scr[14*68 + lane]; v3.w = scr[15*68 + lane];
            ushort* O = (ushort*)Cout + 2*(size_t)BL_*D_;
            size_t base = ((size_t)(bb*H_ + hh)*64 + lane)*L_ + posb;
            *(u16x8*)(O + base)     = pack8(v0, v1);
            *(u16x8*)(O + base + 8) = pack8(v2, v3);
        } else {
            int bb = grow / L_;
            int pos = grow - bb * L_;
            float4 a0 = *(float4*)&scr[rr*68 + (cseg << 4) + 0];
            float4 a1 = *(float4*)&scr[rr*68 + (cseg << 4) + 4];
            float4 a2 = *(float4*)&scr[rr*68 + (cseg << 4) + 8];
            float4 a3 = *(float4*)&scr[rr*68 + (cseg << 4) + 12];
            if (cseg < 2) {
                int oseg = cseg ^ 1;
                float4 p0 = *(float4*)&scr[rr*68 + (oseg << 4) + 0];
                float4 p1 = *(float4*)&scr[rr*68 + (oseg << 4) + 4];
                float4 p2 = *(float4*)&scr[rr*68 + (oseg << 4) + 8];
                float4 p3 = *(float4*)&scr[rr*68 + (oseg << 4) + 12];
                const float* tb = rtab + pos*32;
                float4 c0 = *(const float4*)(tb + 0),  c1 = *(const float4*)(tb + 4);
                float4 c2 = *(const float4*)(tb + 8),  c3 = *(const float4*)(tb + 12);
                float4 s0 = *(const float4*)(tb + 16), s1 = *(const float4*)(tb + 20);
                float4 s2 = *(const float4*)(tb + 24), s3 = *(const float4*)(tb + 28);
                float sg = (cseg == 0) ? -1.f : 1.f;
                a0.x = a0.x*c0.x + sg*p0.x*s0.x; a0.y = a0.y*c0.y + sg*p0.y*s0.y;
                a0.z = a0.z*c0.z + sg*p0.z*s0.z; a0.w = a0.w*c0.w + sg*p0.w*s0.w;
                a1.x = a1.x*c1.x + sg*p1.x*s1.x; a1.y = a1.y*c1.y + sg*p1.y*s1.y;
                a1.z = a1.z*c1.z + sg*p1.z*s1.z; a1.w = a1.w*c1.w + sg*p1.w*s1.w;
                a2.x = a2.x*c2.x + sg*p2.x*s2.x; a2.y = a2.y*c2.y + sg*p2.y*s2.y;
                a2.z = a2.z*c2.z + sg*p2.z*s2.z; a2.w = a2.w*c2.w + sg*p2.w*s2.w;
                a3.x = a3.x*c3.x + sg*p3.x*s3.x; a3.y = a3.y*c3.y + sg*p3.y*s3.y;
                a3.z = a3.z*c3.z + sg*p3.z*s3.z; a3.w = a3.w*c3.w + sg*p3.w*s3.w;
            }
            ushort* O = (ushort*)Cout + (size_t)which * ((size_t)BL_*D_);
            size_t base = (((size_t)(bb*H_ + hh)*L_ + pos) << 6) + (cseg << 4);
            *(u16x8*)(O + base)     = pack8(a0, a1);
            *(u16x8*)(O + base + 8) = pack8(a2, a3);
        }
    }
}

// ---------------- 512-thr GEMM: KG=1 -> 128x256 tile (FFN1);  -------------
// KG=2 -> 128x128 tile, in-block split-K (Wo / FFN2), no global partials.
// Epilogue/handoff scratch ALIASES the staging LDS (dead after the K-loop's
// final barrier) -> KG=2: 68 KB (2 blocks/CU), KG=1: 48 KB.
// modes: 1 f32 +bias +res(row-major) | 2 f32 +bias +res(strided x_full) |
//        3 bf16 relu(+bias)^2
template<int KG>
__global__ __launch_bounds__(512) void gemm512_kernel(
    const ushort* __restrict__ A, const ushort* __restrict__ Bt,
    const float* __restrict__ bias, const float* __restrict__ res,
    void* __restrict__ Cout, int Nc, int Kstride, int Klen, int mode)
{
    constexpr int TN  = (KG == 1) ? 256 : 128;
    constexpr int SMU = (KG == 1) ? 24576 : 34816;   // ushorts (48 KB / 68 KB)
    __shared__ ushort SM[SMU];
    char* SMb = (char*)SM;

    int tid = threadIdx.x;
    int lane = tid & 63, w = tid >> 6;
    int l15 = lane & 15, l4 = lane >> 4;

    // XCD-aware bijective swizzle (grids are %8==0)
    int nx = gridDim.x;
    int flat = blockIdx.y * nx + blockIdx.x;
    int cpx = (nx * gridDim.y) >> 3;
    int sz = (flat & 7) * cpx + (flat >> 3);
    int row0 = (sz / nx) << 7, col0 = (sz % nx) * TN;

    int wm, wn, g;
    if (KG == 1) { g = 0; wm = w >> 2; wn = w & 3; }
    else         { g = w >> 2; wm = (w >> 1) & 1; wn = w & 1; }

    f32x4 acc[4][4] = {};
    const int kl = (KG == 2) ? (Klen >> 1) : Klen;
    const int kb = (KG == 2) ? g * kl : 0;

    int cur = 0;
    if (KG == 1) {
        int rA = tid >> 2, scA = tid & 3;
        int lcA = (scA ^ ((rA >> 1) & 3)) << 3;
        const ushort* Ar = A + (size_t)(row0 + rA) * Kstride + lcA;
        int lcB1 = (scA ^ (((128 + rA) >> 1) & 3)) << 3;
        const ushort* Br0 = Bt + (size_t)(col0 + rA)       * Kstride + lcA;
        const ushort* Br1 = Bt + (size_t)(col0 + 128 + rA) * Kstride + lcB1;
#define STG1(buf, k0rel)                                                        \
        do {                                                                    \
            gl_lds16(Ar  + (k0rel), SMb + (buf)*8192 + (tid << 4));             \
            gl_lds16(Br0 + (k0rel), SMb + 16384 + (buf)*16384 + (tid << 4));    \
            gl_lds16(Br1 + (k0rel), SMb + 16384 + (buf)*16384 + 8192 + (tid << 4)); \
        } while (0)
        STG1(0, 0);
        __syncthreads();
        for (int k0 = 0; k0 < kl; k0 += 32) {
            if (k0 + 32 < kl) STG1(cur ^ 1, k0 + 32);
            const ushort* As = (const ushort*)(SMb + cur*8192);
            const ushort* Bs = (const ushort*)(SMb + 16384 + cur*16384);
            bf16x8 af[4], bfr[4];
#pragma unroll
            for (int i = 0; i < 4; ++i) {
                int ra = (wm << 6) + (i << 4) + l15;
                af[i]  = *(const bf16x8*)(&As[ra*32 + ((l4 ^ ((ra >> 1) & 3)) << 3)]);
                int rb = (wn << 6) + (i << 4) + l15;
                bfr[i] = *(const bf16x8*)(&Bs[rb*32 + ((l4 ^ ((rb >> 1) & 3)) << 3)]);
            }
#pragma unroll
            for (int i = 0; i < 4; ++i)
#pragma unroll
                for (int j = 0; j < 4; ++j)
                    acc[i][j] = __builtin_amdgcn_mfma_f32_16x16x32_bf16(af[i], bfr[j], acc[i][j], 0, 0, 0);
            __syncthreads();
            cur ^= 1;
        }
#undef STG1
    } else {
        int gt = tid & 255;
        int rA = gt >> 2, scA = gt & 3;
        int lc = (scA ^ ((rA >> 1) & 3)) << 3;
        const ushort* Ar0 = A  + (size_t)(row0 + rA)      * Kstride + kb + lc;
        const ushort* Ar1 = A  + (size_t)(row0 + 64 + rA) * Kstride + kb + lc;
        const ushort* Br0 = Bt + (size_t)(col0 + rA)      * Kstride + kb + lc;
        const ushort* Br1 = Bt + (size_t)(col0 + 64 + rA) * Kstride + kb + lc;
#define STG2(buf, k0rel)                                                        \
        do { int rbase = (g*2 + (buf)) * 8192;                                  \
            gl_lds16(Ar0 + (k0rel), SMb + rbase + (gt << 4));                   \
            gl_lds16(Ar1 + (k0rel), SMb + rbase + 4096 + (gt << 4));            \
            gl_lds16(Br0 + (k0rel), SMb + 32768 + rbase + (gt << 4));           \
            gl_lds16(Br1 + (k0rel), SMb + 32768 + rbase + 4096 + (gt << 4));    \
        } while (0)
        STG2(0, 0);
        __syncthreads();
        for (int k0 = 0; k0 < kl; k0 += 32) {
            if (k0 + 32 < kl) STG2(cur ^ 1, k0 + 32);
            const ushort* As = (const ushort*)(SMb + (g*2 + cur)*8192);
            const ushort* Bs = (const ushort*)(SMb + 32768 + (g*2 + cur)*8192);
            bf16x8 af[4], bfr[4];
#pragma unroll
            for (int i = 0; i < 4; ++i) {
                int ra = (wm << 6) + (i << 4) + l15;
                af[i]  = *(const bf16x8*)(&As[ra*32 + ((l4 ^ ((ra >> 1) & 3)) << 3)]);
                int rb = (wn << 6) + (i << 4) + l15;
                bfr[i] = *(const bf16x8*)(&Bs[rb*32 + ((l4 ^ ((rb >> 1) & 3)) << 3)]);
            }
#pragma unroll
            for (int i = 0; i < 4; ++i)
#pragma unroll
                for (int j = 0; j < 4; ++j)
                    acc[i][j] = __builtin_amdgcn_mfma_f32_16x16x32_bf16(af[i], bfr[j], acc[i][j], 0, 0, 0);
            __syncthreads();
            cur ^= 1;
        }
#undef STG2
    }

    // scratch aliases the staging LDS (dead after final K-loop barrier)
    float* scr;
    if (KG == 1) scr = (float*)SMb + w * 1088;           // 8 x 4352 B = 34816
    else         scr = (float*)SMb + (w & 3) * (64 * 68); // 4 x 17408 B = 69632

    if (KG == 2) {
        // group 1 hands accumulators to group 0 through LDS
        if (g == 1) {
#pragma unroll
            for (int i = 0; i < 4; ++i)
#pragma unroll
                for (int j = 0; j < 4; ++j)
#pragma unroll
                    for (int r = 0; r < 4; ++r)
                        scr[((i << 4) + (l4 << 2) + r)*68 + (j << 4) + l15] = acc[i][j][r];
        }
        __syncthreads();
        if (g == 1) return;
#pragma unroll
        for (int i = 0; i < 4; ++i)
#pragma unroll
            for (int j = 0; j < 4; ++j)
#pragma unroll
                for (int r = 0; r < 4; ++r)
                    acc[i][j][r] += scr[((i << 4) + (l4 << 2) + r)*68 + (j << 4) + l15];
    }

    float bcol[4];
#pragma unroll
    for (int j = 0; j < 4; ++j) bcol[j] = bias[col0 + (wn << 6) + (j << 4) + l15];
    int rr = lane >> 2, cseg = lane & 3;
    int colbase = col0 + (wn << 6);

#pragma unroll
    for (int i = 0; i < 4; ++i) {
        LGKM0;
#pragma unroll
        for (int j = 0; j < 4; ++j)
#pragma unroll
            for (int r = 0; r < 4; ++r) {
                float v = acc[i][j][r] + bcol[j];
                if (mode == 3) { v = fmaxf(v, 0.f); v *= v; }
                scr[((l4 << 2) + r)*68 + (j << 4) + l15] = v;
            }
        LGKM0;
        int grow = row0 + (wm << 6) + (i << 4) + rr;
        float4 q0 = *(float4*)&scr[rr*68 + (cseg << 4) + 0];
        float4 q1 = *(float4*)&scr[rr*68 + (cseg << 4) + 4];
        float4 q2 = *(float4*)&scr[rr*68 + (cseg << 4) + 8];
        float4 q3 = *(float4*)&scr[rr*68 + (cseg << 4) + 12];
        int gcol = colbase + (cseg << 4);
        if (mode == 3) {
            ushort* O = (ushort*)Cout;
            *(u16x8*)(O + (size_t)grow*Nc + gcol)     = pack8(q0, q1);
            *(u16x8*)(O + (size_t)grow*Nc + gcol + 8) = pack8(q2, q3);
        } else {
            size_t roff;
            if (mode == 2) {
                int rs = (grow >> 10)*L_ + PREF + (grow & (T_-1));
                roff = (size_t)rs*D_ + gcol;
            } else {
                roff = (size_t)grow*Nc + gcol;
            }
            float4 r0 = *(const float4*)(res + roff);
            float4 r1 = *(const float4*)(res + roff + 4);
            float4 r2 = *(const float4*)(res + roff + 8);
            float4 r3 = *(const float4*)(res + roff + 12);
            q0.x += r0.x; q0.y += r0.y; q0.z += r0.z; q0.w += r0.w;
            q1.x += r1.x; q1.y += r1.y; q1.z += r1.z; q1.w += r1.w;
            q2.x += r2.x; q2.y += r2.y; q2.z += r2.z; q2.w += r2.w;
            q3.x += r3.x; q3.y += r3.y; q3.z += r3.z; q3.w += r3.w;
            float* O = (float*)Cout;
            size_t o = (size_t)grow*Nc + gcol;
            *(float4*)(O + o)      = q0;
            *(float4*)(O + o + 4)  = q1;
            *(float4*)(O + o + 8)  = q2;
            *(float4*)(O + o + 12) = q3;
        }
    }
}

// ---------------- MFMA flash attention, swapped-operand softmax ----------
__global__ __launch_bounds__(256) void attn_mfma_kernel(
    const ushort* __restrict__ qhd, const ushort* __restrict__ khd,
    const ushort* __restrict__ vt, ushort* __restrict__ attn_bf)
{
    __shared__ ushort Ks[2][64*64];
    __shared__ ushort Vs[2][64*64];
    __shared__ ushort Ps[4*16*64];

    // XCD swizzle: consecutive (b,h) stay on one XCD for KV L2 reuse
    int bid0 = blockIdx.x;
    int bid = (bid0 & 7) * (gridDim.x >> 3) + (bid0 >> 3);
    int qb = 15 - (bid & 15);
    int h  = (bid >> 4) & (H_ - 1);
    int b  = bid >> 8;
    int tid = threadIdx.x, lane = tid & 63, w = tid >> 6;
    int l15 = lane & 15, lg = lane >> 4;
    int i0 = PREF + (qb << 6);
    int wq0 = w << 4;
    size_t bh = (size_t)(b * H_ + h);

    const ushort* qrow = qhd + (bh * L_ + i0 + wq0 + l15) * 64;
    bf16x8 bq0 = *(const bf16x8*)(qrow + (lg << 3));
    bf16x8 bq1 = *(const bf16x8*)(qrow + 32 + (lg << 3));

    f32x4 acc[4] = {};
    float mrun = -INFINITY;
    float lsum = 0.f;

    int srow = tid >> 3;
    int sslot = tid & 7;
    ushort* Ps_w = Ps + (w << 10);
    const float SC = 0.125f * 1.4426950408889634f;
    int qcap = i0 + wq0 + l15;

#define STAGE_T(buf, t)                                                     \
    do { int j0s = (t) << 6;                                                \
        gl_lds16(khd + (bh * L_ + j0s + srow) * 64 + ((sslot ^ (srow & 7)) << 3),      \
                 (char*)Ks[buf] + (tid << 4));                              \
        gl_lds16(khd + (bh * L_ + j0s + 32 + srow) * 64 + ((sslot ^ ((32+srow) & 7)) << 3), \
                 (char*)Ks[buf] + ((256 + tid) << 4));                      \
        gl_lds16(vt + (bh * 64 + srow) * L_ + j0s + ((sslot ^ (srow & 7)) << 3),       \
                 (char*)Vs[buf] + (tid << 4));                              \
        gl_lds16(vt + (bh * 64 + 32 + srow) * L_ + j0s + ((sslot ^ ((32+srow) & 7)) << 3), \
                 (char*)Vs[buf] + ((256 + tid) << 4));                      \
    } while (0)

    int ntile = 4 + qb;
    STAGE_T(0, 0);
    __syncthreads();
    int cur = 0;
    for (int t = 0; t < ntile; ++t) {
        if (t + 1 < ntile) STAGE_T(cur ^ 1, t + 1);
        const ushort* Kc = Ks[cur];
        const ushort* Vc = Vs[cur];

        f32x4 s4[4];
        __builtin_amdgcn_s_setprio(1);
#pragma unroll
        for (int st = 0; st < 4; ++st) {
            int rk = (st << 4) + l15;
            bf16x8 ak0 = *(const bf16x8*)(Kc + (rk << 6) + ((lg       ^ (rk & 7)) << 3));
            bf16x8 ak1 = *(const bf16x8*)(Kc + (rk << 6) + (((4 + lg) ^ (rk & 7)) << 3));
            f32x4 z = {};
            z = __builtin_amdgcn_mfma_f32_16x16x32_bf16(ak0, bq0, z, 0, 0, 0);
            z = __builtin_amdgcn_mfma_f32_16x16x32_bf16(ak1, bq1, z, 0, 0, 0);
            s4[st] = z;
        }
        __builtin_amdgcn_s_setprio(0);

        int j0 = t << 6;
        float sv[4][4];
        bool diag = (t == ntile - 1);
        int kbq = j0 + (lg << 2);
#pragma unroll
        for (int st = 0; st < 4; ++st)
#pragma unroll
            for (int r = 0; r < 4; ++r) {
                float s = s4[st][r] * SC;
                if (diag && (kbq + (st << 4) + r > qcap)) s = -INFINITY;
                sv[st][r] = s;
            }
        float bm;
        {
            float t0 = fmaxf(fmaxf(sv[0][0], sv[0][1]), fmaxf(sv[0][2], sv[0][3]));
            float t1 = fmaxf(fmaxf(sv[1][0], sv[1][1]), fmaxf(sv[1][2], sv[1][3]));
            float t2 = fmaxf(fmaxf(sv[2][0], sv[2][1]), fmaxf(sv[2][2], sv[2][3]));
            float t3 = fmaxf(fmaxf(sv[3][0], sv[3][1]), fmaxf(sv[3][2], sv[3][3]));
            bm = fmaxf(fmaxf(t0, t1), fmaxf(t2, t3));
        }
        bm = fmaxf(bm, __shfl_xor(bm, 16, 64));
        bm = fmaxf(bm, __shfl_xor(bm, 32, 64));

        float mn = fmaxf(mrun, bm);
        float cr = exp2f(mrun - mn);
        mrun = mn;
        float pe[4][4];
        float ps = 0.f;
#pragma unroll
        for (int st = 0; st < 4; ++st)
#pragma unroll
            for (int r = 0; r < 4; ++r) {
                float e = exp2f(sv[st][r] - mn);
                pe[st][r] = e; ps += e;
            }
        ps += __shfl_xor(ps, 16, 64);
        ps += __shfl_xor(ps, 32, 64);
        lsum = lsum * cr + ps;
#pragma unroll
        for (int su = 0; su < 4; ++su) acc[su] *= cr;

#pragma unroll
        for (int st = 0; st < 4; ++st) {
            int slot = (st << 1) + (lg >> 1);
            int sb = ((lg & 1) << 3);
#pragma unroll
            for (int rp = 0; rp < 2; ++rp) {
                uint u = (uint)f2bf(pe[st][2*rp]) | ((uint)f2bf(pe[st][2*rp+1]) << 16);
                *(uint*)((char*)Ps_w + l15*128 + ((slot ^ (l15 & 7)) << 4) + sb + (rp << 2)) = u;
            }
        }
        {
            bf16x8 bp0 = *(const bf16x8*)((char*)Ps_w + l15*128 + ((lg       ^ (l15 & 7)) << 4));
            bf16x8 bp1 = *(const bf16x8*)((char*)Ps_w + l15*128 + (((4 + lg) ^ (l15 & 7)) << 4));
            __builtin_amdgcn_s_setprio(1);
#pragma unroll
            for (int su = 0; su < 4; ++su) {
                int rd = (su << 4) + l15;
                bf16x8 av0 = *(const bf16x8*)(Vc + (rd << 6) + ((lg       ^ (rd & 7)) << 3));
                bf16x8 av1 = *(const bf16x8*)(Vc + (rd << 6) + (((4 + lg) ^ (rd & 7)) << 3));
                acc[su] = __builtin_amdgcn_mfma_f32_16x16x32_bf16(av0, bp0, acc[su], 0, 0, 0);
                acc[su] = __builtin_amdgcn_mfma_f32_16x16x32_bf16(av1, bp1, acc[su], 0, 0, 0);
            }
            __builtin_amdgcn_s_setprio(0);
        }
        __syncthreads();
        cur ^= 1;
    }
#undef STAGE_T

    float rl = 1.0f / lsum;
    size_t orow = (size_t)b * T_ + (i0 - PREF) + wq0 + l15;
#pragma unroll
    for (int su = 0; su < 4; ++su) {
        ushort4 o4;
        o4.x = f2bf(acc[su][0] * rl);
        o4.y = f2bf(acc[su][1] * rl);
        o4.z = f2bf(acc[su][2] * rl);
        o4.w = f2bf(acc[su][3] * rl);
        *(ushort4*)(attn_bf + orow * D_ + (h << 6) + (su << 4) + (lg << 2)) = o4;
    }
}

// ---------------- launch ----------------
extern "C" void kernel_launch(void* const* d_in, const int* in_sizes, int n_in,
                              void* d_out, int out_size, void* d_ws, size_t ws_size,
                              hipStream_t stream) {
    const float* x   = (const float*)d_in[0];
    const float* mem = (const float*)d_in[1];
    const float* nmr = (const float*)d_in[2];
    const float* Wq  = (const float*)d_in[3];
    const float* bq  = (const float*)d_in[4];
    const float* Wk  = (const float*)d_in[5];
    const float* bk  = (const float*)d_in[6];
    const float* Wv  = (const float*)d_in[7];
    const float* bv  = (const float*)d_in[8];
    const float* Wo  = (const float*)d_in[9];
    const float* bo  = (const float*)d_in[10];
    const float* W1  = (const float*)d_in[11];
    const float* b1  = (const float*)d_in[12];
    const float* W2  = (const float*)d_in[13];
    const float* b2  = (const float*)d_in[14];
    const float* g1  = (const float*)d_in[15];
    const float* be1 = (const float*)d_in[16];
    const float* g2  = (const float*)d_in[17];
    const float* be2 = (const float*)d_in[18];
    float* out = (float*)d_out;

    const size_t BLD = (size_t)BL_ * D_;
    const size_t BTD = (size_t)BT_ * D_;

    float* f = (float*)d_ws;
    float* x_full = f;                         // BLD f32
    float* x2     = f + BLD;                   // BTD f32
    float* bqkv   = x2 + BTD;                  // 4096 f32 (3072 used)
    float* rtab   = bqkv + 4096;               // L_*32 f32
    ushort* bfb   = (ushort*)(rtab + (size_t)L_*32);
    ushort* xa_bf   = bfb;                     // BLD  (reused as attn_bf)
    ushort* qhd     = bfb + BLD;               // BLD  (reused as ln2_bf)
    ushort* khd     = bfb + 2*BLD;             // BLD
    ushort* vt      = bfb + 3*BLD;             // BLD
    ushort* h1_bf   = bfb + 4*BLD;             // BT_*FFN_
    ushort* wq_bf = h1_bf + (size_t)BT_*FFN_;  // Q|K|V|Wo|W1|W2 contiguous
    ushort* wk_bf = wq_bf + (size_t)D_*D_;
    ushort* wv_bf = wk_bf + (size_t)D_*D_;
    ushort* wo_bf = wv_bf + (size_t)D_*D_;
    ushort* w1_bf = wo_bf + (size_t)D_*D_;
    ushort* w2_bf = w1_bf + (size_t)D_*FFN_;
    ushort* attn_bf = xa_bf;
    ushort* ln2_bf  = qhd;

    // weight prep + tables
    wtr4_kernel<<<dim3(16, 16, 4), 256, 0, stream>>>(Wq, Wk, Wv, Wo,
                                                     wq_bf, wk_bf, wv_bf, wo_bf);
    wtr_kernel<<<dim3(FFN_/64, D_/64),   256, 0, stream>>>(W1, w1_bf, D_,   FFN_);
    wtr_kernel<<<dim3(D_/64,   FFN_/64), 256, 0, stream>>>(W2, w2_bf, FFN_, D_);
    prep_kernel<<<(L_*32 + 3072 + 255)/256, 256, 0, stream>>>(rtab, bq, bk, bv, bqkv);

    ln1_concat_kernel<<<BL_, 256, 0, stream>>>(x, mem, nmr, g1, be1, x_full, xa_bf);

    // fused QKV projection (N=3072) with table-RoPE / layout epilogues
    gemm_bf16_kernel<<<dim3(3072/128, BL_/128), 256, 0, stream>>>(
        xa_bf, wq_bf, bqkv, rtab, qhd, D_, D_, D_, 7);

    attn_mfma_kernel<<<B_*H_*(T_/64), 256, 0, stream>>>(qhd, khd, vt, attn_bf);

    // x2 = attn @ Wo + bo + x_full[strided]   (in-block split-K=2)
    gemm512_kernel<2><<<dim3(D_/128, BT_/128), 512, 0, stream>>>(
        attn_bf, wo_bf, bo, x_full, x2, D_, D_, D_, 2);

    ln2_kernel<<<BT_, 256, 0, stream>>>(x2, g2, be2, ln2_bf);

    // h1 = relu(xf @ W1 + b1)^2   (128x256 tile)
    gemm512_kernel<1><<<dim3(FFN_/256, BT_/128), 512, 0, stream>>>(
        ln2_bf, w1_bf, b1, nullptr, h1_bf, FFN_, D_, D_, 3);

    // out = h1 @ W2 + b2 + x2   (in-block split-K=2)
    gemm512_kernel<2><<<dim3(D_/128, BT_/128), 512, 0, stream>>>(
        h1_bf, w2_bf, b2, x2, out, D_, FFN_, FFN_, 1);
}